// Round 2
// baseline (760.659 us; speedup 1.0000x reference)
//
#include <hip/hip_runtime.h>
#include <hip/hip_bf16.h>

// Problem dims (fixed)
#define Bdim 16
#define Sdim 512
#define Ddim 512
#define Hdim 8
#define DKdim 64
#define Fdim 2048
#define Mrows (Bdim * Sdim)   // 8192

typedef __attribute__((ext_vector_type(8))) short  frag16;   // 8 bf16 (4 VGPRs)
typedef __attribute__((ext_vector_type(4))) float  f32x4;    // MFMA acc
typedef __attribute__((ext_vector_type(8))) unsigned short ushort8;
typedef __attribute__((ext_vector_type(4))) unsigned short ushort4v;

// round-to-nearest-even fp32 -> bf16 (finite data)
__device__ __forceinline__ unsigned short f2b(float x) {
    union { float f; unsigned int u; } v; v.f = x;
    unsigned int r = (v.u + 0x7FFFu + ((v.u >> 16) & 1u)) >> 16;
    return (unsigned short)r;
}

// ---------------------------------------------------------------------------
// bf16 MFMA GEMM, 128x128 tile (used for FFN1, N=2048).
// XCD-chunked swizzle + 2-phase double-buffered K-loop.
// ---------------------------------------------------------------------------
__global__ __launch_bounds__(256) void gemm_mfma(
    const __hip_bfloat16* __restrict__ A, const __hip_bfloat16* __restrict__ Bt,
    const float* __restrict__ bias, const float* __restrict__ R,
    float* __restrict__ Cf, unsigned short* __restrict__ Cb,
    int M, int N, int K, int do_relu)
{
    __shared__ short As[2][128 * 32];
    __shared__ short Bs[2][128 * 32];

    const int t = threadIdx.x;
    const int lane = t & 63;
    const int wave = t >> 6;

    // XCD-aware chunked swizzle (grid size divisible by 8)
    const int gx = gridDim.x;
    const int nb = gx * gridDim.y;
    const int lid = blockIdx.x + gx * blockIdx.y;
    const int wid = (lid & 7) * (nb >> 3) + (lid >> 3);
    const int bm = (wid / gx) * 128;
    const int bn = (wid % gx) * 128;

    const int wm = (wave >> 1) * 64;
    const int wn = (wave & 1) * 64;

    f32x4 acc[4][4] = {};
    const int lrow = lane >> 2;
    const int lcol = (lane & 3) * 8;

    auto stage = [&](int k0, int buf) {
#pragma unroll
        for (int i = 0; i < 2; ++i) {
            const int chunk = wave * 2 + i;
            const int row = chunk * 16 + lrow;
            const __hip_bfloat16* ga = A + (size_t)(bm + row) * K + k0 + lcol;
            const __hip_bfloat16* gb = Bt + (size_t)(bn + row) * K + k0 + lcol;
            __builtin_amdgcn_global_load_lds(
                (const __attribute__((address_space(1))) unsigned int*)ga,
                (__attribute__((address_space(3))) unsigned int*)(&As[buf][chunk * 512]),
                16, 0, 0);
            __builtin_amdgcn_global_load_lds(
                (const __attribute__((address_space(1))) unsigned int*)gb,
                (__attribute__((address_space(3))) unsigned int*)(&Bs[buf][chunk * 512]),
                16, 0, 0);
        }
    };

    const int fr = lane & 15;
    const int quad = lane >> 4;
    const int nk = K >> 5;

    stage(0, 0);
    __syncthreads();

    for (int it = 0; it < nk; ++it) {
        const int buf = it & 1;
        if (it + 1 < nk) stage((it + 1) << 5, buf ^ 1);
        frag16 af[4], bfr[4];
#pragma unroll
        for (int i = 0; i < 4; ++i) {
            af[i]  = *(const frag16*)(&As[buf][(wm + i * 16 + fr) * 32 + quad * 8]);
            bfr[i] = *(const frag16*)(&Bs[buf][(wn + i * 16 + fr) * 32 + quad * 8]);
        }
#pragma unroll
        for (int mi = 0; mi < 4; ++mi)
#pragma unroll
            for (int ni = 0; ni < 4; ++ni)
                acc[mi][ni] = __builtin_amdgcn_mfma_f32_16x16x32_bf16(
                    af[mi], bfr[ni], acc[mi][ni], 0, 0, 0);
        __syncthreads();
    }

#pragma unroll
    for (int mi = 0; mi < 4; ++mi) {
#pragma unroll
        for (int r = 0; r < 4; ++r) {
            const int m = bm + wm + mi * 16 + quad * 4 + r;
#pragma unroll
            for (int ni = 0; ni < 4; ++ni) {
                const int n = bn + wn + ni * 16 + fr;
                float v = acc[mi][ni][r] + bias[n];
                if (R) v += R[(size_t)m * N + n];
                if (do_relu) v = fmaxf(v, 0.f);
                if (Cf) Cf[(size_t)m * N + n] = v;
                if (Cb) Cb[(size_t)m * N + n] = f2b(v);
            }
        }
    }
}

// ---------------------------------------------------------------------------
// bf16 MFMA GEMM, 128x64 tile, N=512 fixed. Dual-mode via blockIdx.z:
// z=0: A0@B0^T+bias0 -> Cb (normal bf16) / Cf(+R) fp32
// z=1: A1@B1^T+bias1 -> CbT transposed Vt[b,h,d,s] bf16
// XCD-chunked swizzle + 2-phase double-buffered K-loop.
// ---------------------------------------------------------------------------
__global__ __launch_bounds__(256) void gemm_n64(
    const unsigned short* __restrict__ A0, const unsigned short* __restrict__ A1,
    const unsigned short* __restrict__ B0, const unsigned short* __restrict__ B1,
    const float* __restrict__ bias0, const float* __restrict__ bias1,
    const float* __restrict__ R, float* __restrict__ Cf,
    unsigned short* __restrict__ Cb, unsigned short* __restrict__ CbT,
    int K)
{
    const int NN = 512;
    __shared__ short As[2][128 * 32];
    __shared__ short Bs[2][64 * 32];

    const int trans = blockIdx.z;
    const unsigned short* A  = trans ? A1 : A0;
    const unsigned short* Bt = trans ? B1 : B0;
    const float* bias        = trans ? bias1 : bias0;

    const int t = threadIdx.x;
    const int lane = t & 63;
    const int wave = t >> 6;

    // XCD-aware chunked swizzle within each z-slice (512 % 8 == 0 so the
    // z offset preserves the XCD residue).
    const int lid = blockIdx.x + 8 * blockIdx.y;          // 0..511
    const int wid = (lid & 7) * 64 + (lid >> 3);
    const int bm = (wid >> 3) * 128;
    const int bn = (wid & 7) * 64;

    const int wm = (wave >> 1) * 64;
    const int wn = (wave & 1) * 32;

    f32x4 acc[4][2] = {};
    const int lrow = lane >> 2;
    const int lcol = (lane & 3) * 8;

    auto stage = [&](int k0, int buf) {
#pragma unroll
        for (int i = 0; i < 2; ++i) {
            const int chunk = wave * 2 + i;
            const int row = chunk * 16 + lrow;
            const unsigned short* ga = A + (size_t)(bm + row) * K + k0 + lcol;
            __builtin_amdgcn_global_load_lds(
                (const __attribute__((address_space(1))) unsigned int*)ga,
                (__attribute__((address_space(3))) unsigned int*)(&As[buf][chunk * 512]),
                16, 0, 0);
        }
        {
            const int row = wave * 16 + lrow;
            const unsigned short* gb = Bt + (size_t)(bn + row) * K + k0 + lcol;
            __builtin_amdgcn_global_load_lds(
                (const __attribute__((address_space(1))) unsigned int*)gb,
                (__attribute__((address_space(3))) unsigned int*)(&Bs[buf][wave * 512]),
                16, 0, 0);
        }
    };

    const int fr = lane & 15;
    const int quad = lane >> 4;
    const int nk = K >> 5;

    stage(0, 0);
    __syncthreads();

    for (int it = 0; it < nk; ++it) {
        const int buf = it & 1;
        if (it + 1 < nk) stage((it + 1) << 5, buf ^ 1);
        frag16 af[4], bfr[2];
#pragma unroll
        for (int i = 0; i < 4; ++i)
            af[i] = *(const frag16*)(&As[buf][(wm + i * 16 + fr) * 32 + quad * 8]);
#pragma unroll
        for (int i = 0; i < 2; ++i)
            bfr[i] = *(const frag16*)(&Bs[buf][(wn + i * 16 + fr) * 32 + quad * 8]);
#pragma unroll
        for (int mi = 0; mi < 4; ++mi)
#pragma unroll
            for (int ni = 0; ni < 2; ++ni)
                acc[mi][ni] = __builtin_amdgcn_mfma_f32_16x16x32_bf16(
                    af[mi], bfr[ni], acc[mi][ni], 0, 0, 0);
        __syncthreads();
    }

    if (trans) {
#pragma unroll
        for (int mi = 0; mi < 4; ++mi)
#pragma unroll
            for (int ni = 0; ni < 2; ++ni) {
                const int m = bm + wm + mi * 16 + quad * 4;
                const int n = bn + wn + ni * 16 + fr;
                ushort4v o;
#pragma unroll
                for (int r = 0; r < 4; ++r) o[r] = f2b(acc[mi][ni][r] + bias[n]);
                const int bb = m >> 9, s = m & 511;
                const int hh = n >> 6, dd = n & 63;
                *(ushort4v*)(CbT + (((size_t)((bb * Hdim + hh) * DKdim + dd)) << 9) + s) = o;
            }
        return;
    }

#pragma unroll
    for (int mi = 0; mi < 4; ++mi) {
#pragma unroll
        for (int r = 0; r < 4; ++r) {
            const int m = bm + wm + mi * 16 + quad * 4 + r;
#pragma unroll
            for (int ni = 0; ni < 2; ++ni) {
                const int n = bn + wn + ni * 16 + fr;
                float v = acc[mi][ni][r] + bias[n];
                if (R) v += R[(size_t)m * NN + n];
                if (Cf) Cf[(size_t)m * NN + n] = v;
                if (Cb) Cb[(size_t)m * NN + n] = f2b(v);
            }
        }
    }
}

// ---------------------------------------------------------------------------
// fp32 -> bf16 convert
// ---------------------------------------------------------------------------
__global__ __launch_bounds__(256) void conv_b(
    const float* __restrict__ X, unsigned short* __restrict__ Y)
{
    const size_t i = ((size_t)blockIdx.x * 256 + threadIdx.x) * 8;
    float4 a = *(const float4*)(X + i);
    float4 b = *(const float4*)(X + i + 4);
    ushort8 o;
    o[0] = f2b(a.x); o[1] = f2b(a.y); o[2] = f2b(a.z); o[3] = f2b(a.w);
    o[4] = f2b(b.x); o[5] = f2b(b.y); o[6] = f2b(b.z); o[7] = f2b(b.w);
    *(ushort8*)(Y + i) = o;
}

// ---------------------------------------------------------------------------
// ALL weight transposes fused: 1600 tiles of 64x64, [K,N] fp32 -> [N,K] bf16
// ---------------------------------------------------------------------------
__global__ __launch_bounds__(256) void wtrans_all(
    const float* __restrict__ Wk, const float* __restrict__ Wv,
    const float* __restrict__ Wo, const float* __restrict__ W1,
    const float* __restrict__ W2, unsigned short* __restrict__ dst)
{
    const int bid = blockIdx.x;
    const float* src; unsigned short* d; int K, N, tk, tn;
    if (bid < 576) {
        const int mat = bid >> 6, tile = bid & 63;
        const int l = mat / 3, wch = mat % 3;
        const float* W = (wch == 0) ? Wk : (wch == 1) ? Wv : Wo;
        src = W + (size_t)l * 262144;
        d = dst + (size_t)mat * 262144;
        K = 512; N = 512; tn = tile & 7; tk = tile >> 3;
    } else if (bid < 1088) {
        const int idx = bid - 576, l2 = idx >> 8, tile = idx & 255;
        src = W1 + (size_t)(l2 * 2) * (512 * 2048);
        d = dst + 9 * 262144 + (size_t)l2 * (512 * 2048);
        K = 512; N = 2048; tn = tile & 31; tk = tile >> 5;
    } else {
        const int idx = bid - 1088, l2 = idx >> 8, tile = idx & 255;
        src = W2 + (size_t)(l2 * 2) * (2048 * 512);
        d = dst + 9 * 262144 + 2 * (512 * 2048) + (size_t)l2 * (2048 * 512);
        K = 2048; N = 512; tn = tile & 7; tk = tile >> 3;
    }
    const int n0 = tn * 64, k0 = tk * 64;
    __shared__ float T[64][65];
    const int t = threadIdx.x;
    const int kl = t >> 4, n4 = (t & 15) << 2;
#pragma unroll
    for (int it = 0; it < 4; ++it) {
        const int k = kl + it * 16;
        float4 v = *(const float4*)(src + (size_t)(k0 + k) * N + n0 + n4);
        T[n4 + 0][k] = v.x; T[n4 + 1][k] = v.y;
        T[n4 + 2][k] = v.z; T[n4 + 3][k] = v.w;
    }
    __syncthreads();
    const int nl = t >> 3, k8 = (t & 7) << 3;
#pragma unroll
    for (int it = 0; it < 2; ++it) {
        const int n = nl + it * 32;
        ushort8 o;
#pragma unroll
        for (int c = 0; c < 8; ++c) o[c] = f2b(T[n][k8 + c]);
        *(ushort8*)(d + (size_t)(n0 + n) * K + k0 + k8) = o;
    }
}

// ---------------------------------------------------------------------------
// Flash-style monotonic attention v4. Wave-pair j-split (v3) + XCD-chunked
// block swizzle: the 16 q-tile blocks sharing one (b,h)'s K/Vt panels
// (128 KB) land on ONE XCD so the panels stay L2-resident (2 MB/XCD working
// set) instead of being refetched from HBM by all 8 XCDs.
// Fully-masked row (mask0, i==0): uniform 1/512 over ALL j.
// ---------------------------------------------------------------------------
__global__ __launch_bounds__(256, 8) void attn_flash4(
    const unsigned short* __restrict__ Kb,   // [B*S, D] bf16 (Q == K)
    const unsigned short* __restrict__ Vt,   // [B,H,DK,S] bf16
    const float* __restrict__ gam,
    unsigned short* __restrict__ Ob,         // [B*S, D] bf16
    int mask_type)
{
    __shared__ float CTs[2][16 * 33];            // cross-tile strict suffix (per pair)
    __shared__ unsigned short Pst[4][16 * 36];   // P staging (A-frag layout, per wave)
    __shared__ float S1s[2][2][16];              // sum1 partials [pair][p][row]
    __shared__ float S2s[2][2][16];              // sum2 partials
    __shared__ float OaccS[2][16 * 66];          // oacc combine

    // XCD-chunked bijective swizzle: grid (16,8,16) = 2048 blocks, chunk=256
    const int lid = blockIdx.x + 16 * blockIdx.y + 128 * blockIdx.z;
    const int wid = (lid & 7) * 256 + (lid >> 3);
    const int bx = wid & 15;
    const int h  = (wid >> 4) & 7;
    const int b  = wid >> 7;
    const int qt = (bx + h + b) & 15;            // balance swizzle

    const int t = threadIdx.x, lane = t & 63, w = t >> 6;
    const int pair = w >> 1;                 // which 16-row q-subtile
    const int p = w & 1;                     // j-split parity within the pair
    const int quad = lane >> 4, fr = lane & 15;
    const int q0 = qt * 32 + pair * 16;
    const int iRow = q0 + fr;                // this lane's q row

    const unsigned short* kbase = Kb + (size_t)b * Sdim * Ddim + h * DKdim;

    // Q as B-operand: rows q0+fr
    frag16 aq0 = *(const frag16*)(kbase + (size_t)(q0 + fr) * Ddim + quad * 8);
    frag16 aq1 = *(const frag16*)(kbase + (size_t)(q0 + fr) * Ddim + 32 + quad * 8);

    float* CTw = CTs[pair];
    const int jnmax = (q0 + 15) >> 4;

    // ---- Pass 1: sum1 partials + per-tile totals into CT (tiles split by parity)
    float psum = 0.f;
    for (int jn = p; jn <= jnmax; jn += 2) {
        frag16 k0 = *(const frag16*)(kbase + (size_t)(jn * 16 + fr) * Ddim + quad * 8);
        frag16 k1 = *(const frag16*)(kbase + (size_t)(jn * 16 + fr) * Ddim + 32 + quad * 8);
        f32x4 z = {0.f, 0.f, 0.f, 0.f};
        z = __builtin_amdgcn_mfma_f32_16x16x32_bf16(k0, aq0, z, 0, 0, 0);
        z = __builtin_amdgcn_mfma_f32_16x16x32_bf16(k1, aq1, z, 0, 0, 0);
        const int jbase = jn * 16 + quad * 4;
        float tq = 0.f;
#pragma unroll
        for (int r = 0; r < 4; ++r) {
            const int j = jbase + r;
            const bool valid = mask_type ? (j <= iRow) : (j < iRow);
            tq += valid ? __expf(z[r] * 0.125f) : 0.f;
        }
        psum += tq;
        float tt = tq;
        tt += __shfl_xor(tt, 16);
        tt += __shfl_xor(tt, 32);
        if (quad == 0) CTw[fr * 33 + jn] = tt;
    }
    {
        float s1 = psum;
        s1 += __shfl_xor(s1, 16);
        s1 += __shfl_xor(s1, 32);
        if (lane < 16) S1s[pair][p][lane] = s1;
    }
    __syncthreads();

    // totals -> strict cross-tile suffix (p==0 wave of each pair; rows by lanes 0..15)
    if (p == 0 && lane < 16) {
        float run = 0.f;
        for (int jn = 31; jn >= 0; --jn) {
            const float tv = (jn <= jnmax) ? CTw[lane * 33 + jn] : 0.f;
            CTw[lane * 33 + jn] = run;
            run += tv;
        }
    }
    __syncthreads();

    const float rsum1 = 1.f / (S1s[pair][0][fr] + S1s[pair][1][fr]);  // inf iff fully masked
    const float gneg = -log1pf(__expf(gam[h]));   // -softplus(gamma)

    // ---- Pass 2: independent u-tiles split by parity, online PV
    unsigned short* Pw = Pst[w];
    const unsigned short* vtb = Vt + (size_t)(b * Hdim + h) * DKdim * Sdim;
    const bool fm_pair = (mask_type == 0) && (q0 == 0);
    const bool fmrow = (mask_type == 0) && (iRow == 0);
    const int umax = fm_pair ? (Sdim / 32 - 1) : ((q0 + 15) >> 5);
    float sum2p = 0.f;
    f32x4 oacc[4] = {};

    for (int u = umax - p; u >= 0; u -= 2) {
#pragma unroll
        for (int half = 0; half < 2; ++half) {
            const int jn = 2 * u + half;
            frag16 k0 = *(const frag16*)(kbase + (size_t)(jn * 16 + fr) * Ddim + quad * 8);
            frag16 k1 = *(const frag16*)(kbase + (size_t)(jn * 16 + fr) * Ddim + 32 + quad * 8);
            f32x4 z = {0.f, 0.f, 0.f, 0.f};
            z = __builtin_amdgcn_mfma_f32_16x16x32_bf16(k0, aq0, z, 0, 0, 0);
            z = __builtin_amdgcn_mfma_f32_16x16x32_bf16(k1, aq1, z, 0, 0, 0);
            const int jbase = jn * 16 + quad * 4;
            float s[4], e1[4], lsuf[4];
            float tq = 0.f;
#pragma unroll
            for (int r = 3; r >= 0; --r) {
                lsuf[r] = tq;                      // strict suffix within 4-run
                const int j = jbase + r;
                const bool valid = mask_type ? (j <= iRow) : (j < iRow);
                s[r] = z[r] * 0.125f;
                e1[r] = valid ? __expf(s[r]) : 0.f;
                tq += e1[r];
            }
            // strict suffix over quads (2 guarded shfl_down)
            float incl = tq;
            {
                float u1 = __shfl_down(incl, 16);
                incl += (quad < 3) ? u1 : 0.f;
                float u2 = __shfl_down(incl, 32);
                incl += (quad < 2) ? u2 : 0.f;
            }
            const float qsuf = incl - tq;
            const float ct = CTw[fr * 33 + jn];
            ushort4v pk;
#pragma unroll
            for (int r = 0; r < 4; ++r) {
                const int j = jbase + r;
                const bool valid = mask_type ? (j <= iRow) : (j < iRow);
                const float suf = ct + qsuf + lsuf[r];
                const float ratio = suf * rsum1;
                const int dd = iRow - j;
                const float pos = (float)(dd >= 0 ? dd : -dd);
                const float arg = (ratio > 0.f) ? ratio * pos : 0.f;   // NaN-safe
                const float te = fminf(fmaxf(__expf(gneg * sqrtf(arg)), 1e-5f), 1e5f);
                const float e2 = valid ? __expf(s[r] * te) : (fmrow ? 1.f : 0.f);
                sum2p += e2;
                pk[r] = f2b(e2);
            }
            *(ushort4v*)(Pw + fr * 36 + half * 16 + quad * 4) = pk;
        }
        // PV over this pair's 32-wide window (A = P from LDS, B = Vt)
        frag16 pf = *(const frag16*)(Pw + fr * 36 + quad * 8);
        const int jb = u * 32;
#pragma unroll
        for (int dt = 0; dt < 4; ++dt) {
            frag16 vf = *(const frag16*)(vtb + (size_t)(dt * 16 + fr) * Sdim + jb + quad * 8);
            oacc[dt] = __builtin_amdgcn_mfma_f32_16x16x32_bf16(pf, vf, oacc[dt], 0, 0, 0);
        }
    }

    // ---- combine the pair's partials
    {
        float s2 = sum2p;
        s2 += __shfl_xor(s2, 16);
        s2 += __shfl_xor(s2, 32);
        if (lane < 16) S2s[pair][p][lane] = s2;
    }
    if (p == 1) {
        float* Os = OaccS[pair];
#pragma unroll
        for (int dt = 0; dt < 4; ++dt)
#pragma unroll
            for (int r = 0; r < 4; ++r)
                Os[(quad * 4 + r) * 66 + dt * 16 + fr] = oacc[dt][r];
    }
    __syncthreads();

    if (p == 0) {
        const float* Os = OaccS[pair];
        const float rs2 = 1.f / (S2s[pair][0][fr] + S2s[pair][1][fr]);   // for row fr
        float rs2q[4];
#pragma unroll
        for (int r = 0; r < 4; ++r) rs2q[r] = __shfl(rs2, quad * 4 + r);

        // O rows q0+quad*4+r, cols dt*16+fr
        unsigned short* obase = Ob + ((size_t)(b * Sdim + q0)) * Ddim + h * DKdim;
#pragma unroll
        for (int dt = 0; dt < 4; ++dt)
#pragma unroll
            for (int r = 0; r < 4; ++r) {
                const float v = oacc[dt][r] + Os[(quad * 4 + r) * 66 + dt * 16 + fr];
                obase[(size_t)(quad * 4 + r) * Ddim + dt * 16 + fr] = f2b(v * rs2q[r]);
            }
    }
}

// ---------------------------------------------------------------------------
// LayerNorm over last dim (512); fp32 out (nullable) + bf16 out (nullable).
// ---------------------------------------------------------------------------
__global__ __launch_bounds__(256) void ln_kernel(
    const float* __restrict__ X, const float* __restrict__ g,
    const float* __restrict__ bta, float* __restrict__ Y,
    unsigned short* __restrict__ Yb)
{
    const int row = blockIdx.x;
    const int t = threadIdx.x;
    __shared__ float r1[256], r2[256];
    const float* x = X + (size_t)row * Ddim;
    float a = x[t], b = x[t + 256];
    r1[t] = a + b;
    r2[t] = a * a + b * b;
    __syncthreads();
    for (int off = 128; off; off >>= 1) {
        if (t < off) { r1[t] += r1[t + off]; r2[t] += r2[t + off]; }
        __syncthreads();
    }
    float mean = r1[0] * (1.f / Ddim);
    float var = r2[0] * (1.f / Ddim) - mean * mean;
    float rs = rsqrtf(var + 1e-5f);
    float y0 = (a - mean) * rs * g[t] + bta[t];
    float y1 = (b - mean) * rs * g[t + 256] + bta[t + 256];
    if (Y) {
        float* y = Y + (size_t)row * Ddim;
        y[t] = y0;
        y[t + 256] = y1;
    }
    if (Yb) {
        unsigned short* yb = Yb + (size_t)row * Ddim;
        yb[t] = f2b(y0);
        yb[t + 256] = f2b(y1);
    }
}

// ---------------------------------------------------------------------------
extern "C" void kernel_launch(void* const* d_in, const int* in_sizes, int n_in,
                              void* d_out, int out_size, void* d_ws, size_t ws_size,
                              hipStream_t stream)
{
    const float* x0     = (const float*)d_in[0];
    const float* y0     = (const float*)d_in[1];
    const float* Wk     = (const float*)d_in[2];
    const float* bk     = (const float*)d_in[3];
    const float* Wv     = (const float*)d_in[4];
    const float* bv     = (const float*)d_in[5];
    const float* Wo     = (const float*)d_in[6];
    const float* bo     = (const float*)d_in[7];
    const float* gammas = (const float*)d_in[8];
    const float* ln1g   = (const float*)d_in[9];
    const float* ln1b   = (const float*)d_in[10];
    const float* W1     = (const float*)d_in[11];
    const float* b1     = (const float*)d_in[12];
    const float* W2     = (const float*)d_in[13];
    const float* b2     = (const float*)d_in[14];
    const float* ln2g   = (const float*)d_in[15];
    const float* ln2b   = (const float*)d_in[16];

    const size_t NBSD = (size_t)Mrows * Ddim;   // 4,194,304
    float* ws = (float*)d_ws;
    float* T1   = ws;
    float* X1   = T1 + NBSD;
    float* Xbuf = X1 + NBSD;
    unsigned short* Kbf = (unsigned short*)(Xbuf + NBSD);
    unsigned short* Vt  = Kbf + NBSD;
    unsigned short* AOb = Vt + NBSD;
    unsigned short* Abf = AOb + NBSD;
    unsigned short* Xbf = Abf + NBSD;
    unsigned short* Ybf = Xbf + NBSD;
    unsigned short* Hbb = Ybf + NBSD;                       // [M,F]
    unsigned short* WtAll = Hbb + (size_t)Mrows * Fdim;

    auto WtK = [&](int l) { return WtAll + (size_t)(l * 3 + 0) * 262144; };
    auto WtV = [&](int l) { return WtAll + (size_t)(l * 3 + 1) * 262144; };
    auto WtO = [&](int l) { return WtAll + (size_t)(l * 3 + 2) * 262144; };
    auto Wt1 = [&](int l) { return WtAll + 9 * 262144 + (size_t)(l >> 1) * (512 * 2048); };
    auto Wt2 = [&](int l) { return WtAll + 9 * 262144 + 2 * (512 * 2048) + (size_t)(l >> 1) * (2048 * 512); };

    const int convBlocks = (int)(NBSD / 2048);

    wtrans_all<<<1600, 256, 0, stream>>>(Wk, Wv, Wo, W1, W2, WtAll);

    auto run_block = [&](int l, const float* qinf, const unsigned short* qinb,
                         const unsigned short* vinb, int mask_type, bool ffn,
                         float* outf, unsigned short* outb) {
        const float* bk_l = bk + (size_t)l * Ddim;
        const float* bv_l = bv + (size_t)l * Ddim;
        const float* bo_l = bo + (size_t)l * Ddim;

        // K (=Q) + V projections in one launch (z=0: K->Kbf, z=1: V->Vt)
        gemm_n64<<<dim3(8, 64, 2), 256, 0, stream>>>(
            qinb, vinb, WtK(l), WtV(l), bk_l, bv_l,
            nullptr, nullptr, Kbf, Vt, Ddim);
        // attention (flash-style streaming, wave-pair j-split, XCD-local)
        attn_flash4<<<dim3(Sdim / 32, Hdim, Bdim), 256, 0, stream>>>(
            Kbf, Vt, gammas + (size_t)l * Hdim, AOb, mask_type);
        // O-projection + residual -> T1 (fp32); LN1
        gemm_n64<<<dim3(8, 64, 1), 256, 0, stream>>>(
            AOb, AOb, WtO(l), WtO(l), bo_l, bo_l,
            qinf, T1, nullptr, nullptr, Ddim);
        float* x1f = ffn ? X1 : outf;
        unsigned short* x1b = ffn ? Abf : outb;
        ln_kernel<<<Mrows, 256, 0, stream>>>(T1,
            ln1g + (size_t)l * Ddim, ln1b + (size_t)l * Ddim, x1f, x1b);
        if (ffn) {
            const float* b1_l = b1 + (size_t)l * Fdim;
            const float* b2_l = b2 + (size_t)l * Ddim;
            gemm_mfma<<<dim3(Fdim / 128, Mrows / 128), 256, 0, stream>>>(
                (const __hip_bfloat16*)Abf, (const __hip_bfloat16*)Wt1(l),
                b1_l, nullptr, nullptr, Hbb, Mrows, Fdim, Ddim, 1);
            gemm_n64<<<dim3(8, 64, 1), 256, 0, stream>>>(
                Hbb, Hbb, Wt2(l), Wt2(l), b2_l, b2_l,
                X1, T1, nullptr, nullptr, Fdim);
            ln_kernel<<<Mrows, 256, 0, stream>>>(T1,
                ln2g + (size_t)l * Ddim, ln2b + (size_t)l * Ddim, outf, outb);
        }
    };

    // Block 0: knowledge encoder (y), mask1, FFN -> Ybf (bf16 only)
    conv_b<<<convBlocks, 256, 0, stream>>>(y0, Abf);
    run_block(0, y0, Abf, Abf, 1, true, nullptr, Ybf);
    // Block 1: question encoder (x), mask1, no FFN -> Xbuf/Xbf
    conv_b<<<convBlocks, 256, 0, stream>>>(x0, Abf);
    run_block(1, x0, Abf, Abf, 1, false, Xbuf, Xbf);
    // Block 2: knowledge retriever, q/k=x, v=y, mask0, FFN -> d_out (fp32)
    run_block(2, Xbuf, Xbf, Ybf, 0, true, (float*)d_out, nullptr);
}

// Round 3
// 697.057 us; speedup vs baseline: 1.0912x; 1.0912x over previous
//
#include <hip/hip_runtime.h>
#include <hip/hip_bf16.h>

// Problem dims (fixed)
#define Bdim 16
#define Sdim 512
#define Ddim 512
#define Hdim 8
#define DKdim 64
#define Fdim 2048
#define Mrows (Bdim * Sdim)   // 8192

typedef __attribute__((ext_vector_type(8))) short  frag16;   // 8 bf16 (4 VGPRs)
typedef __attribute__((ext_vector_type(4))) float  f32x4;    // MFMA acc
typedef __attribute__((ext_vector_type(8))) unsigned short ushort8;
typedef __attribute__((ext_vector_type(4))) unsigned short ushort4v;

// round-to-nearest-even fp32 -> bf16 (finite data)
__device__ __forceinline__ unsigned short f2b(float x) {
    union { float f; unsigned int u; } v; v.f = x;
    unsigned int r = (v.u + 0x7FFFu + ((v.u >> 16) & 1u)) >> 16;
    return (unsigned short)r;
}

// ---------------------------------------------------------------------------
// bf16 MFMA GEMM, 128x128 tile (used for FFN1, N=2048).
// XCD-chunked swizzle + 2-phase double-buffered K-loop.
// ---------------------------------------------------------------------------
__global__ __launch_bounds__(256) void gemm_mfma(
    const __hip_bfloat16* __restrict__ A, const __hip_bfloat16* __restrict__ Bt,
    const float* __restrict__ bias, const float* __restrict__ R,
    float* __restrict__ Cf, unsigned short* __restrict__ Cb,
    int M, int N, int K, int do_relu)
{
    __shared__ short As[2][128 * 32];
    __shared__ short Bs[2][128 * 32];

    const int t = threadIdx.x;
    const int lane = t & 63;
    const int wave = t >> 6;

    // XCD-aware chunked swizzle (grid size divisible by 8)
    const int gx = gridDim.x;
    const int nb = gx * gridDim.y;
    const int lid = blockIdx.x + gx * blockIdx.y;
    const int wid = (lid & 7) * (nb >> 3) + (lid >> 3);
    const int bm = (wid / gx) * 128;
    const int bn = (wid % gx) * 128;

    const int wm = (wave >> 1) * 64;
    const int wn = (wave & 1) * 64;

    f32x4 acc[4][4] = {};
    const int lrow = lane >> 2;
    const int lcol = (lane & 3) * 8;

    auto stage = [&](int k0, int buf) {
#pragma unroll
        for (int i = 0; i < 2; ++i) {
            const int chunk = wave * 2 + i;
            const int row = chunk * 16 + lrow;
            const __hip_bfloat16* ga = A + (size_t)(bm + row) * K + k0 + lcol;
            const __hip_bfloat16* gb = Bt + (size_t)(bn + row) * K + k0 + lcol;
            __builtin_amdgcn_global_load_lds(
                (const __attribute__((address_space(1))) unsigned int*)ga,
                (__attribute__((address_space(3))) unsigned int*)(&As[buf][chunk * 512]),
                16, 0, 0);
            __builtin_amdgcn_global_load_lds(
                (const __attribute__((address_space(1))) unsigned int*)gb,
                (__attribute__((address_space(3))) unsigned int*)(&Bs[buf][chunk * 512]),
                16, 0, 0);
        }
    };

    const int fr = lane & 15;
    const int quad = lane >> 4;
    const int nk = K >> 5;

    stage(0, 0);
    __syncthreads();

    for (int it = 0; it < nk; ++it) {
        const int buf = it & 1;
        if (it + 1 < nk) stage((it + 1) << 5, buf ^ 1);
        frag16 af[4], bfr[4];
#pragma unroll
        for (int i = 0; i < 4; ++i) {
            af[i]  = *(const frag16*)(&As[buf][(wm + i * 16 + fr) * 32 + quad * 8]);
            bfr[i] = *(const frag16*)(&Bs[buf][(wn + i * 16 + fr) * 32 + quad * 8]);
        }
#pragma unroll
        for (int mi = 0; mi < 4; ++mi)
#pragma unroll
            for (int ni = 0; ni < 4; ++ni)
                acc[mi][ni] = __builtin_amdgcn_mfma_f32_16x16x32_bf16(
                    af[mi], bfr[ni], acc[mi][ni], 0, 0, 0);
        __syncthreads();
    }

#pragma unroll
    for (int mi = 0; mi < 4; ++mi) {
#pragma unroll
        for (int r = 0; r < 4; ++r) {
            const int m = bm + wm + mi * 16 + quad * 4 + r;
#pragma unroll
            for (int ni = 0; ni < 4; ++ni) {
                const int n = bn + wn + ni * 16 + fr;
                float v = acc[mi][ni][r] + bias[n];
                if (R) v += R[(size_t)m * N + n];
                if (do_relu) v = fmaxf(v, 0.f);
                if (Cf) Cf[(size_t)m * N + n] = v;
                if (Cb) Cb[(size_t)m * N + n] = f2b(v);
            }
        }
    }
}

// ---------------------------------------------------------------------------
// bf16 MFMA GEMM, 128x64 tile, N=512 fixed. Dual-mode via blockIdx.z:
// z=0: A0@B0^T+bias0 -> Cb (normal bf16) / Cf(+R) fp32
// z=1: A1@B1^T+bias1 -> CbT transposed Vt[b,h,d,s] bf16
// XCD-chunked swizzle + 2-phase double-buffered K-loop.
// ---------------------------------------------------------------------------
__global__ __launch_bounds__(256) void gemm_n64(
    const unsigned short* __restrict__ A0, const unsigned short* __restrict__ A1,
    const unsigned short* __restrict__ B0, const unsigned short* __restrict__ B1,
    const float* __restrict__ bias0, const float* __restrict__ bias1,
    const float* __restrict__ R, float* __restrict__ Cf,
    unsigned short* __restrict__ Cb, unsigned short* __restrict__ CbT,
    int K)
{
    const int NN = 512;
    __shared__ short As[2][128 * 32];
    __shared__ short Bs[2][64 * 32];

    const int trans = blockIdx.z;
    const unsigned short* A  = trans ? A1 : A0;
    const unsigned short* Bt = trans ? B1 : B0;
    const float* bias        = trans ? bias1 : bias0;

    const int t = threadIdx.x;
    const int lane = t & 63;
    const int wave = t >> 6;

    // XCD-aware chunked swizzle within each z-slice (512 % 8 == 0 so the
    // z offset preserves the XCD residue).
    const int lid = blockIdx.x + 8 * blockIdx.y;          // 0..511
    const int wid = (lid & 7) * 64 + (lid >> 3);
    const int bm = (wid >> 3) * 128;
    const int bn = (wid & 7) * 64;

    const int wm = (wave >> 1) * 64;
    const int wn = (wave & 1) * 32;

    f32x4 acc[4][2] = {};
    const int lrow = lane >> 2;
    const int lcol = (lane & 3) * 8;

    auto stage = [&](int k0, int buf) {
#pragma unroll
        for (int i = 0; i < 2; ++i) {
            const int chunk = wave * 2 + i;
            const int row = chunk * 16 + lrow;
            const unsigned short* ga = A + (size_t)(bm + row) * K + k0 + lcol;
            __builtin_amdgcn_global_load_lds(
                (const __attribute__((address_space(1))) unsigned int*)ga,
                (__attribute__((address_space(3))) unsigned int*)(&As[buf][chunk * 512]),
                16, 0, 0);
        }
        {
            const int row = wave * 16 + lrow;
            const unsigned short* gb = Bt + (size_t)(bn + row) * K + k0 + lcol;
            __builtin_amdgcn_global_load_lds(
                (const __attribute__((address_space(1))) unsigned int*)gb,
                (__attribute__((address_space(3))) unsigned int*)(&Bs[buf][wave * 512]),
                16, 0, 0);
        }
    };

    const int fr = lane & 15;
    const int quad = lane >> 4;
    const int nk = K >> 5;

    stage(0, 0);
    __syncthreads();

    for (int it = 0; it < nk; ++it) {
        const int buf = it & 1;
        if (it + 1 < nk) stage((it + 1) << 5, buf ^ 1);
        frag16 af[4], bfr[2];
#pragma unroll
        for (int i = 0; i < 4; ++i)
            af[i] = *(const frag16*)(&As[buf][(wm + i * 16 + fr) * 32 + quad * 8]);
#pragma unroll
        for (int i = 0; i < 2; ++i)
            bfr[i] = *(const frag16*)(&Bs[buf][(wn + i * 16 + fr) * 32 + quad * 8]);
#pragma unroll
        for (int mi = 0; mi < 4; ++mi)
#pragma unroll
            for (int ni = 0; ni < 2; ++ni)
                acc[mi][ni] = __builtin_amdgcn_mfma_f32_16x16x32_bf16(
                    af[mi], bfr[ni], acc[mi][ni], 0, 0, 0);
        __syncthreads();
    }

    if (trans) {
#pragma unroll
        for (int mi = 0; mi < 4; ++mi)
#pragma unroll
            for (int ni = 0; ni < 2; ++ni) {
                const int m = bm + wm + mi * 16 + quad * 4;
                const int n = bn + wn + ni * 16 + fr;
                ushort4v o;
#pragma unroll
                for (int r = 0; r < 4; ++r) o[r] = f2b(acc[mi][ni][r] + bias[n]);
                const int bb = m >> 9, s = m & 511;
                const int hh = n >> 6, dd = n & 63;
                *(ushort4v*)(CbT + (((size_t)((bb * Hdim + hh) * DKdim + dd)) << 9) + s) = o;
            }
        return;
    }

#pragma unroll
    for (int mi = 0; mi < 4; ++mi) {
#pragma unroll
        for (int r = 0; r < 4; ++r) {
            const int m = bm + wm + mi * 16 + quad * 4 + r;
#pragma unroll
            for (int ni = 0; ni < 2; ++ni) {
                const int n = bn + wn + ni * 16 + fr;
                float v = acc[mi][ni][r] + bias[n];
                if (R) v += R[(size_t)m * NN + n];
                if (Cf) Cf[(size_t)m * NN + n] = v;
                if (Cb) Cb[(size_t)m * NN + n] = f2b(v);
            }
        }
    }
}

// ---------------------------------------------------------------------------
// fp32 -> bf16 convert
// ---------------------------------------------------------------------------
__global__ __launch_bounds__(256) void conv_b(
    const float* __restrict__ X, unsigned short* __restrict__ Y)
{
    const size_t i = ((size_t)blockIdx.x * 256 + threadIdx.x) * 8;
    float4 a = *(const float4*)(X + i);
    float4 b = *(const float4*)(X + i + 4);
    ushort8 o;
    o[0] = f2b(a.x); o[1] = f2b(a.y); o[2] = f2b(a.z); o[3] = f2b(a.w);
    o[4] = f2b(b.x); o[5] = f2b(b.y); o[6] = f2b(b.z); o[7] = f2b(b.w);
    *(ushort8*)(Y + i) = o;
}

// ---------------------------------------------------------------------------
// ALL weight transposes fused: 1600 tiles of 64x64, [K,N] fp32 -> [N,K] bf16
// ---------------------------------------------------------------------------
__global__ __launch_bounds__(256) void wtrans_all(
    const float* __restrict__ Wk, const float* __restrict__ Wv,
    const float* __restrict__ Wo, const float* __restrict__ W1,
    const float* __restrict__ W2, unsigned short* __restrict__ dst)
{
    const int bid = blockIdx.x;
    const float* src; unsigned short* d; int K, N, tk, tn;
    if (bid < 576) {
        const int mat = bid >> 6, tile = bid & 63;
        const int l = mat / 3, wch = mat % 3;
        const float* W = (wch == 0) ? Wk : (wch == 1) ? Wv : Wo;
        src = W + (size_t)l * 262144;
        d = dst + (size_t)mat * 262144;
        K = 512; N = 512; tn = tile & 7; tk = tile >> 3;
    } else if (bid < 1088) {
        const int idx = bid - 576, l2 = idx >> 8, tile = idx & 255;
        src = W1 + (size_t)(l2 * 2) * (512 * 2048);
        d = dst + 9 * 262144 + (size_t)l2 * (512 * 2048);
        K = 512; N = 2048; tn = tile & 31; tk = tile >> 5;
    } else {
        const int idx = bid - 1088, l2 = idx >> 8, tile = idx & 255;
        src = W2 + (size_t)(l2 * 2) * (2048 * 512);
        d = dst + 9 * 262144 + 2 * (512 * 2048) + (size_t)l2 * (2048 * 512);
        K = 2048; N = 512; tn = tile & 7; tk = tile >> 3;
    }
    const int n0 = tn * 64, k0 = tk * 64;
    __shared__ float T[64][65];
    const int t = threadIdx.x;
    const int kl = t >> 4, n4 = (t & 15) << 2;
#pragma unroll
    for (int it = 0; it < 4; ++it) {
        const int k = kl + it * 16;
        float4 v = *(const float4*)(src + (size_t)(k0 + k) * N + n0 + n4);
        T[n4 + 0][k] = v.x; T[n4 + 1][k] = v.y;
        T[n4 + 2][k] = v.z; T[n4 + 3][k] = v.w;
    }
    __syncthreads();
    const int nl = t >> 3, k8 = (t & 7) << 3;
#pragma unroll
    for (int it = 0; it < 2; ++it) {
        const int n = nl + it * 32;
        ushort8 o;
#pragma unroll
        for (int c = 0; c < 8; ++c) o[c] = f2b(T[n][k8 + c]);
        *(ushort8*)(d + (size_t)(n0 + n) * K + k0 + k8) = o;
    }
}

// ---------------------------------------------------------------------------
// Flash-style monotonic attention v5. Wave-pair j-split (v3) + COMPLEMENTARY
// TILE PAIRING: pair 0 handles 16-row q-tile qt, pair 1 handles tile 31-qt,
// so per-block work is max(qt+1, 32-qt) in [17,32] (1.9:1) instead of
// proportional to qt (16:1). The heavy-tail blocks that serialized the
// kernel's last phase are gone. Natural block mapping + (bx+h+b)&15 mixing
// keeps per-CU resident work uniform (v4's XCD remap correlated co-resident
// work -> 60% regression; reverted).
// Fully-masked row (mask0, i==0): uniform 1/512 over ALL j.
// ---------------------------------------------------------------------------
__global__ __launch_bounds__(256, 8) void attn_flash5(
    const unsigned short* __restrict__ Kb,   // [B*S, D] bf16 (Q == K)
    const unsigned short* __restrict__ Vt,   // [B,H,DK,S] bf16
    const float* __restrict__ gam,
    unsigned short* __restrict__ Ob,         // [B*S, D] bf16
    int mask_type)
{
    __shared__ float CTs[2][16 * 33];            // cross-tile strict suffix (per pair)
    __shared__ unsigned short Pst[4][16 * 36];   // P staging (A-frag layout, per wave)
    __shared__ float S1s[2][2][16];              // sum1 partials [pair][p][row]
    __shared__ float S2s[2][2][16];              // sum2 partials
    __shared__ float OaccS[2][16 * 66];          // oacc combine

    const int h = blockIdx.y, b = blockIdx.z;
    const int qt = (blockIdx.x + blockIdx.y + blockIdx.z) & 15;   // balance mix

    const int t = threadIdx.x, lane = t & 63, w = t >> 6;
    const int pair = w >> 1;                 // which 16-row q-subtile slot
    const int p = w & 1;                     // j-split parity within the pair
    const int quad = lane >> 4, fr = lane & 15;
    const int tile = pair ? (31 - qt) : qt;  // complementary tiles: balanced block
    const int q0 = tile * 16;
    const int iRow = q0 + fr;                // this lane's q row

    const unsigned short* kbase = Kb + (size_t)b * Sdim * Ddim + h * DKdim;

    // Q as B-operand: rows q0+fr
    frag16 aq0 = *(const frag16*)(kbase + (size_t)(q0 + fr) * Ddim + quad * 8);
    frag16 aq1 = *(const frag16*)(kbase + (size_t)(q0 + fr) * Ddim + 32 + quad * 8);

    float* CTw = CTs[pair];
    const int jnmax = (q0 + 15) >> 4;

    // ---- Pass 1: sum1 partials + per-tile totals into CT (tiles split by parity)
    float psum = 0.f;
    for (int jn = p; jn <= jnmax; jn += 2) {
        frag16 k0 = *(const frag16*)(kbase + (size_t)(jn * 16 + fr) * Ddim + quad * 8);
        frag16 k1 = *(const frag16*)(kbase + (size_t)(jn * 16 + fr) * Ddim + 32 + quad * 8);
        f32x4 z = {0.f, 0.f, 0.f, 0.f};
        z = __builtin_amdgcn_mfma_f32_16x16x32_bf16(k0, aq0, z, 0, 0, 0);
        z = __builtin_amdgcn_mfma_f32_16x16x32_bf16(k1, aq1, z, 0, 0, 0);
        const int jbase = jn * 16 + quad * 4;
        float tq = 0.f;
#pragma unroll
        for (int r = 0; r < 4; ++r) {
            const int j = jbase + r;
            const bool valid = mask_type ? (j <= iRow) : (j < iRow);
            tq += valid ? __expf(z[r] * 0.125f) : 0.f;
        }
        psum += tq;
        float tt = tq;
        tt += __shfl_xor(tt, 16);
        tt += __shfl_xor(tt, 32);
        if (quad == 0) CTw[fr * 33 + jn] = tt;
    }
    {
        float s1 = psum;
        s1 += __shfl_xor(s1, 16);
        s1 += __shfl_xor(s1, 32);
        if (lane < 16) S1s[pair][p][lane] = s1;
    }
    __syncthreads();

    // totals -> strict cross-tile suffix (p==0 wave of each pair; rows by lanes 0..15)
    if (p == 0 && lane < 16) {
        float run = 0.f;
        for (int jn = 31; jn >= 0; --jn) {
            const float tv = (jn <= jnmax) ? CTw[lane * 33 + jn] : 0.f;
            CTw[lane * 33 + jn] = run;
            run += tv;
        }
    }
    __syncthreads();

    const float rsum1 = 1.f / (S1s[pair][0][fr] + S1s[pair][1][fr]);  // inf iff fully masked
    const float gneg = -log1pf(__expf(gam[h]));   // -softplus(gamma)

    // ---- Pass 2: independent u-tiles split by parity, online PV
    unsigned short* Pw = Pst[w];
    const unsigned short* vtb = Vt + (size_t)(b * Hdim + h) * DKdim * Sdim;
    const bool fm_pair = (mask_type == 0) && (q0 == 0);
    const bool fmrow = (mask_type == 0) && (iRow == 0);
    const int umax = fm_pair ? (Sdim / 32 - 1) : ((q0 + 15) >> 5);
    float sum2p = 0.f;
    f32x4 oacc[4] = {};

    for (int u = umax - p; u >= 0; u -= 2) {
#pragma unroll
        for (int half = 0; half < 2; ++half) {
            const int jn = 2 * u + half;
            frag16 k0 = *(const frag16*)(kbase + (size_t)(jn * 16 + fr) * Ddim + quad * 8);
            frag16 k1 = *(const frag16*)(kbase + (size_t)(jn * 16 + fr) * Ddim + 32 + quad * 8);
            f32x4 z = {0.f, 0.f, 0.f, 0.f};
            z = __builtin_amdgcn_mfma_f32_16x16x32_bf16(k0, aq0, z, 0, 0, 0);
            z = __builtin_amdgcn_mfma_f32_16x16x32_bf16(k1, aq1, z, 0, 0, 0);
            const int jbase = jn * 16 + quad * 4;
            float s[4], e1[4], lsuf[4];
            float tq = 0.f;
#pragma unroll
            for (int r = 3; r >= 0; --r) {
                lsuf[r] = tq;                      // strict suffix within 4-run
                const int j = jbase + r;
                const bool valid = mask_type ? (j <= iRow) : (j < iRow);
                s[r] = z[r] * 0.125f;
                e1[r] = valid ? __expf(s[r]) : 0.f;
                tq += e1[r];
            }
            // strict suffix over quads (2 guarded shfl_down)
            float incl = tq;
            {
                float u1 = __shfl_down(incl, 16);
                incl += (quad < 3) ? u1 : 0.f;
                float u2 = __shfl_down(incl, 32);
                incl += (quad < 2) ? u2 : 0.f;
            }
            const float qsuf = incl - tq;
            const float ct = CTw[fr * 33 + jn];
            ushort4v pk;
#pragma unroll
            for (int r = 0; r < 4; ++r) {
                const int j = jbase + r;
                const bool valid = mask_type ? (j <= iRow) : (j < iRow);
                const float suf = ct + qsuf + lsuf[r];
                const float ratio = suf * rsum1;
                const int dd = iRow - j;
                const float pos = (float)(dd >= 0 ? dd : -dd);
                const float arg = (ratio > 0.f) ? ratio * pos : 0.f;   // NaN-safe
                const float te = fminf(fmaxf(__expf(gneg * sqrtf(arg)), 1e-5f), 1e5f);
                const float e2 = valid ? __expf(s[r] * te) : (fmrow ? 1.f : 0.f);
                sum2p += e2;
                pk[r] = f2b(e2);
            }
            *(ushort4v*)(Pw + fr * 36 + half * 16 + quad * 4) = pk;
        }
        // PV over this pair's 32-wide window (A = P from LDS, B = Vt)
        frag16 pf = *(const frag16*)(Pw + fr * 36 + quad * 8);
        const int jb = u * 32;
#pragma unroll
        for (int dt = 0; dt < 4; ++dt) {
            frag16 vf = *(const frag16*)(vtb + (size_t)(dt * 16 + fr) * Sdim + jb + quad * 8);
            oacc[dt] = __builtin_amdgcn_mfma_f32_16x16x32_bf16(pf, vf, oacc[dt], 0, 0, 0);
        }
    }

    // ---- combine the pair's partials
    {
        float s2 = sum2p;
        s2 += __shfl_xor(s2, 16);
        s2 += __shfl_xor(s2, 32);
        if (lane < 16) S2s[pair][p][lane] = s2;
    }
    if (p == 1) {
        float* Os = OaccS[pair];
#pragma unroll
        for (int dt = 0; dt < 4; ++dt)
#pragma unroll
            for (int r = 0; r < 4; ++r)
                Os[(quad * 4 + r) * 66 + dt * 16 + fr] = oacc[dt][r];
    }
    __syncthreads();

    if (p == 0) {
        const float* Os = OaccS[pair];
        const float rs2 = 1.f / (S2s[pair][0][fr] + S2s[pair][1][fr]);   // for row fr
        float rs2q[4];
#pragma unroll
        for (int r = 0; r < 4; ++r) rs2q[r] = __shfl(rs2, quad * 4 + r);

        // O rows q0+quad*4+r, cols dt*16+fr
        unsigned short* obase = Ob + ((size_t)(b * Sdim + q0)) * Ddim + h * DKdim;
#pragma unroll
        for (int dt = 0; dt < 4; ++dt)
#pragma unroll
            for (int r = 0; r < 4; ++r) {
                const float v = oacc[dt][r] + Os[(quad * 4 + r) * 66 + dt * 16 + fr];
                obase[(size_t)(quad * 4 + r) * Ddim + dt * 16 + fr] = f2b(v * rs2q[r]);
            }
    }
}

// ---------------------------------------------------------------------------
// LayerNorm over last dim (512); fp32 out (nullable) + bf16 out (nullable).
// ---------------------------------------------------------------------------
__global__ __launch_bounds__(256) void ln_kernel(
    const float* __restrict__ X, const float* __restrict__ g,
    const float* __restrict__ bta, float* __restrict__ Y,
    unsigned short* __restrict__ Yb)
{
    const int row = blockIdx.x;
    const int t = threadIdx.x;
    __shared__ float r1[256], r2[256];
    const float* x = X + (size_t)row * Ddim;
    float a = x[t], b = x[t + 256];
    r1[t] = a + b;
    r2[t] = a * a + b * b;
    __syncthreads();
    for (int off = 128; off; off >>= 1) {
        if (t < off) { r1[t] += r1[t + off]; r2[t] += r2[t + off]; }
        __syncthreads();
    }
    float mean = r1[0] * (1.f / Ddim);
    float var = r2[0] * (1.f / Ddim) - mean * mean;
    float rs = rsqrtf(var + 1e-5f);
    float y0 = (a - mean) * rs * g[t] + bta[t];
    float y1 = (b - mean) * rs * g[t + 256] + bta[t + 256];
    if (Y) {
        float* y = Y + (size_t)row * Ddim;
        y[t] = y0;
        y[t + 256] = y1;
    }
    if (Yb) {
        unsigned short* yb = Yb + (size_t)row * Ddim;
        yb[t] = f2b(y0);
        yb[t + 256] = f2b(y1);
    }
}

// ---------------------------------------------------------------------------
extern "C" void kernel_launch(void* const* d_in, const int* in_sizes, int n_in,
                              void* d_out, int out_size, void* d_ws, size_t ws_size,
                              hipStream_t stream)
{
    const float* x0     = (const float*)d_in[0];
    const float* y0     = (const float*)d_in[1];
    const float* Wk     = (const float*)d_in[2];
    const float* bk     = (const float*)d_in[3];
    const float* Wv     = (const float*)d_in[4];
    const float* bv     = (const float*)d_in[5];
    const float* Wo     = (const float*)d_in[6];
    const float* bo     = (const float*)d_in[7];
    const float* gammas = (const float*)d_in[8];
    const float* ln1g   = (const float*)d_in[9];
    const float* ln1b   = (const float*)d_in[10];
    const float* W1     = (const float*)d_in[11];
    const float* b1     = (const float*)d_in[12];
    const float* W2     = (const float*)d_in[13];
    const float* b2     = (const float*)d_in[14];
    const float* ln2g   = (const float*)d_in[15];
    const float* ln2b   = (const float*)d_in[16];

    const size_t NBSD = (size_t)Mrows * Ddim;   // 4,194,304
    float* ws = (float*)d_ws;
    float* T1   = ws;
    float* X1   = T1 + NBSD;
    float* Xbuf = X1 + NBSD;
    unsigned short* Kbf = (unsigned short*)(Xbuf + NBSD);
    unsigned short* Vt  = Kbf + NBSD;
    unsigned short* AOb = Vt + NBSD;
    unsigned short* Abf = AOb + NBSD;
    unsigned short* Xbf = Abf + NBSD;
    unsigned short* Ybf = Xbf + NBSD;
    unsigned short* Hbb = Ybf + NBSD;                       // [M,F]
    unsigned short* WtAll = Hbb + (size_t)Mrows * Fdim;

    auto WtK = [&](int l) { return WtAll + (size_t)(l * 3 + 0) * 262144; };
    auto WtV = [&](int l) { return WtAll + (size_t)(l * 3 + 1) * 262144; };
    auto WtO = [&](int l) { return WtAll + (size_t)(l * 3 + 2) * 262144; };
    auto Wt1 = [&](int l) { return WtAll + 9 * 262144 + (size_t)(l >> 1) * (512 * 2048); };
    auto Wt2 = [&](int l) { return WtAll + 9 * 262144 + 2 * (512 * 2048) + (size_t)(l >> 1) * (2048 * 512); };

    const int convBlocks = (int)(NBSD / 2048);

    wtrans_all<<<1600, 256, 0, stream>>>(Wk, Wv, Wo, W1, W2, WtAll);

    auto run_block = [&](int l, const float* qinf, const unsigned short* qinb,
                         const unsigned short* vinb, int mask_type, bool ffn,
                         float* outf, unsigned short* outb) {
        const float* bk_l = bk + (size_t)l * Ddim;
        const float* bv_l = bv + (size_t)l * Ddim;
        const float* bo_l = bo + (size_t)l * Ddim;

        // K (=Q) + V projections in one launch (z=0: K->Kbf, z=1: V->Vt)
        gemm_n64<<<dim3(8, 64, 2), 256, 0, stream>>>(
            qinb, vinb, WtK(l), WtV(l), bk_l, bv_l,
            nullptr, nullptr, Kbf, Vt, Ddim);
        // attention (flash-style streaming, balanced complementary tiles)
        attn_flash5<<<dim3(Sdim / 32, Hdim, Bdim), 256, 0, stream>>>(
            Kbf, Vt, gammas + (size_t)l * Hdim, AOb, mask_type);
        // O-projection + residual -> T1 (fp32); LN1
        gemm_n64<<<dim3(8, 64, 1), 256, 0, stream>>>(
            AOb, AOb, WtO(l), WtO(l), bo_l, bo_l,
            qinf, T1, nullptr, nullptr, Ddim);
        float* x1f = ffn ? X1 : outf;
        unsigned short* x1b = ffn ? Abf : outb;
        ln_kernel<<<Mrows, 256, 0, stream>>>(T1,
            ln1g + (size_t)l * Ddim, ln1b + (size_t)l * Ddim, x1f, x1b);
        if (ffn) {
            const float* b1_l = b1 + (size_t)l * Fdim;
            const float* b2_l = b2 + (size_t)l * Ddim;
            gemm_mfma<<<dim3(Fdim / 128, Mrows / 128), 256, 0, stream>>>(
                (const __hip_bfloat16*)Abf, (const __hip_bfloat16*)Wt1(l),
                b1_l, nullptr, nullptr, Hbb, Mrows, Fdim, Ddim, 1);
            gemm_n64<<<dim3(8, 64, 1), 256, 0, stream>>>(
                Hbb, Hbb, Wt2(l), Wt2(l), b2_l, b2_l,
                X1, T1, nullptr, nullptr, Fdim);
            ln_kernel<<<Mrows, 256, 0, stream>>>(T1,
                ln2g + (size_t)l * Ddim, ln2b + (size_t)l * Ddim, outf, outb);
        }
    };

    // Block 0: knowledge encoder (y), mask1, FFN -> Ybf (bf16 only)
    conv_b<<<convBlocks, 256, 0, stream>>>(y0, Abf);
    run_block(0, y0, Abf, Abf, 1, true, nullptr, Ybf);
    // Block 1: question encoder (x), mask1, no FFN -> Xbuf/Xbf
    conv_b<<<convBlocks, 256, 0, stream>>>(x0, Abf);
    run_block(1, x0, Abf, Abf, 1, false, Xbuf, Xbf);
    // Block 2: knowledge retriever, q/k=x, v=y, mask0, FFN -> d_out (fp32)
    run_block(2, Xbuf, Xbf, Ybf, 0, true, (float*)d_out, nullptr);
}

// Round 4
// 665.749 us; speedup vs baseline: 1.1426x; 1.0470x over previous
//
#include <hip/hip_runtime.h>
#include <hip/hip_bf16.h>

// Problem dims (fixed)
#define Bdim 16
#define Sdim 512
#define Ddim 512
#define Hdim 8
#define DKdim 64
#define Fdim 2048
#define Mrows (Bdim * Sdim)   // 8192

typedef __attribute__((ext_vector_type(8))) short  frag16;   // 8 bf16 (4 VGPRs)
typedef __attribute__((ext_vector_type(4))) float  f32x4;    // MFMA acc
typedef __attribute__((ext_vector_type(8))) unsigned short ushort8;
typedef __attribute__((ext_vector_type(4))) unsigned short ushort4v;

// round-to-nearest-even fp32 -> bf16 (finite data)
__device__ __forceinline__ unsigned short f2b(float x) {
    union { float f; unsigned int u; } v; v.f = x;
    unsigned int r = (v.u + 0x7FFFu + ((v.u >> 16) & 1u)) >> 16;
    return (unsigned short)r;
}

// ---------------------------------------------------------------------------
// bf16 MFMA GEMM, 128x128 tile (used for FFN1, N=2048).
// XCD-chunked swizzle + 2-phase double-buffered K-loop.
// ---------------------------------------------------------------------------
__global__ __launch_bounds__(256) void gemm_mfma(
    const __hip_bfloat16* __restrict__ A, const __hip_bfloat16* __restrict__ Bt,
    const float* __restrict__ bias, const float* __restrict__ R,
    float* __restrict__ Cf, unsigned short* __restrict__ Cb,
    int M, int N, int K, int do_relu)
{
    __shared__ short As[2][128 * 32];
    __shared__ short Bs[2][128 * 32];

    const int t = threadIdx.x;
    const int lane = t & 63;
    const int wave = t >> 6;

    // XCD-aware chunked swizzle (grid size divisible by 8)
    const int gx = gridDim.x;
    const int nb = gx * gridDim.y;
    const int lid = blockIdx.x + gx * blockIdx.y;
    const int wid = (lid & 7) * (nb >> 3) + (lid >> 3);
    const int bm = (wid / gx) * 128;
    const int bn = (wid % gx) * 128;

    const int wm = (wave >> 1) * 64;
    const int wn = (wave & 1) * 64;

    f32x4 acc[4][4] = {};
    const int lrow = lane >> 2;
    const int lcol = (lane & 3) * 8;

    auto stage = [&](int k0, int buf) {
#pragma unroll
        for (int i = 0; i < 2; ++i) {
            const int chunk = wave * 2 + i;
            const int row = chunk * 16 + lrow;
            const __hip_bfloat16* ga = A + (size_t)(bm + row) * K + k0 + lcol;
            const __hip_bfloat16* gb = Bt + (size_t)(bn + row) * K + k0 + lcol;
            __builtin_amdgcn_global_load_lds(
                (const __attribute__((address_space(1))) unsigned int*)ga,
                (__attribute__((address_space(3))) unsigned int*)(&As[buf][chunk * 512]),
                16, 0, 0);
            __builtin_amdgcn_global_load_lds(
                (const __attribute__((address_space(1))) unsigned int*)gb,
                (__attribute__((address_space(3))) unsigned int*)(&Bs[buf][chunk * 512]),
                16, 0, 0);
        }
    };

    const int fr = lane & 15;
    const int quad = lane >> 4;
    const int nk = K >> 5;

    stage(0, 0);
    __syncthreads();

    for (int it = 0; it < nk; ++it) {
        const int buf = it & 1;
        if (it + 1 < nk) stage((it + 1) << 5, buf ^ 1);
        frag16 af[4], bfr[4];
#pragma unroll
        for (int i = 0; i < 4; ++i) {
            af[i]  = *(const frag16*)(&As[buf][(wm + i * 16 + fr) * 32 + quad * 8]);
            bfr[i] = *(const frag16*)(&Bs[buf][(wn + i * 16 + fr) * 32 + quad * 8]);
        }
#pragma unroll
        for (int mi = 0; mi < 4; ++mi)
#pragma unroll
            for (int ni = 0; ni < 4; ++ni)
                acc[mi][ni] = __builtin_amdgcn_mfma_f32_16x16x32_bf16(
                    af[mi], bfr[ni], acc[mi][ni], 0, 0, 0);
        __syncthreads();
    }

#pragma unroll
    for (int mi = 0; mi < 4; ++mi) {
#pragma unroll
        for (int r = 0; r < 4; ++r) {
            const int m = bm + wm + mi * 16 + quad * 4 + r;
#pragma unroll
            for (int ni = 0; ni < 4; ++ni) {
                const int n = bn + wn + ni * 16 + fr;
                float v = acc[mi][ni][r] + bias[n];
                if (R) v += R[(size_t)m * N + n];
                if (do_relu) v = fmaxf(v, 0.f);
                if (Cf) Cf[(size_t)m * N + n] = v;
                if (Cb) Cb[(size_t)m * N + n] = f2b(v);
            }
        }
    }
}

// ---------------------------------------------------------------------------
// bf16 MFMA GEMM, 128x64 tile, N=512 fixed. Dual-mode via blockIdx.z:
// z=0: A0@B0^T+bias0 -> Cb (normal bf16) / Cf(+R) fp32
// z=1: A1@B1^T+bias1 -> CbT transposed Vt[b,h,d,s] bf16
// XCD-chunked swizzle + 2-phase double-buffered K-loop.
// ---------------------------------------------------------------------------
__global__ __launch_bounds__(256) void gemm_n64(
    const unsigned short* __restrict__ A0, const unsigned short* __restrict__ A1,
    const unsigned short* __restrict__ B0, const unsigned short* __restrict__ B1,
    const float* __restrict__ bias0, const float* __restrict__ bias1,
    const float* __restrict__ R, float* __restrict__ Cf,
    unsigned short* __restrict__ Cb, unsigned short* __restrict__ CbT,
    int K)
{
    const int NN = 512;
    __shared__ short As[2][128 * 32];
    __shared__ short Bs[2][64 * 32];

    const int trans = blockIdx.z;
    const unsigned short* A  = trans ? A1 : A0;
    const unsigned short* Bt = trans ? B1 : B0;
    const float* bias        = trans ? bias1 : bias0;

    const int t = threadIdx.x;
    const int lane = t & 63;
    const int wave = t >> 6;

    // XCD-aware chunked swizzle within each z-slice (512 % 8 == 0 so the
    // z offset preserves the XCD residue).
    const int lid = blockIdx.x + 8 * blockIdx.y;          // 0..511
    const int wid = (lid & 7) * 64 + (lid >> 3);
    const int bm = (wid >> 3) * 128;
    const int bn = (wid & 7) * 64;

    const int wm = (wave >> 1) * 64;
    const int wn = (wave & 1) * 32;

    f32x4 acc[4][2] = {};
    const int lrow = lane >> 2;
    const int lcol = (lane & 3) * 8;

    auto stage = [&](int k0, int buf) {
#pragma unroll
        for (int i = 0; i < 2; ++i) {
            const int chunk = wave * 2 + i;
            const int row = chunk * 16 + lrow;
            const unsigned short* ga = A + (size_t)(bm + row) * K + k0 + lcol;
            __builtin_amdgcn_global_load_lds(
                (const __attribute__((address_space(1))) unsigned int*)ga,
                (__attribute__((address_space(3))) unsigned int*)(&As[buf][chunk * 512]),
                16, 0, 0);
        }
        {
            const int row = wave * 16 + lrow;
            const unsigned short* gb = Bt + (size_t)(bn + row) * K + k0 + lcol;
            __builtin_amdgcn_global_load_lds(
                (const __attribute__((address_space(1))) unsigned int*)gb,
                (__attribute__((address_space(3))) unsigned int*)(&Bs[buf][wave * 512]),
                16, 0, 0);
        }
    };

    const int fr = lane & 15;
    const int quad = lane >> 4;
    const int nk = K >> 5;

    stage(0, 0);
    __syncthreads();

    for (int it = 0; it < nk; ++it) {
        const int buf = it & 1;
        if (it + 1 < nk) stage((it + 1) << 5, buf ^ 1);
        frag16 af[4], bfr[2];
#pragma unroll
        for (int i = 0; i < 4; ++i)
            af[i] = *(const frag16*)(&As[buf][(wm + i * 16 + fr) * 32 + quad * 8]);
#pragma unroll
        for (int i = 0; i < 2; ++i)
            bfr[i] = *(const frag16*)(&Bs[buf][(wn + i * 16 + fr) * 32 + quad * 8]);
#pragma unroll
        for (int mi = 0; mi < 4; ++mi)
#pragma unroll
            for (int ni = 0; ni < 2; ++ni)
                acc[mi][ni] = __builtin_amdgcn_mfma_f32_16x16x32_bf16(
                    af[mi], bfr[ni], acc[mi][ni], 0, 0, 0);
        __syncthreads();
    }

    if (trans) {
#pragma unroll
        for (int mi = 0; mi < 4; ++mi)
#pragma unroll
            for (int ni = 0; ni < 2; ++ni) {
                const int m = bm + wm + mi * 16 + quad * 4;
                const int n = bn + wn + ni * 16 + fr;
                ushort4v o;
#pragma unroll
                for (int r = 0; r < 4; ++r) o[r] = f2b(acc[mi][ni][r] + bias[n]);
                const int bb = m >> 9, s = m & 511;
                const int hh = n >> 6, dd = n & 63;
                *(ushort4v*)(CbT + (((size_t)((bb * Hdim + hh) * DKdim + dd)) << 9) + s) = o;
            }
        return;
    }

#pragma unroll
    for (int mi = 0; mi < 4; ++mi) {
#pragma unroll
        for (int r = 0; r < 4; ++r) {
            const int m = bm + wm + mi * 16 + quad * 4 + r;
#pragma unroll
            for (int ni = 0; ni < 2; ++ni) {
                const int n = bn + wn + ni * 16 + fr;
                float v = acc[mi][ni][r] + bias[n];
                if (R) v += R[(size_t)m * NN + n];
                if (Cf) Cf[(size_t)m * NN + n] = v;
                if (Cb) Cb[(size_t)m * NN + n] = f2b(v);
            }
        }
    }
}

// ---------------------------------------------------------------------------
// fp32 -> bf16 convert
// ---------------------------------------------------------------------------
__global__ __launch_bounds__(256) void conv_b(
    const float* __restrict__ X, unsigned short* __restrict__ Y)
{
    const size_t i = ((size_t)blockIdx.x * 256 + threadIdx.x) * 8;
    float4 a = *(const float4*)(X + i);
    float4 b = *(const float4*)(X + i + 4);
    ushort8 o;
    o[0] = f2b(a.x); o[1] = f2b(a.y); o[2] = f2b(a.z); o[3] = f2b(a.w);
    o[4] = f2b(b.x); o[5] = f2b(b.y); o[6] = f2b(b.z); o[7] = f2b(b.w);
    *(ushort8*)(Y + i) = o;
}

// ---------------------------------------------------------------------------
// ALL weight transposes fused: 1600 tiles of 64x64, [K,N] fp32 -> [N,K] bf16
// ---------------------------------------------------------------------------
__global__ __launch_bounds__(256) void wtrans_all(
    const float* __restrict__ Wk, const float* __restrict__ Wv,
    const float* __restrict__ Wo, const float* __restrict__ W1,
    const float* __restrict__ W2, unsigned short* __restrict__ dst)
{
    const int bid = blockIdx.x;
    const float* src; unsigned short* d; int K, N, tk, tn;
    if (bid < 576) {
        const int mat = bid >> 6, tile = bid & 63;
        const int l = mat / 3, wch = mat % 3;
        const float* W = (wch == 0) ? Wk : (wch == 1) ? Wv : Wo;
        src = W + (size_t)l * 262144;
        d = dst + (size_t)mat * 262144;
        K = 512; N = 512; tn = tile & 7; tk = tile >> 3;
    } else if (bid < 1088) {
        const int idx = bid - 576, l2 = idx >> 8, tile = idx & 255;
        src = W1 + (size_t)(l2 * 2) * (512 * 2048);
        d = dst + 9 * 262144 + (size_t)l2 * (512 * 2048);
        K = 512; N = 2048; tn = tile & 31; tk = tile >> 5;
    } else {
        const int idx = bid - 1088, l2 = idx >> 8, tile = idx & 255;
        src = W2 + (size_t)(l2 * 2) * (2048 * 512);
        d = dst + 9 * 262144 + 2 * (512 * 2048) + (size_t)l2 * (2048 * 512);
        K = 2048; N = 512; tn = tile & 7; tk = tile >> 3;
    }
    const int n0 = tn * 64, k0 = tk * 64;
    __shared__ float T[64][65];
    const int t = threadIdx.x;
    const int kl = t >> 4, n4 = (t & 15) << 2;
#pragma unroll
    for (int it = 0; it < 4; ++it) {
        const int k = kl + it * 16;
        float4 v = *(const float4*)(src + (size_t)(k0 + k) * N + n0 + n4);
        T[n4 + 0][k] = v.x; T[n4 + 1][k] = v.y;
        T[n4 + 2][k] = v.z; T[n4 + 3][k] = v.w;
    }
    __syncthreads();
    const int nl = t >> 3, k8 = (t & 7) << 3;
#pragma unroll
    for (int it = 0; it < 2; ++it) {
        const int n = nl + it * 32;
        ushort8 o;
#pragma unroll
        for (int c = 0; c < 8; ++c) o[c] = f2b(T[n][k8 + c]);
        *(ushort8*)(d + (size_t)(n0 + n) * K + k0 + k8) = o;
    }
}

// ---------------------------------------------------------------------------
// Flash-style monotonic attention v6. ONE 16-row q-tile per 128-thread block
// (2 waves, j-parity split — v3's proven symmetric intra-block structure,
// both waves stream the SAME j-sequence => L1 reuse, equal work => no
// barrier-wait imbalance). 4096 blocks of 2 waves = full 32-wave/CU
// residency with fine drain granularity. tile = (bx + h + 2*b) & 31 makes
// each CU's co-resident tile set a stride-2 spread (sum-balanced; the 2*b
// is what avoids consecutive-tile clustering under round-robin residency).
// Fully-masked row (mask0, i==0): uniform 1/512 over ALL j.
// ---------------------------------------------------------------------------
__global__ __launch_bounds__(128, 16) void attn_flash6(
    const unsigned short* __restrict__ Kb,   // [B*S, D] bf16 (Q == K)
    const unsigned short* __restrict__ Vt,   // [B,H,DK,S] bf16
    const float* __restrict__ gam,
    unsigned short* __restrict__ Ob,         // [B*S, D] bf16
    int mask_type)
{
    __shared__ float CTw[16 * 33];               // cross-tile strict suffix
    __shared__ unsigned short Pst[2][16 * 36];   // P staging (A-frag layout, per wave)
    __shared__ float S1s[2][16];                 // sum1 partials [p][row]
    __shared__ float S2s[2][16];                 // sum2 partials
    __shared__ float OaccS[16 * 66];             // oacc combine

    const int h = blockIdx.y, b = blockIdx.z;
    const int tile = (blockIdx.x + blockIdx.y + 2 * blockIdx.z) & 31;

    const int t = threadIdx.x, lane = t & 63, p = t >> 6;  // p: j-split parity
    const int quad = lane >> 4, fr = lane & 15;
    const int q0 = tile * 16;
    const int iRow = q0 + fr;                // this lane's q row

    const unsigned short* kbase = Kb + (size_t)b * Sdim * Ddim + h * DKdim;

    // Q as B-operand: rows q0+fr
    frag16 aq0 = *(const frag16*)(kbase + (size_t)(q0 + fr) * Ddim + quad * 8);
    frag16 aq1 = *(const frag16*)(kbase + (size_t)(q0 + fr) * Ddim + 32 + quad * 8);

    const int jnmax = tile;                  // (q0+15)>>4

    // ---- Pass 1: sum1 partials + per-tile totals into CT (tiles split by parity)
    float psum = 0.f;
    for (int jn = p; jn <= jnmax; jn += 2) {
        frag16 k0 = *(const frag16*)(kbase + (size_t)(jn * 16 + fr) * Ddim + quad * 8);
        frag16 k1 = *(const frag16*)(kbase + (size_t)(jn * 16 + fr) * Ddim + 32 + quad * 8);
        f32x4 z = {0.f, 0.f, 0.f, 0.f};
        z = __builtin_amdgcn_mfma_f32_16x16x32_bf16(k0, aq0, z, 0, 0, 0);
        z = __builtin_amdgcn_mfma_f32_16x16x32_bf16(k1, aq1, z, 0, 0, 0);
        const int jbase = jn * 16 + quad * 4;
        float tq = 0.f;
#pragma unroll
        for (int r = 0; r < 4; ++r) {
            const int j = jbase + r;
            const bool valid = mask_type ? (j <= iRow) : (j < iRow);
            tq += valid ? __expf(z[r] * 0.125f) : 0.f;
        }
        psum += tq;
        float tt = tq;
        tt += __shfl_xor(tt, 16);
        tt += __shfl_xor(tt, 32);
        if (quad == 0) CTw[fr * 33 + jn] = tt;
    }
    {
        float s1 = psum;
        s1 += __shfl_xor(s1, 16);
        s1 += __shfl_xor(s1, 32);
        if (lane < 16) S1s[p][lane] = s1;
    }
    __syncthreads();

    // totals -> strict cross-tile suffix (p==0 wave; rows by lanes 0..15)
    if (p == 0 && lane < 16) {
        float run = 0.f;
        for (int jn = 31; jn >= 0; --jn) {
            const float tv = (jn <= jnmax) ? CTw[lane * 33 + jn] : 0.f;
            CTw[lane * 33 + jn] = run;
            run += tv;
        }
    }
    __syncthreads();

    const float rsum1 = 1.f / (S1s[0][fr] + S1s[1][fr]);  // inf iff fully masked
    const float gneg = -log1pf(__expf(gam[h]));   // -softplus(gamma)

    // ---- Pass 2: independent u-tiles split by parity, online PV
    unsigned short* Pw = Pst[p];
    const unsigned short* vtb = Vt + (size_t)(b * Hdim + h) * DKdim * Sdim;
    const bool fm_blk = (mask_type == 0) && (q0 == 0);
    const bool fmrow = (mask_type == 0) && (iRow == 0);
    const int umax = fm_blk ? (Sdim / 32 - 1) : (tile >> 1);
    float sum2p = 0.f;
    f32x4 oacc[4] = {};

    for (int u = umax - p; u >= 0; u -= 2) {
#pragma unroll
        for (int half = 0; half < 2; ++half) {
            const int jn = 2 * u + half;
            frag16 k0 = *(const frag16*)(kbase + (size_t)(jn * 16 + fr) * Ddim + quad * 8);
            frag16 k1 = *(const frag16*)(kbase + (size_t)(jn * 16 + fr) * Ddim + 32 + quad * 8);
            f32x4 z = {0.f, 0.f, 0.f, 0.f};
            z = __builtin_amdgcn_mfma_f32_16x16x32_bf16(k0, aq0, z, 0, 0, 0);
            z = __builtin_amdgcn_mfma_f32_16x16x32_bf16(k1, aq1, z, 0, 0, 0);
            const int jbase = jn * 16 + quad * 4;
            float s[4], e1[4], lsuf[4];
            float tq = 0.f;
#pragma unroll
            for (int r = 3; r >= 0; --r) {
                lsuf[r] = tq;                      // strict suffix within 4-run
                const int j = jbase + r;
                const bool valid = mask_type ? (j <= iRow) : (j < iRow);
                s[r] = z[r] * 0.125f;
                e1[r] = valid ? __expf(s[r]) : 0.f;
                tq += e1[r];
            }
            // strict suffix over quads (2 guarded shfl_down)
            float incl = tq;
            {
                float u1 = __shfl_down(incl, 16);
                incl += (quad < 3) ? u1 : 0.f;
                float u2 = __shfl_down(incl, 32);
                incl += (quad < 2) ? u2 : 0.f;
            }
            const float qsuf = incl - tq;
            const float ct = CTw[fr * 33 + jn];
            ushort4v pk;
#pragma unroll
            for (int r = 0; r < 4; ++r) {
                const int j = jbase + r;
                const bool valid = mask_type ? (j <= iRow) : (j < iRow);
                const float suf = ct + qsuf + lsuf[r];
                const float ratio = suf * rsum1;
                const int dd = iRow - j;
                const float pos = (float)(dd >= 0 ? dd : -dd);
                const float arg = (ratio > 0.f) ? ratio * pos : 0.f;   // NaN-safe
                const float te = fminf(fmaxf(__expf(gneg * sqrtf(arg)), 1e-5f), 1e5f);
                const float e2 = valid ? __expf(s[r] * te) : (fmrow ? 1.f : 0.f);
                sum2p += e2;
                pk[r] = f2b(e2);
            }
            *(ushort4v*)(Pw + fr * 36 + half * 16 + quad * 4) = pk;
        }
        // PV over this pair's 32-wide window (A = P from LDS, B = Vt)
        frag16 pf = *(const frag16*)(Pw + fr * 36 + quad * 8);
        const int jb = u * 32;
#pragma unroll
        for (int dt = 0; dt < 4; ++dt) {
            frag16 vf = *(const frag16*)(vtb + (size_t)(dt * 16 + fr) * Sdim + jb + quad * 8);
            oacc[dt] = __builtin_amdgcn_mfma_f32_16x16x32_bf16(pf, vf, oacc[dt], 0, 0, 0);
        }
    }

    // ---- combine the two waves' partials
    {
        float s2 = sum2p;
        s2 += __shfl_xor(s2, 16);
        s2 += __shfl_xor(s2, 32);
        if (lane < 16) S2s[p][lane] = s2;
    }
    if (p == 1) {
#pragma unroll
        for (int dt = 0; dt < 4; ++dt)
#pragma unroll
            for (int r = 0; r < 4; ++r)
                OaccS[(quad * 4 + r) * 66 + dt * 16 + fr] = oacc[dt][r];
    }
    __syncthreads();

    if (p == 0) {
        const float rs2 = 1.f / (S2s[0][fr] + S2s[1][fr]);   // for row fr
        float rs2q[4];
#pragma unroll
        for (int r = 0; r < 4; ++r) rs2q[r] = __shfl(rs2, quad * 4 + r);

        // O rows q0+quad*4+r, cols dt*16+fr
        unsigned short* obase = Ob + ((size_t)(b * Sdim + q0)) * Ddim + h * DKdim;
#pragma unroll
        for (int dt = 0; dt < 4; ++dt)
#pragma unroll
            for (int r = 0; r < 4; ++r) {
                const float v = oacc[dt][r] + OaccS[(quad * 4 + r) * 66 + dt * 16 + fr];
                obase[(size_t)(quad * 4 + r) * Ddim + dt * 16 + fr] = f2b(v * rs2q[r]);
            }
    }
}

// ---------------------------------------------------------------------------
// LayerNorm over last dim (512); fp32 out (nullable) + bf16 out (nullable).
// ---------------------------------------------------------------------------
__global__ __launch_bounds__(256) void ln_kernel(
    const float* __restrict__ X, const float* __restrict__ g,
    const float* __restrict__ bta, float* __restrict__ Y,
    unsigned short* __restrict__ Yb)
{
    const int row = blockIdx.x;
    const int t = threadIdx.x;
    __shared__ float r1[256], r2[256];
    const float* x = X + (size_t)row * Ddim;
    float a = x[t], b = x[t + 256];
    r1[t] = a + b;
    r2[t] = a * a + b * b;
    __syncthreads();
    for (int off = 128; off; off >>= 1) {
        if (t < off) { r1[t] += r1[t + off]; r2[t] += r2[t + off]; }
        __syncthreads();
    }
    float mean = r1[0] * (1.f / Ddim);
    float var = r2[0] * (1.f / Ddim) - mean * mean;
    float rs = rsqrtf(var + 1e-5f);
    float y0 = (a - mean) * rs * g[t] + bta[t];
    float y1 = (b - mean) * rs * g[t + 256] + bta[t + 256];
    if (Y) {
        float* y = Y + (size_t)row * Ddim;
        y[t] = y0;
        y[t + 256] = y1;
    }
    if (Yb) {
        unsigned short* yb = Yb + (size_t)row * Ddim;
        yb[t] = f2b(y0);
        yb[t + 256] = f2b(y1);
    }
}

// ---------------------------------------------------------------------------
extern "C" void kernel_launch(void* const* d_in, const int* in_sizes, int n_in,
                              void* d_out, int out_size, void* d_ws, size_t ws_size,
                              hipStream_t stream)
{
    const float* x0     = (const float*)d_in[0];
    const float* y0     = (const float*)d_in[1];
    const float* Wk     = (const float*)d_in[2];
    const float* bk     = (const float*)d_in[3];
    const float* Wv     = (const float*)d_in[4];
    const float* bv     = (const float*)d_in[5];
    const float* Wo     = (const float*)d_in[6];
    const float* bo     = (const float*)d_in[7];
    const float* gammas = (const float*)d_in[8];
    const float* ln1g   = (const float*)d_in[9];
    const float* ln1b   = (const float*)d_in[10];
    const float* W1     = (const float*)d_in[11];
    const float* b1     = (const float*)d_in[12];
    const float* W2     = (const float*)d_in[13];
    const float* b2     = (const float*)d_in[14];
    const float* ln2g   = (const float*)d_in[15];
    const float* ln2b   = (const float*)d_in[16];

    const size_t NBSD = (size_t)Mrows * Ddim;   // 4,194,304
    float* ws = (float*)d_ws;
    float* T1   = ws;
    float* X1   = T1 + NBSD;
    float* Xbuf = X1 + NBSD;
    unsigned short* Kbf = (unsigned short*)(Xbuf + NBSD);
    unsigned short* Vt  = Kbf + NBSD;
    unsigned short* AOb = Vt + NBSD;
    unsigned short* Abf = AOb + NBSD;
    unsigned short* Xbf = Abf + NBSD;
    unsigned short* Ybf = Xbf + NBSD;
    unsigned short* Hbb = Ybf + NBSD;                       // [M,F]
    unsigned short* WtAll = Hbb + (size_t)Mrows * Fdim;

    auto WtK = [&](int l) { return WtAll + (size_t)(l * 3 + 0) * 262144; };
    auto WtV = [&](int l) { return WtAll + (size_t)(l * 3 + 1) * 262144; };
    auto WtO = [&](int l) { return WtAll + (size_t)(l * 3 + 2) * 262144; };
    auto Wt1 = [&](int l) { return WtAll + 9 * 262144 + (size_t)(l >> 1) * (512 * 2048); };
    auto Wt2 = [&](int l) { return WtAll + 9 * 262144 + 2 * (512 * 2048) + (size_t)(l >> 1) * (2048 * 512); };

    const int convBlocks = (int)(NBSD / 2048);

    wtrans_all<<<1600, 256, 0, stream>>>(Wk, Wv, Wo, W1, W2, WtAll);

    auto run_block = [&](int l, const float* qinf, const unsigned short* qinb,
                         const unsigned short* vinb, int mask_type, bool ffn,
                         float* outf, unsigned short* outb) {
        const float* bk_l = bk + (size_t)l * Ddim;
        const float* bv_l = bv + (size_t)l * Ddim;
        const float* bo_l = bo + (size_t)l * Ddim;

        // K (=Q) + V projections in one launch (z=0: K->Kbf, z=1: V->Vt)
        gemm_n64<<<dim3(8, 64, 2), 256, 0, stream>>>(
            qinb, vinb, WtK(l), WtV(l), bk_l, bv_l,
            nullptr, nullptr, Kbf, Vt, Ddim);
        // attention (flash-style streaming, 1 q-tile per 2-wave block)
        attn_flash6<<<dim3(Sdim / 16, Hdim, Bdim), 128, 0, stream>>>(
            Kbf, Vt, gammas + (size_t)l * Hdim, AOb, mask_type);
        // O-projection + residual -> T1 (fp32); LN1
        gemm_n64<<<dim3(8, 64, 1), 256, 0, stream>>>(
            AOb, AOb, WtO(l), WtO(l), bo_l, bo_l,
            qinf, T1, nullptr, nullptr, Ddim);
        float* x1f = ffn ? X1 : outf;
        unsigned short* x1b = ffn ? Abf : outb;
        ln_kernel<<<Mrows, 256, 0, stream>>>(T1,
            ln1g + (size_t)l * Ddim, ln1b + (size_t)l * Ddim, x1f, x1b);
        if (ffn) {
            const float* b1_l = b1 + (size_t)l * Fdim;
            const float* b2_l = b2 + (size_t)l * Ddim;
            gemm_mfma<<<dim3(Fdim / 128, Mrows / 128), 256, 0, stream>>>(
                (const __hip_bfloat16*)Abf, (const __hip_bfloat16*)Wt1(l),
                b1_l, nullptr, nullptr, Hbb, Mrows, Fdim, Ddim, 1);
            gemm_n64<<<dim3(8, 64, 1), 256, 0, stream>>>(
                Hbb, Hbb, Wt2(l), Wt2(l), b2_l, b2_l,
                X1, T1, nullptr, nullptr, Fdim);
            ln_kernel<<<Mrows, 256, 0, stream>>>(T1,
                ln2g + (size_t)l * Ddim, ln2b + (size_t)l * Ddim, outf, outb);
        }
    };

    // Block 0: knowledge encoder (y), mask1, FFN -> Ybf (bf16 only)
    conv_b<<<convBlocks, 256, 0, stream>>>(y0, Abf);
    run_block(0, y0, Abf, Abf, 1, true, nullptr, Ybf);
    // Block 1: question encoder (x), mask1, no FFN -> Xbuf/Xbf
    conv_b<<<convBlocks, 256, 0, stream>>>(x0, Abf);
    run_block(1, x0, Abf, Abf, 1, false, Xbuf, Xbf);
    // Block 2: knowledge retriever, q/k=x, v=y, mask0, FFN -> d_out (fp32)
    run_block(2, Xbuf, Xbf, Ybf, 0, true, (float*)d_out, nullptr);
}

// Round 5
// 646.374 us; speedup vs baseline: 1.1768x; 1.0300x over previous
//
#include <hip/hip_runtime.h>
#include <hip/hip_bf16.h>

// Problem dims (fixed)
#define Bdim 16
#define Sdim 512
#define Ddim 512
#define Hdim 8
#define DKdim 64
#define Fdim 2048
#define Mrows (Bdim * Sdim)   // 8192

typedef __attribute__((ext_vector_type(8))) short  frag16;   // 8 bf16 (4 VGPRs)
typedef __attribute__((ext_vector_type(4))) float  f32x4;    // MFMA acc
typedef __attribute__((ext_vector_type(8))) unsigned short ushort8;
typedef __attribute__((ext_vector_type(4))) unsigned short ushort4v;

// raw 2^x (v_exp_f32); fallback keeps semantics
#if defined(__has_builtin)
#  if __has_builtin(__builtin_amdgcn_exp2f)
#    define EXP2(x) __builtin_amdgcn_exp2f(x)
#  endif
#endif
#ifndef EXP2
#  define EXP2(x) __expf((x) * 0.6931471805599453f)
#endif
#define SC2 0.18033688011112042f   // 0.125 * log2(e)

// round-to-nearest-even fp32 -> bf16 (finite data)
__device__ __forceinline__ unsigned short f2b(float x) {
    union { float f; unsigned int u; } v; v.f = x;
    unsigned int r = (v.u + 0x7FFFu + ((v.u >> 16) & 1u)) >> 16;
    return (unsigned short)r;
}

// ---------------------------------------------------------------------------
// bf16 MFMA GEMM, 128x128 tile (used for FFN1, N=2048).
// XCD-chunked swizzle + 2-phase double-buffered K-loop.
// ---------------------------------------------------------------------------
__global__ __launch_bounds__(256) void gemm_mfma(
    const __hip_bfloat16* __restrict__ A, const __hip_bfloat16* __restrict__ Bt,
    const float* __restrict__ bias, const float* __restrict__ R,
    float* __restrict__ Cf, unsigned short* __restrict__ Cb,
    int M, int N, int K, int do_relu)
{
    __shared__ short As[2][128 * 32];
    __shared__ short Bs[2][128 * 32];

    const int t = threadIdx.x;
    const int lane = t & 63;
    const int wave = t >> 6;

    // XCD-aware chunked swizzle (grid size divisible by 8)
    const int gx = gridDim.x;
    const int nb = gx * gridDim.y;
    const int lid = blockIdx.x + gx * blockIdx.y;
    const int wid = (lid & 7) * (nb >> 3) + (lid >> 3);
    const int bm = (wid / gx) * 128;
    const int bn = (wid % gx) * 128;

    const int wm = (wave >> 1) * 64;
    const int wn = (wave & 1) * 64;

    f32x4 acc[4][4] = {};
    const int lrow = lane >> 2;
    const int lcol = (lane & 3) * 8;

    auto stage = [&](int k0, int buf) {
#pragma unroll
        for (int i = 0; i < 2; ++i) {
            const int chunk = wave * 2 + i;
            const int row = chunk * 16 + lrow;
            const __hip_bfloat16* ga = A + (size_t)(bm + row) * K + k0 + lcol;
            const __hip_bfloat16* gb = Bt + (size_t)(bn + row) * K + k0 + lcol;
            __builtin_amdgcn_global_load_lds(
                (const __attribute__((address_space(1))) unsigned int*)ga,
                (__attribute__((address_space(3))) unsigned int*)(&As[buf][chunk * 512]),
                16, 0, 0);
            __builtin_amdgcn_global_load_lds(
                (const __attribute__((address_space(1))) unsigned int*)gb,
                (__attribute__((address_space(3))) unsigned int*)(&Bs[buf][chunk * 512]),
                16, 0, 0);
        }
    };

    const int fr = lane & 15;
    const int quad = lane >> 4;
    const int nk = K >> 5;

    stage(0, 0);
    __syncthreads();

    for (int it = 0; it < nk; ++it) {
        const int buf = it & 1;
        if (it + 1 < nk) stage((it + 1) << 5, buf ^ 1);
        frag16 af[4], bfr[4];
#pragma unroll
        for (int i = 0; i < 4; ++i) {
            af[i]  = *(const frag16*)(&As[buf][(wm + i * 16 + fr) * 32 + quad * 8]);
            bfr[i] = *(const frag16*)(&Bs[buf][(wn + i * 16 + fr) * 32 + quad * 8]);
        }
#pragma unroll
        for (int mi = 0; mi < 4; ++mi)
#pragma unroll
            for (int ni = 0; ni < 4; ++ni)
                acc[mi][ni] = __builtin_amdgcn_mfma_f32_16x16x32_bf16(
                    af[mi], bfr[ni], acc[mi][ni], 0, 0, 0);
        __syncthreads();
    }

#pragma unroll
    for (int mi = 0; mi < 4; ++mi) {
#pragma unroll
        for (int r = 0; r < 4; ++r) {
            const int m = bm + wm + mi * 16 + quad * 4 + r;
#pragma unroll
            for (int ni = 0; ni < 4; ++ni) {
                const int n = bn + wn + ni * 16 + fr;
                float v = acc[mi][ni][r] + bias[n];
                if (R) v += R[(size_t)m * N + n];
                if (do_relu) v = fmaxf(v, 0.f);
                if (Cf) Cf[(size_t)m * N + n] = v;
                if (Cb) Cb[(size_t)m * N + n] = f2b(v);
            }
        }
    }
}

// ---------------------------------------------------------------------------
// bf16 MFMA GEMM, 128x64 tile, N=512 fixed. Dual-mode via blockIdx.z:
// z=0: A0@B0^T+bias0 -> Cb (normal bf16) / Cf(+R) fp32
// z=1: A1@B1^T+bias1 -> CbT transposed Vt[b,h,d,s] bf16
// XCD-chunked swizzle + 2-phase double-buffered K-loop.
// ---------------------------------------------------------------------------
__global__ __launch_bounds__(256) void gemm_n64(
    const unsigned short* __restrict__ A0, const unsigned short* __restrict__ A1,
    const unsigned short* __restrict__ B0, const unsigned short* __restrict__ B1,
    const float* __restrict__ bias0, const float* __restrict__ bias1,
    const float* __restrict__ R, float* __restrict__ Cf,
    unsigned short* __restrict__ Cb, unsigned short* __restrict__ CbT,
    int K)
{
    const int NN = 512;
    __shared__ short As[2][128 * 32];
    __shared__ short Bs[2][64 * 32];

    const int trans = blockIdx.z;
    const unsigned short* A  = trans ? A1 : A0;
    const unsigned short* Bt = trans ? B1 : B0;
    const float* bias        = trans ? bias1 : bias0;

    const int t = threadIdx.x;
    const int lane = t & 63;
    const int wave = t >> 6;

    // XCD-aware chunked swizzle within each z-slice (512 % 8 == 0 so the
    // z offset preserves the XCD residue).
    const int lid = blockIdx.x + 8 * blockIdx.y;          // 0..511
    const int wid = (lid & 7) * 64 + (lid >> 3);
    const int bm = (wid >> 3) * 128;
    const int bn = (wid & 7) * 64;

    const int wm = (wave >> 1) * 64;
    const int wn = (wave & 1) * 32;

    f32x4 acc[4][2] = {};
    const int lrow = lane >> 2;
    const int lcol = (lane & 3) * 8;

    auto stage = [&](int k0, int buf) {
#pragma unroll
        for (int i = 0; i < 2; ++i) {
            const int chunk = wave * 2 + i;
            const int row = chunk * 16 + lrow;
            const unsigned short* ga = A + (size_t)(bm + row) * K + k0 + lcol;
            __builtin_amdgcn_global_load_lds(
                (const __attribute__((address_space(1))) unsigned int*)ga,
                (__attribute__((address_space(3))) unsigned int*)(&As[buf][chunk * 512]),
                16, 0, 0);
        }
        {
            const int row = wave * 16 + lrow;
            const unsigned short* gb = Bt + (size_t)(bn + row) * K + k0 + lcol;
            __builtin_amdgcn_global_load_lds(
                (const __attribute__((address_space(1))) unsigned int*)gb,
                (__attribute__((address_space(3))) unsigned int*)(&Bs[buf][wave * 512]),
                16, 0, 0);
        }
    };

    const int fr = lane & 15;
    const int quad = lane >> 4;
    const int nk = K >> 5;

    stage(0, 0);
    __syncthreads();

    for (int it = 0; it < nk; ++it) {
        const int buf = it & 1;
        if (it + 1 < nk) stage((it + 1) << 5, buf ^ 1);
        frag16 af[4], bfr[2];
#pragma unroll
        for (int i = 0; i < 4; ++i)
            af[i] = *(const frag16*)(&As[buf][(wm + i * 16 + fr) * 32 + quad * 8]);
#pragma unroll
        for (int i = 0; i < 2; ++i)
            bfr[i] = *(const frag16*)(&Bs[buf][(wn + i * 16 + fr) * 32 + quad * 8]);
#pragma unroll
        for (int mi = 0; mi < 4; ++mi)
#pragma unroll
            for (int ni = 0; ni < 2; ++ni)
                acc[mi][ni] = __builtin_amdgcn_mfma_f32_16x16x32_bf16(
                    af[mi], bfr[ni], acc[mi][ni], 0, 0, 0);
        __syncthreads();
    }

    if (trans) {
#pragma unroll
        for (int mi = 0; mi < 4; ++mi)
#pragma unroll
            for (int ni = 0; ni < 2; ++ni) {
                const int m = bm + wm + mi * 16 + quad * 4;
                const int n = bn + wn + ni * 16 + fr;
                ushort4v o;
#pragma unroll
                for (int r = 0; r < 4; ++r) o[r] = f2b(acc[mi][ni][r] + bias[n]);
                const int bb = m >> 9, s = m & 511;
                const int hh = n >> 6, dd = n & 63;
                *(ushort4v*)(CbT + (((size_t)((bb * Hdim + hh) * DKdim + dd)) << 9) + s) = o;
            }
        return;
    }

#pragma unroll
    for (int mi = 0; mi < 4; ++mi) {
#pragma unroll
        for (int r = 0; r < 4; ++r) {
            const int m = bm + wm + mi * 16 + quad * 4 + r;
#pragma unroll
            for (int ni = 0; ni < 2; ++ni) {
                const int n = bn + wn + ni * 16 + fr;
                float v = acc[mi][ni][r] + bias[n];
                if (R) v += R[(size_t)m * NN + n];
                if (Cf) Cf[(size_t)m * NN + n] = v;
                if (Cb) Cb[(size_t)m * NN + n] = f2b(v);
            }
        }
    }
}

// ---------------------------------------------------------------------------
// fp32 -> bf16 convert
// ---------------------------------------------------------------------------
__global__ __launch_bounds__(256) void conv_b(
    const float* __restrict__ X, unsigned short* __restrict__ Y)
{
    const size_t i = ((size_t)blockIdx.x * 256 + threadIdx.x) * 8;
    float4 a = *(const float4*)(X + i);
    float4 b = *(const float4*)(X + i + 4);
    ushort8 o;
    o[0] = f2b(a.x); o[1] = f2b(a.y); o[2] = f2b(a.z); o[3] = f2b(a.w);
    o[4] = f2b(b.x); o[5] = f2b(b.y); o[6] = f2b(b.z); o[7] = f2b(b.w);
    *(ushort8*)(Y + i) = o;
}

// ---------------------------------------------------------------------------
// ALL weight transposes fused: 1600 tiles of 64x64, [K,N] fp32 -> [N,K] bf16
// ---------------------------------------------------------------------------
__global__ __launch_bounds__(256) void wtrans_all(
    const float* __restrict__ Wk, const float* __restrict__ Wv,
    const float* __restrict__ Wo, const float* __restrict__ W1,
    const float* __restrict__ W2, unsigned short* __restrict__ dst)
{
    const int bid = blockIdx.x;
    const float* src; unsigned short* d; int K, N, tk, tn;
    if (bid < 576) {
        const int mat = bid >> 6, tile = bid & 63;
        const int l = mat / 3, wch = mat % 3;
        const float* W = (wch == 0) ? Wk : (wch == 1) ? Wv : Wo;
        src = W + (size_t)l * 262144;
        d = dst + (size_t)mat * 262144;
        K = 512; N = 512; tn = tile & 7; tk = tile >> 3;
    } else if (bid < 1088) {
        const int idx = bid - 576, l2 = idx >> 8, tile = idx & 255;
        src = W1 + (size_t)(l2 * 2) * (512 * 2048);
        d = dst + 9 * 262144 + (size_t)l2 * (512 * 2048);
        K = 512; N = 2048; tn = tile & 31; tk = tile >> 5;
    } else {
        const int idx = bid - 1088, l2 = idx >> 8, tile = idx & 255;
        src = W2 + (size_t)(l2 * 2) * (2048 * 512);
        d = dst + 9 * 262144 + 2 * (512 * 2048) + (size_t)l2 * (2048 * 512);
        K = 2048; N = 512; tn = tile & 7; tk = tile >> 3;
    }
    const int n0 = tn * 64, k0 = tk * 64;
    __shared__ float T[64][65];
    const int t = threadIdx.x;
    const int kl = t >> 4, n4 = (t & 15) << 2;
#pragma unroll
    for (int it = 0; it < 4; ++it) {
        const int k = kl + it * 16;
        float4 v = *(const float4*)(src + (size_t)(k0 + k) * N + n0 + n4);
        T[n4 + 0][k] = v.x; T[n4 + 1][k] = v.y;
        T[n4 + 2][k] = v.z; T[n4 + 3][k] = v.w;
    }
    __syncthreads();
    const int nl = t >> 3, k8 = (t & 7) << 3;
#pragma unroll
    for (int it = 0; it < 2; ++it) {
        const int n = nl + it * 32;
        ushort8 o;
#pragma unroll
        for (int c = 0; c < 8; ++c) o[c] = f2b(T[n][k8 + c]);
        *(ushort8*)(d + (size_t)(n0 + n) * K + k0 + k8) = o;
    }
}

// ---------------------------------------------------------------------------
// Flash-style monotonic attention v7. EQUAL-WORK PAIR BLOCKS: each 2-wave
// block processes tiles bx and 31-bx SEQUENTIALLY (33 tile-units per block,
// identical for every block) -> flat residency, no drain tail (v6's 32%
// time-avg occupancy was the mean/max work ratio of its unbalanced blocks).
// Waves split j by parity within each tile (v3/v6 proven structure).
// VALU diet: wave-uniform tile specialization (full / diagonal / empty),
// exp2 with folded log2e, no redundant clamps, float-domain |pos|,
// cvt_pk bf16 packing. Empty-tile path also implements the mask0 row-0
// uniform-1/512 case (P=1 for row 0 across all j).
// ---------------------------------------------------------------------------
__global__ __launch_bounds__(128, 4) void attn_flash7(
    const unsigned short* __restrict__ Kb,   // [B*S, D] bf16 (Q == K)
    const unsigned short* __restrict__ Vt,   // [B,H,DK,S] bf16
    const float* __restrict__ gam,
    unsigned short* __restrict__ Ob,         // [B*S, D] bf16
    int mask_type)
{
    __shared__ float CTw[16 * 33];               // cross-tile strict suffix
    __shared__ unsigned short Pst[2][16 * 36];   // P staging (A-frag layout, per wave)
    __shared__ float S1s[2][16];                 // sum1 partials [p][row]
    __shared__ float S2s[2][16];                 // sum2 partials
    __shared__ float OaccS[16 * 66];             // oacc combine

    const int h = blockIdx.y, b = blockIdx.z;
    const int t = threadIdx.x, lane = t & 63, p = t >> 6;  // p: j-split parity
    const int quad = lane >> 4, fr = lane & 15;

    const unsigned short* kbase = Kb + (size_t)b * Sdim * Ddim + h * DKdim;
    const unsigned short* vtb = Vt + (size_t)(b * Hdim + h) * DKdim * Sdim;
    const float gneg2 = -log1pf(__expf(gam[h])) * 1.4426950408889634f;

    for (int half_t = 0; half_t < 2; ++half_t) {
        const int tile = half_t ? (31 - blockIdx.x) : blockIdx.x;
        const int q0 = tile * 16;
        const int iRow = q0 + fr;            // this lane's q row

        // Q as B-operand: rows q0+fr
        frag16 aq0 = *(const frag16*)(kbase + (size_t)(q0 + fr) * Ddim + quad * 8);
        frag16 aq1 = *(const frag16*)(kbase + (size_t)(q0 + fr) * Ddim + 32 + quad * 8);

        // ---- Pass 1: sum1 partials + per-tile totals into CT (parity split)
        float psum = 0.f;
        for (int jn = p; jn <= tile; jn += 2) {
            frag16 k0 = *(const frag16*)(kbase + (size_t)(jn * 16 + fr) * Ddim + quad * 8);
            frag16 k1 = *(const frag16*)(kbase + (size_t)(jn * 16 + fr) * Ddim + 32 + quad * 8);
            f32x4 z = {0.f, 0.f, 0.f, 0.f};
            z = __builtin_amdgcn_mfma_f32_16x16x32_bf16(k0, aq0, z, 0, 0, 0);
            z = __builtin_amdgcn_mfma_f32_16x16x32_bf16(k1, aq1, z, 0, 0, 0);
            float tq = 0.f;
            if (jn < tile) {                 // fully-valid tile (both masks)
#pragma unroll
                for (int r = 0; r < 4; ++r) tq += EXP2(z[r] * SC2);
            } else {                         // diagonal tile
#pragma unroll
                for (int r = 0; r < 4; ++r) {
                    const bool valid = mask_type ? (quad * 4 + r <= fr)
                                                 : (quad * 4 + r < fr);
                    tq += valid ? EXP2(z[r] * SC2) : 0.f;
                }
            }
            psum += tq;
            float tt = tq;
            tt += __shfl_xor(tt, 16);
            tt += __shfl_xor(tt, 32);
            if (quad == 0) CTw[fr * 33 + jn] = tt;
        }
        {
            float s1 = psum;
            s1 += __shfl_xor(s1, 16);
            s1 += __shfl_xor(s1, 32);
            if (lane < 16) S1s[p][lane] = s1;
        }
        __syncthreads();

        // totals -> strict cross-tile suffix (p==0 wave; rows by lanes 0..15)
        if (p == 0 && lane < 16) {
            float run = 0.f;
            for (int jn = tile; jn >= 0; --jn) {
                const float tv = CTw[lane * 33 + jn];
                CTw[lane * 33 + jn] = run;
                run += tv;
            }
        }
        __syncthreads();

        const float rsum1 = 1.f / (S1s[0][fr] + S1s[1][fr]);  // inf iff fully masked
        unsigned short* Pw = Pst[p];
        const bool fm_blk = (mask_type == 0) && (tile == 0);
        const bool fmrow = fm_blk && (fr == 0);
        const int umax = fm_blk ? (Sdim / 32 - 1) : (tile >> 1);
        float sum2p = 0.f;
        f32x4 oacc[4] = {};

        // ---- Pass 2: independent u-tiles split by parity, online PV
        for (int u = umax - p; u >= 0; u -= 2) {
#pragma unroll
            for (int half = 0; half < 2; ++half) {
                const int jn = 2 * u + half;
                uint2 pku;
                if (jn > tile) {
                    // empty tile: P=0, except mask0 row-0 uniform case (P=1)
                    const unsigned int pv = fmrow ? 0x3F803F80u : 0u;
                    pku.x = pv; pku.y = pv;
                    sum2p += fmrow ? 4.f : 0.f;
                } else {
                    frag16 k0 = *(const frag16*)(kbase + (size_t)(jn * 16 + fr) * Ddim + quad * 8);
                    frag16 k1 = *(const frag16*)(kbase + (size_t)(jn * 16 + fr) * Ddim + 32 + quad * 8);
                    f32x4 z = {0.f, 0.f, 0.f, 0.f};
                    z = __builtin_amdgcn_mfma_f32_16x16x32_bf16(k0, aq0, z, 0, 0, 0);
                    z = __builtin_amdgcn_mfma_f32_16x16x32_bf16(k1, aq1, z, 0, 0, 0);
                    const bool full = (jn < tile);   // wave-uniform
                    float s2r[4], lsuf[4];
                    float tq = 0.f;
#pragma unroll
                    for (int r = 3; r >= 0; --r) {
                        lsuf[r] = tq;                // strict suffix within 4-run
                        s2r[r] = z[r] * SC2;
                        float e1 = EXP2(s2r[r]);
                        if (!full) {
                            const bool valid = mask_type ? (quad * 4 + r <= fr)
                                                         : (quad * 4 + r < fr);
                            e1 = valid ? e1 : 0.f;
                        }
                        tq += e1;
                    }
                    // strict suffix over quads (2 guarded shfl_down)
                    float incl = tq;
                    {
                        float u1 = __shfl_down(incl, 16);
                        incl += (quad < 3) ? u1 : 0.f;
                        float u2 = __shfl_down(incl, 32);
                        incl += (quad < 2) ? u2 : 0.f;
                    }
                    const float base = CTw[fr * 33 + jn] + (incl - tq);
                    const float pos0 = (float)(iRow - (jn * 16 + quad * 4));
                    float e2v[4];
#pragma unroll
                    for (int r = 0; r < 4; ++r) {
                        const float ratio = (base + lsuf[r]) * rsum1;   // >= 0
                        const float arg = ratio * fabsf(pos0 - (float)r);
                        const float te = fmaxf(EXP2(gneg2 * sqrtf(arg)), 1e-5f); // <= 1
                        float e2 = EXP2(s2r[r] * te);
                        if (!full) {
                            const bool valid = mask_type ? (quad * 4 + r <= fr)
                                                         : (quad * 4 + r < fr);
                            e2 = valid ? e2 : (fmrow ? 1.f : 0.f);
                        }
                        sum2p += e2;
                        e2v[r] = e2;
                    }
                    union { __hip_bfloat162 hh; unsigned int u; } c0, c1;
                    c0.hh = __float22bfloat162_rn(make_float2(e2v[0], e2v[1]));
                    c1.hh = __float22bfloat162_rn(make_float2(e2v[2], e2v[3]));
                    pku.x = c0.u; pku.y = c1.u;
                }
                *(uint2*)(Pw + fr * 36 + half * 16 + quad * 4) = pku;
            }
            // PV over this pair's 32-wide window (A = P from LDS, B = Vt)
            frag16 pf = *(const frag16*)(Pw + fr * 36 + quad * 8);
            const int jb = u * 32;
#pragma unroll
            for (int dt = 0; dt < 4; ++dt) {
                frag16 vf = *(const frag16*)(vtb + (size_t)(dt * 16 + fr) * Sdim + jb + quad * 8);
                oacc[dt] = __builtin_amdgcn_mfma_f32_16x16x32_bf16(pf, vf, oacc[dt], 0, 0, 0);
            }
        }

        // ---- combine the two waves' partials
        {
            float s2 = sum2p;
            s2 += __shfl_xor(s2, 16);
            s2 += __shfl_xor(s2, 32);
            if (lane < 16) S2s[p][lane] = s2;
        }
        if (p == 1) {
#pragma unroll
            for (int dt = 0; dt < 4; ++dt)
#pragma unroll
                for (int r = 0; r < 4; ++r)
                    OaccS[(quad * 4 + r) * 66 + dt * 16 + fr] = oacc[dt][r];
        }
        __syncthreads();

        if (p == 0) {
            const float rs2 = 1.f / (S2s[0][fr] + S2s[1][fr]);   // for row fr
            float rs2q[4];
#pragma unroll
            for (int r = 0; r < 4; ++r) rs2q[r] = __shfl(rs2, quad * 4 + r);

            // O rows q0+quad*4+r, cols dt*16+fr
            unsigned short* obase = Ob + ((size_t)(b * Sdim + q0)) * Ddim + h * DKdim;
#pragma unroll
            for (int dt = 0; dt < 4; ++dt)
#pragma unroll
                for (int r = 0; r < 4; ++r) {
                    const float v = oacc[dt][r] + OaccS[(quad * 4 + r) * 66 + dt * 16 + fr];
                    obase[(size_t)(quad * 4 + r) * Ddim + dt * 16 + fr] = f2b(v * rs2q[r]);
                }
        }
        // next iteration's shared-mem writes are ordered against this
        // iteration's reads by the barriers above (see analysis): CTw writes
        // (pass 1) occur only after the combine barrier each wave crossed.
    }
}

// ---------------------------------------------------------------------------
// LayerNorm over last dim (512); fp32 out (nullable) + bf16 out (nullable).
// ---------------------------------------------------------------------------
__global__ __launch_bounds__(256) void ln_kernel(
    const float* __restrict__ X, const float* __restrict__ g,
    const float* __restrict__ bta, float* __restrict__ Y,
    unsigned short* __restrict__ Yb)
{
    const int row = blockIdx.x;
    const int t = threadIdx.x;
    __shared__ float r1[256], r2[256];
    const float* x = X + (size_t)row * Ddim;
    float a = x[t], b = x[t + 256];
    r1[t] = a + b;
    r2[t] = a * a + b * b;
    __syncthreads();
    for (int off = 128; off; off >>= 1) {
        if (t < off) { r1[t] += r1[t + off]; r2[t] += r2[t + off]; }
        __syncthreads();
    }
    float mean = r1[0] * (1.f / Ddim);
    float var = r2[0] * (1.f / Ddim) - mean * mean;
    float rs = rsqrtf(var + 1e-5f);
    float y0 = (a - mean) * rs * g[t] + bta[t];
    float y1 = (b - mean) * rs * g[t + 256] + bta[t + 256];
    if (Y) {
        float* y = Y + (size_t)row * Ddim;
        y[t] = y0;
        y[t + 256] = y1;
    }
    if (Yb) {
        unsigned short* yb = Yb + (size_t)row * Ddim;
        yb[t] = f2b(y0);
        yb[t + 256] = f2b(y1);
    }
}

// ---------------------------------------------------------------------------
extern "C" void kernel_launch(void* const* d_in, const int* in_sizes, int n_in,
                              void* d_out, int out_size, void* d_ws, size_t ws_size,
                              hipStream_t stream)
{
    const float* x0     = (const float*)d_in[0];
    const float* y0     = (const float*)d_in[1];
    const float* Wk     = (const float*)d_in[2];
    const float* bk     = (const float*)d_in[3];
    const float* Wv     = (const float*)d_in[4];
    const float* bv     = (const float*)d_in[5];
    const float* Wo     = (const float*)d_in[6];
    const float* bo     = (const float*)d_in[7];
    const float* gammas = (const float*)d_in[8];
    const float* ln1g   = (const float*)d_in[9];
    const float* ln1b   = (const float*)d_in[10];
    const float* W1     = (const float*)d_in[11];
    const float* b1     = (const float*)d_in[12];
    const float* W2     = (const float*)d_in[13];
    const float* b2     = (const float*)d_in[14];
    const float* ln2g   = (const float*)d_in[15];
    const float* ln2b   = (const float*)d_in[16];

    const size_t NBSD = (size_t)Mrows * Ddim;   // 4,194,304
    float* ws = (float*)d_ws;
    float* T1   = ws;
    float* X1   = T1 + NBSD;
    float* Xbuf = X1 + NBSD;
    unsigned short* Kbf = (unsigned short*)(Xbuf + NBSD);
    unsigned short* Vt  = Kbf + NBSD;
    unsigned short* AOb = Vt + NBSD;
    unsigned short* Abf = AOb + NBSD;
    unsigned short* Xbf = Abf + NBSD;
    unsigned short* Ybf = Xbf + NBSD;
    unsigned short* Hbb = Ybf + NBSD;                       // [M,F]
    unsigned short* WtAll = Hbb + (size_t)Mrows * Fdim;

    auto WtK = [&](int l) { return WtAll + (size_t)(l * 3 + 0) * 262144; };
    auto WtV = [&](int l) { return WtAll + (size_t)(l * 3 + 1) * 262144; };
    auto WtO = [&](int l) { return WtAll + (size_t)(l * 3 + 2) * 262144; };
    auto Wt1 = [&](int l) { return WtAll + 9 * 262144 + (size_t)(l >> 1) * (512 * 2048); };
    auto Wt2 = [&](int l) { return WtAll + 9 * 262144 + 2 * (512 * 2048) + (size_t)(l >> 1) * (2048 * 512); };

    const int convBlocks = (int)(NBSD / 2048);

    wtrans_all<<<1600, 256, 0, stream>>>(Wk, Wv, Wo, W1, W2, WtAll);

    auto run_block = [&](int l, const float* qinf, const unsigned short* qinb,
                         const unsigned short* vinb, int mask_type, bool ffn,
                         float* outf, unsigned short* outb) {
        const float* bk_l = bk + (size_t)l * Ddim;
        const float* bv_l = bv + (size_t)l * Ddim;
        const float* bo_l = bo + (size_t)l * Ddim;

        // K (=Q) + V projections in one launch (z=0: K->Kbf, z=1: V->Vt)
        gemm_n64<<<dim3(8, 64, 2), 256, 0, stream>>>(
            qinb, vinb, WtK(l), WtV(l), bk_l, bv_l,
            nullptr, nullptr, Kbf, Vt, Ddim);
        // attention (flash-style streaming, equal-work pair blocks)
        attn_flash7<<<dim3(16, Hdim, Bdim), 128, 0, stream>>>(
            Kbf, Vt, gammas + (size_t)l * Hdim, AOb, mask_type);
        // O-projection + residual -> T1 (fp32); LN1
        gemm_n64<<<dim3(8, 64, 1), 256, 0, stream>>>(
            AOb, AOb, WtO(l), WtO(l), bo_l, bo_l,
            qinf, T1, nullptr, nullptr, Ddim);
        float* x1f = ffn ? X1 : outf;
        unsigned short* x1b = ffn ? Abf : outb;
        ln_kernel<<<Mrows, 256, 0, stream>>>(T1,
            ln1g + (size_t)l * Ddim, ln1b + (size_t)l * Ddim, x1f, x1b);
        if (ffn) {
            const float* b1_l = b1 + (size_t)l * Fdim;
            const float* b2_l = b2 + (size_t)l * Ddim;
            gemm_mfma<<<dim3(Fdim / 128, Mrows / 128), 256, 0, stream>>>(
                (const __hip_bfloat16*)Abf, (const __hip_bfloat16*)Wt1(l),
                b1_l, nullptr, nullptr, Hbb, Mrows, Fdim, Ddim, 1);
            gemm_n64<<<dim3(8, 64, 1), 256, 0, stream>>>(
                Hbb, Hbb, Wt2(l), Wt2(l), b2_l, b2_l,
                X1, T1, nullptr, nullptr, Fdim);
            ln_kernel<<<Mrows, 256, 0, stream>>>(T1,
                ln2g + (size_t)l * Ddim, ln2b + (size_t)l * Ddim, outf, outb);
        }
    };

    // Block 0: knowledge encoder (y), mask1, FFN -> Ybf (bf16 only)
    conv_b<<<convBlocks, 256, 0, stream>>>(y0, Abf);
    run_block(0, y0, Abf, Abf, 1, true, nullptr, Ybf);
    // Block 1: question encoder (x), mask1, no FFN -> Xbuf/Xbf
    conv_b<<<convBlocks, 256, 0, stream>>>(x0, Abf);
    run_block(1, x0, Abf, Abf, 1, false, Xbuf, Xbf);
    // Block 2: knowledge retriever, q/k=x, v=y, mask0, FFN -> d_out (fp32)
    run_block(2, Xbuf, Xbf, Ybf, 0, true, (float*)d_out, nullptr);
}

// Round 6
// 627.651 us; speedup vs baseline: 1.2119x; 1.0298x over previous
//
#include <hip/hip_runtime.h>
#include <hip/hip_bf16.h>

// Problem dims (fixed)
#define Bdim 16
#define Sdim 512
#define Ddim 512
#define Hdim 8
#define DKdim 64
#define Fdim 2048
#define Mrows (Bdim * Sdim)   // 8192

typedef __attribute__((ext_vector_type(8))) short  frag16;   // 8 bf16 (4 VGPRs)
typedef __attribute__((ext_vector_type(4))) float  f32x4;    // MFMA acc
typedef __attribute__((ext_vector_type(8))) unsigned short ushort8;
typedef __attribute__((ext_vector_type(4))) unsigned short ushort4v;

// raw 2^x (v_exp_f32); fallback keeps semantics
#if defined(__has_builtin)
#  if __has_builtin(__builtin_amdgcn_exp2f)
#    define EXP2(x) __builtin_amdgcn_exp2f(x)
#  endif
#endif
#ifndef EXP2
#  define EXP2(x) __expf((x) * 0.6931471805599453f)
#endif
#define SC2 0.18033688011112042f   // 0.125 * log2(e)

// round-to-nearest-even fp32 -> bf16 (finite data)
__device__ __forceinline__ unsigned short f2b(float x) {
    union { float f; unsigned int u; } v; v.f = x;
    unsigned int r = (v.u + 0x7FFFu + ((v.u >> 16) & 1u)) >> 16;
    return (unsigned short)r;
}

// ---------------------------------------------------------------------------
// bf16 MFMA GEMM, 128x128 tile (used for FFN1, N=2048).
// XCD-chunked swizzle + 2-phase double-buffered K-loop.
// ---------------------------------------------------------------------------
__global__ __launch_bounds__(256) void gemm_mfma(
    const __hip_bfloat16* __restrict__ A, const __hip_bfloat16* __restrict__ Bt,
    const float* __restrict__ bias, const float* __restrict__ R,
    float* __restrict__ Cf, unsigned short* __restrict__ Cb,
    int M, int N, int K, int do_relu)
{
    __shared__ short As[2][128 * 32];
    __shared__ short Bs[2][128 * 32];

    const int t = threadIdx.x;
    const int lane = t & 63;
    const int wave = t >> 6;

    // XCD-aware chunked swizzle (grid size divisible by 8)
    const int gx = gridDim.x;
    const int nb = gx * gridDim.y;
    const int lid = blockIdx.x + gx * blockIdx.y;
    const int wid = (lid & 7) * (nb >> 3) + (lid >> 3);
    const int bm = (wid / gx) * 128;
    const int bn = (wid % gx) * 128;

    const int wm = (wave >> 1) * 64;
    const int wn = (wave & 1) * 64;

    f32x4 acc[4][4] = {};
    const int lrow = lane >> 2;
    const int lcol = (lane & 3) * 8;

    auto stage = [&](int k0, int buf) {
#pragma unroll
        for (int i = 0; i < 2; ++i) {
            const int chunk = wave * 2 + i;
            const int row = chunk * 16 + lrow;
            const __hip_bfloat16* ga = A + (size_t)(bm + row) * K + k0 + lcol;
            const __hip_bfloat16* gb = Bt + (size_t)(bn + row) * K + k0 + lcol;
            __builtin_amdgcn_global_load_lds(
                (const __attribute__((address_space(1))) unsigned int*)ga,
                (__attribute__((address_space(3))) unsigned int*)(&As[buf][chunk * 512]),
                16, 0, 0);
            __builtin_amdgcn_global_load_lds(
                (const __attribute__((address_space(1))) unsigned int*)gb,
                (__attribute__((address_space(3))) unsigned int*)(&Bs[buf][chunk * 512]),
                16, 0, 0);
        }
    };

    const int fr = lane & 15;
    const int quad = lane >> 4;
    const int nk = K >> 5;

    stage(0, 0);
    __syncthreads();

    for (int it = 0; it < nk; ++it) {
        const int buf = it & 1;
        if (it + 1 < nk) stage((it + 1) << 5, buf ^ 1);
        frag16 af[4], bfr[4];
#pragma unroll
        for (int i = 0; i < 4; ++i) {
            af[i]  = *(const frag16*)(&As[buf][(wm + i * 16 + fr) * 32 + quad * 8]);
            bfr[i] = *(const frag16*)(&Bs[buf][(wn + i * 16 + fr) * 32 + quad * 8]);
        }
#pragma unroll
        for (int mi = 0; mi < 4; ++mi)
#pragma unroll
            for (int ni = 0; ni < 4; ++ni)
                acc[mi][ni] = __builtin_amdgcn_mfma_f32_16x16x32_bf16(
                    af[mi], bfr[ni], acc[mi][ni], 0, 0, 0);
        __syncthreads();
    }

#pragma unroll
    for (int mi = 0; mi < 4; ++mi) {
#pragma unroll
        for (int r = 0; r < 4; ++r) {
            const int m = bm + wm + mi * 16 + quad * 4 + r;
#pragma unroll
            for (int ni = 0; ni < 4; ++ni) {
                const int n = bn + wn + ni * 16 + fr;
                float v = acc[mi][ni][r] + bias[n];
                if (R) v += R[(size_t)m * N + n];
                if (do_relu) v = fmaxf(v, 0.f);
                if (Cf) Cf[(size_t)m * N + n] = v;
                if (Cb) Cb[(size_t)m * N + n] = f2b(v);
            }
        }
    }
}

// ---------------------------------------------------------------------------
// bf16 MFMA GEMM, 128x64 tile, N=512 fixed. Dual-mode via blockIdx.z:
// z=0: A0@B0^T+bias0 -> Cb (normal bf16) / Cf(+R) fp32
// z=1: A1@B1^T+bias1 -> CbT transposed Vt[b,h,d,s] bf16
// XCD-chunked swizzle + 2-phase double-buffered K-loop.
// ---------------------------------------------------------------------------
__global__ __launch_bounds__(256) void gemm_n64(
    const unsigned short* __restrict__ A0, const unsigned short* __restrict__ A1,
    const unsigned short* __restrict__ B0, const unsigned short* __restrict__ B1,
    const float* __restrict__ bias0, const float* __restrict__ bias1,
    const float* __restrict__ R, float* __restrict__ Cf,
    unsigned short* __restrict__ Cb, unsigned short* __restrict__ CbT,
    int K)
{
    const int NN = 512;
    __shared__ short As[2][128 * 32];
    __shared__ short Bs[2][64 * 32];

    const int trans = blockIdx.z;
    const unsigned short* A  = trans ? A1 : A0;
    const unsigned short* Bt = trans ? B1 : B0;
    const float* bias        = trans ? bias1 : bias0;

    const int t = threadIdx.x;
    const int lane = t & 63;
    const int wave = t >> 6;

    // XCD-aware chunked swizzle within each z-slice (512 % 8 == 0 so the
    // z offset preserves the XCD residue).
    const int lid = blockIdx.x + 8 * blockIdx.y;          // 0..511
    const int wid = (lid & 7) * 64 + (lid >> 3);
    const int bm = (wid >> 3) * 128;
    const int bn = (wid & 7) * 64;

    const int wm = (wave >> 1) * 64;
    const int wn = (wave & 1) * 32;

    f32x4 acc[4][2] = {};
    const int lrow = lane >> 2;
    const int lcol = (lane & 3) * 8;

    auto stage = [&](int k0, int buf) {
#pragma unroll
        for (int i = 0; i < 2; ++i) {
            const int chunk = wave * 2 + i;
            const int row = chunk * 16 + lrow;
            const unsigned short* ga = A + (size_t)(bm + row) * K + k0 + lcol;
            __builtin_amdgcn_global_load_lds(
                (const __attribute__((address_space(1))) unsigned int*)ga,
                (__attribute__((address_space(3))) unsigned int*)(&As[buf][chunk * 512]),
                16, 0, 0);
        }
        {
            const int row = wave * 16 + lrow;
            const unsigned short* gb = Bt + (size_t)(bn + row) * K + k0 + lcol;
            __builtin_amdgcn_global_load_lds(
                (const __attribute__((address_space(1))) unsigned int*)gb,
                (__attribute__((address_space(3))) unsigned int*)(&Bs[buf][wave * 512]),
                16, 0, 0);
        }
    };

    const int fr = lane & 15;
    const int quad = lane >> 4;
    const int nk = K >> 5;

    stage(0, 0);
    __syncthreads();

    for (int it = 0; it < nk; ++it) {
        const int buf = it & 1;
        if (it + 1 < nk) stage((it + 1) << 5, buf ^ 1);
        frag16 af[4], bfr[2];
#pragma unroll
        for (int i = 0; i < 4; ++i)
            af[i] = *(const frag16*)(&As[buf][(wm + i * 16 + fr) * 32 + quad * 8]);
#pragma unroll
        for (int i = 0; i < 2; ++i)
            bfr[i] = *(const frag16*)(&Bs[buf][(wn + i * 16 + fr) * 32 + quad * 8]);
#pragma unroll
        for (int mi = 0; mi < 4; ++mi)
#pragma unroll
            for (int ni = 0; ni < 2; ++ni)
                acc[mi][ni] = __builtin_amdgcn_mfma_f32_16x16x32_bf16(
                    af[mi], bfr[ni], acc[mi][ni], 0, 0, 0);
        __syncthreads();
    }

    if (trans) {
#pragma unroll
        for (int mi = 0; mi < 4; ++mi)
#pragma unroll
            for (int ni = 0; ni < 2; ++ni) {
                const int m = bm + wm + mi * 16 + quad * 4;
                const int n = bn + wn + ni * 16 + fr;
                ushort4v o;
#pragma unroll
                for (int r = 0; r < 4; ++r) o[r] = f2b(acc[mi][ni][r] + bias[n]);
                const int bb = m >> 9, s = m & 511;
                const int hh = n >> 6, dd = n & 63;
                *(ushort4v*)(CbT + (((size_t)((bb * Hdim + hh) * DKdim + dd)) << 9) + s) = o;
            }
        return;
    }

#pragma unroll
    for (int mi = 0; mi < 4; ++mi) {
#pragma unroll
        for (int r = 0; r < 4; ++r) {
            const int m = bm + wm + mi * 16 + quad * 4 + r;
#pragma unroll
            for (int ni = 0; ni < 2; ++ni) {
                const int n = bn + wn + ni * 16 + fr;
                float v = acc[mi][ni][r] + bias[n];
                if (R) v += R[(size_t)m * NN + n];
                if (Cf) Cf[(size_t)m * NN + n] = v;
                if (Cb) Cb[(size_t)m * NN + n] = f2b(v);
            }
        }
    }
}

// ---------------------------------------------------------------------------
// fp32 -> bf16 convert
// ---------------------------------------------------------------------------
__global__ __launch_bounds__(256) void conv_b(
    const float* __restrict__ X, unsigned short* __restrict__ Y)
{
    const size_t i = ((size_t)blockIdx.x * 256 + threadIdx.x) * 8;
    float4 a = *(const float4*)(X + i);
    float4 b = *(const float4*)(X + i + 4);
    ushort8 o;
    o[0] = f2b(a.x); o[1] = f2b(a.y); o[2] = f2b(a.z); o[3] = f2b(a.w);
    o[4] = f2b(b.x); o[5] = f2b(b.y); o[6] = f2b(b.z); o[7] = f2b(b.w);
    *(ushort8*)(Y + i) = o;
}

// ---------------------------------------------------------------------------
// ALL weight transposes fused: 1600 tiles of 64x64, [K,N] fp32 -> [N,K] bf16
// ---------------------------------------------------------------------------
__global__ __launch_bounds__(256) void wtrans_all(
    const float* __restrict__ Wk, const float* __restrict__ Wv,
    const float* __restrict__ Wo, const float* __restrict__ W1,
    const float* __restrict__ W2, unsigned short* __restrict__ dst)
{
    const int bid = blockIdx.x;
    const float* src; unsigned short* d; int K, N, tk, tn;
    if (bid < 576) {
        const int mat = bid >> 6, tile = bid & 63;
        const int l = mat / 3, wch = mat % 3;
        const float* W = (wch == 0) ? Wk : (wch == 1) ? Wv : Wo;
        src = W + (size_t)l * 262144;
        d = dst + (size_t)mat * 262144;
        K = 512; N = 512; tn = tile & 7; tk = tile >> 3;
    } else if (bid < 1088) {
        const int idx = bid - 576, l2 = idx >> 8, tile = idx & 255;
        src = W1 + (size_t)(l2 * 2) * (512 * 2048);
        d = dst + 9 * 262144 + (size_t)l2 * (512 * 2048);
        K = 512; N = 2048; tn = tile & 31; tk = tile >> 5;
    } else {
        const int idx = bid - 1088, l2 = idx >> 8, tile = idx & 255;
        src = W2 + (size_t)(l2 * 2) * (2048 * 512);
        d = dst + 9 * 262144 + 2 * (512 * 2048) + (size_t)l2 * (2048 * 512);
        K = 2048; N = 512; tn = tile & 7; tk = tile >> 3;
    }
    const int n0 = tn * 64, k0 = tk * 64;
    __shared__ float T[64][65];
    const int t = threadIdx.x;
    const int kl = t >> 4, n4 = (t & 15) << 2;
#pragma unroll
    for (int it = 0; it < 4; ++it) {
        const int k = kl + it * 16;
        float4 v = *(const float4*)(src + (size_t)(k0 + k) * N + n0 + n4);
        T[n4 + 0][k] = v.x; T[n4 + 1][k] = v.y;
        T[n4 + 2][k] = v.z; T[n4 + 3][k] = v.w;
    }
    __syncthreads();
    const int nl = t >> 3, k8 = (t & 7) << 3;
#pragma unroll
    for (int it = 0; it < 2; ++it) {
        const int n = nl + it * 32;
        ushort8 o;
#pragma unroll
        for (int c = 0; c < 8; ++c) o[c] = f2b(T[n][k8 + c]);
        *(ushort8*)(d + (size_t)(n0 + n) * K + k0 + k8) = o;
    }
}

// ---------------------------------------------------------------------------
// Flash-style monotonic attention v8. ONE 16-row q-tile per 256-thread
// block, j-range split across FOUR waves (jn/u == w mod 4). Rationale: all
// prior versions (68-74us) were bounded by the same critical path — the
// heaviest tile's j-stream processed by only 2 waves. 4-way split halves
// the per-wave serial path. Grid (128 bh, 32 ranks) = 4096 blocks = 16384
// waves = 2 residency rounds at 32 waves/CU, with LPT dispatch order
// (heaviest tile first; consecutive blocks share a rank so co-resident
// work per CU is equal) so refill keeps residency flat and the tail is
// the cheapest tiles. 4-way combine: sums via LDS; oacc via 2-step tree.
// Fully-masked row (mask0, i==0): uniform 1/512 over ALL j.
// ---------------------------------------------------------------------------
__global__ __launch_bounds__(256, 8) void attn_flash8(
    const unsigned short* __restrict__ Kb,   // [B*S, D] bf16 (Q == K)
    const unsigned short* __restrict__ Vt,   // [B,H,DK,S] bf16
    const float* __restrict__ gam,
    unsigned short* __restrict__ Ob,         // [B*S, D] bf16
    int mask_type)
{
    __shared__ float CTw[16 * 33];               // cross-tile strict suffix
    __shared__ unsigned short Pst[4][16 * 36];   // P staging (A-frag layout, per wave)
    __shared__ float S1s[4][16];                 // sum1 partials [w][row]
    __shared__ float S2s[4][16];                 // sum2 partials
    __shared__ float OaccA[16 * 66];             // oacc combine buffers
    __shared__ float OaccB[16 * 66];

    const int h = blockIdx.x & 7, b = blockIdx.x >> 3;
    const int rk = blockIdx.y;                   // LPT rank: 0 = heaviest
    const int tile = mask_type ? (31 - rk) : (rk == 0 ? 0 : 32 - rk);

    const int t = threadIdx.x, lane = t & 63, w = t >> 6;   // w: j-split slot
    const int quad = lane >> 4, fr = lane & 15;
    const int q0 = tile * 16;
    const int iRow = q0 + fr;                // this lane's q row

    const unsigned short* kbase = Kb + (size_t)b * Sdim * Ddim + h * DKdim;
    const unsigned short* vtb = Vt + (size_t)(b * Hdim + h) * DKdim * Sdim;
    const float gneg2 = -log1pf(__expf(gam[h])) * 1.4426950408889634f;

    // Q as B-operand: rows q0+fr
    frag16 aq0 = *(const frag16*)(kbase + (size_t)(q0 + fr) * Ddim + quad * 8);
    frag16 aq1 = *(const frag16*)(kbase + (size_t)(q0 + fr) * Ddim + 32 + quad * 8);

    // ---- Pass 1: sum1 partials + per-tile totals into CT (4-way jn split)
    float psum = 0.f;
    for (int jn = w; jn <= tile; jn += 4) {
        frag16 k0 = *(const frag16*)(kbase + (size_t)(jn * 16 + fr) * Ddim + quad * 8);
        frag16 k1 = *(const frag16*)(kbase + (size_t)(jn * 16 + fr) * Ddim + 32 + quad * 8);
        f32x4 z = {0.f, 0.f, 0.f, 0.f};
        z = __builtin_amdgcn_mfma_f32_16x16x32_bf16(k0, aq0, z, 0, 0, 0);
        z = __builtin_amdgcn_mfma_f32_16x16x32_bf16(k1, aq1, z, 0, 0, 0);
        float tq = 0.f;
        if (jn < tile) {                 // fully-valid tile (both masks)
#pragma unroll
            for (int r = 0; r < 4; ++r) tq += EXP2(z[r] * SC2);
        } else {                         // diagonal tile
#pragma unroll
            for (int r = 0; r < 4; ++r) {
                const bool valid = mask_type ? (quad * 4 + r <= fr)
                                             : (quad * 4 + r < fr);
                tq += valid ? EXP2(z[r] * SC2) : 0.f;
            }
        }
        psum += tq;
        float tt = tq;
        tt += __shfl_xor(tt, 16);
        tt += __shfl_xor(tt, 32);
        if (quad == 0) CTw[fr * 33 + jn] = tt;
    }
    {
        float s1 = psum;
        s1 += __shfl_xor(s1, 16);
        s1 += __shfl_xor(s1, 32);
        if (lane < 16) S1s[w][lane] = s1;
    }
    __syncthreads();

    // totals -> strict cross-tile suffix (wave 0; rows by lanes 0..15)
    if (w == 0 && lane < 16) {
        float run = 0.f;
        for (int jn = tile; jn >= 0; --jn) {
            const float tv = CTw[lane * 33 + jn];
            CTw[lane * 33 + jn] = run;
            run += tv;
        }
    }
    __syncthreads();

    const float rsum1 = 1.f / (S1s[0][fr] + S1s[1][fr] + S1s[2][fr] + S1s[3][fr]);
    unsigned short* Pw = Pst[w];
    const bool fm_blk = (mask_type == 0) && (tile == 0);
    const bool fmrow = fm_blk && (fr == 0);
    const int umax = fm_blk ? (Sdim / 32 - 1) : (tile >> 1);
    float sum2p = 0.f;
    f32x4 oacc[4] = {};

    // ---- Pass 2: independent u-tiles, 4-way split, online PV
    for (int u = umax - w; u >= 0; u -= 4) {
#pragma unroll
        for (int half = 0; half < 2; ++half) {
            const int jn = 2 * u + half;
            uint2 pku;
            if (jn > tile) {
                // empty tile: P=0, except mask0 row-0 uniform case (P=1)
                const unsigned int pv = fmrow ? 0x3F803F80u : 0u;
                pku.x = pv; pku.y = pv;
                sum2p += fmrow ? 4.f : 0.f;
            } else {
                frag16 k0 = *(const frag16*)(kbase + (size_t)(jn * 16 + fr) * Ddim + quad * 8);
                frag16 k1 = *(const frag16*)(kbase + (size_t)(jn * 16 + fr) * Ddim + 32 + quad * 8);
                f32x4 z = {0.f, 0.f, 0.f, 0.f};
                z = __builtin_amdgcn_mfma_f32_16x16x32_bf16(k0, aq0, z, 0, 0, 0);
                z = __builtin_amdgcn_mfma_f32_16x16x32_bf16(k1, aq1, z, 0, 0, 0);
                const bool full = (jn < tile);   // wave-uniform
                float s2r[4], lsuf[4];
                float tq = 0.f;
#pragma unroll
                for (int r = 3; r >= 0; --r) {
                    lsuf[r] = tq;                // strict suffix within 4-run
                    s2r[r] = z[r] * SC2;
                    float e1 = EXP2(s2r[r]);
                    if (!full) {
                        const bool valid = mask_type ? (quad * 4 + r <= fr)
                                                     : (quad * 4 + r < fr);
                        e1 = valid ? e1 : 0.f;
                    }
                    tq += e1;
                }
                // strict suffix over quads (2 guarded shfl_down)
                float incl = tq;
                {
                    float u1 = __shfl_down(incl, 16);
                    incl += (quad < 3) ? u1 : 0.f;
                    float u2 = __shfl_down(incl, 32);
                    incl += (quad < 2) ? u2 : 0.f;
                }
                const float base = CTw[fr * 33 + jn] + (incl - tq);
                const float pos0 = (float)(iRow - (jn * 16 + quad * 4));
                float e2v[4];
#pragma unroll
                for (int r = 0; r < 4; ++r) {
                    const float ratio = (base + lsuf[r]) * rsum1;   // >= 0
                    const float arg = ratio * fabsf(pos0 - (float)r);
                    const float te = fmaxf(EXP2(gneg2 * sqrtf(arg)), 1e-5f); // <= 1
                    float e2 = EXP2(s2r[r] * te);
                    if (!full) {
                        const bool valid = mask_type ? (quad * 4 + r <= fr)
                                                     : (quad * 4 + r < fr);
                        e2 = valid ? e2 : (fmrow ? 1.f : 0.f);
                    }
                    sum2p += e2;
                    e2v[r] = e2;
                }
                union { __hip_bfloat162 hh; unsigned int u; } c0, c1;
                c0.hh = __float22bfloat162_rn(make_float2(e2v[0], e2v[1]));
                c1.hh = __float22bfloat162_rn(make_float2(e2v[2], e2v[3]));
                pku.x = c0.u; pku.y = c1.u;
            }
            *(uint2*)(Pw + fr * 36 + half * 16 + quad * 4) = pku;
        }
        // PV over this pair's 32-wide window (A = P from LDS, B = Vt)
        frag16 pf = *(const frag16*)(Pw + fr * 36 + quad * 8);
        const int jb = u * 32;
#pragma unroll
        for (int dt = 0; dt < 4; ++dt) {
            frag16 vf = *(const frag16*)(vtb + (size_t)(dt * 16 + fr) * Sdim + jb + quad * 8);
            oacc[dt] = __builtin_amdgcn_mfma_f32_16x16x32_bf16(pf, vf, oacc[dt], 0, 0, 0);
        }
    }

    // ---- combine the four waves' partials (2-step tree through 2 buffers)
    {
        float s2 = sum2p;
        s2 += __shfl_xor(s2, 16);
        s2 += __shfl_xor(s2, 32);
        if (lane < 16) S2s[w][lane] = s2;
    }
    if (w == 1) {
#pragma unroll
        for (int dt = 0; dt < 4; ++dt)
#pragma unroll
            for (int r = 0; r < 4; ++r)
                OaccA[(quad * 4 + r) * 66 + dt * 16 + fr] = oacc[dt][r];
    }
    if (w == 3) {
#pragma unroll
        for (int dt = 0; dt < 4; ++dt)
#pragma unroll
            for (int r = 0; r < 4; ++r)
                OaccB[(quad * 4 + r) * 66 + dt * 16 + fr] = oacc[dt][r];
    }
    __syncthreads();
    if (w == 0) {
#pragma unroll
        for (int dt = 0; dt < 4; ++dt)
#pragma unroll
            for (int r = 0; r < 4; ++r)
                oacc[dt][r] += OaccA[(quad * 4 + r) * 66 + dt * 16 + fr];
    }
    if (w == 2) {
#pragma unroll
        for (int dt = 0; dt < 4; ++dt)
#pragma unroll
            for (int r = 0; r < 4; ++r)
                oacc[dt][r] += OaccB[(quad * 4 + r) * 66 + dt * 16 + fr];
    }
    __syncthreads();
    if (w == 2) {
#pragma unroll
        for (int dt = 0; dt < 4; ++dt)
#pragma unroll
            for (int r = 0; r < 4; ++r)
                OaccA[(quad * 4 + r) * 66 + dt * 16 + fr] = oacc[dt][r];
    }
    __syncthreads();

    if (w == 0) {
        const float rs2 = 1.f / (S2s[0][fr] + S2s[1][fr] + S2s[2][fr] + S2s[3][fr]);
        float rs2q[4];
#pragma unroll
        for (int r = 0; r < 4; ++r) rs2q[r] = __shfl(rs2, quad * 4 + r);

        // O rows q0+quad*4+r, cols dt*16+fr
        unsigned short* obase = Ob + ((size_t)(b * Sdim + q0)) * Ddim + h * DKdim;
#pragma unroll
        for (int dt = 0; dt < 4; ++dt)
#pragma unroll
            for (int r = 0; r < 4; ++r) {
                const float v = oacc[dt][r] + OaccA[(quad * 4 + r) * 66 + dt * 16 + fr];
                obase[(size_t)(quad * 4 + r) * Ddim + dt * 16 + fr] = f2b(v * rs2q[r]);
            }
    }
}

// ---------------------------------------------------------------------------
// LayerNorm over last dim (512); fp32 out (nullable) + bf16 out (nullable).
// ---------------------------------------------------------------------------
__global__ __launch_bounds__(256) void ln_kernel(
    const float* __restrict__ X, const float* __restrict__ g,
    const float* __restrict__ bta, float* __restrict__ Y,
    unsigned short* __restrict__ Yb)
{
    const int row = blockIdx.x;
    const int t = threadIdx.x;
    __shared__ float r1[256], r2[256];
    const float* x = X + (size_t)row * Ddim;
    float a = x[t], b = x[t + 256];
    r1[t] = a + b;
    r2[t] = a * a + b * b;
    __syncthreads();
    for (int off = 128; off; off >>= 1) {
        if (t < off) { r1[t] += r1[t + off]; r2[t] += r2[t + off]; }
        __syncthreads();
    }
    float mean = r1[0] * (1.f / Ddim);
    float var = r2[0] * (1.f / Ddim) - mean * mean;
    float rs = rsqrtf(var + 1e-5f);
    float y0 = (a - mean) * rs * g[t] + bta[t];
    float y1 = (b - mean) * rs * g[t + 256] + bta[t + 256];
    if (Y) {
        float* y = Y + (size_t)row * Ddim;
        y[t] = y0;
        y[t + 256] = y1;
    }
    if (Yb) {
        unsigned short* yb = Yb + (size_t)row * Ddim;
        yb[t] = f2b(y0);
        yb[t + 256] = f2b(y1);
    }
}

// ---------------------------------------------------------------------------
extern "C" void kernel_launch(void* const* d_in, const int* in_sizes, int n_in,
                              void* d_out, int out_size, void* d_ws, size_t ws_size,
                              hipStream_t stream)
{
    const float* x0     = (const float*)d_in[0];
    const float* y0     = (const float*)d_in[1];
    const float* Wk     = (const float*)d_in[2];
    const float* bk     = (const float*)d_in[3];
    const float* Wv     = (const float*)d_in[4];
    const float* bv     = (const float*)d_in[5];
    const float* Wo     = (const float*)d_in[6];
    const float* bo     = (const float*)d_in[7];
    const float* gammas = (const float*)d_in[8];
    const float* ln1g   = (const float*)d_in[9];
    const float* ln1b   = (const float*)d_in[10];
    const float* W1     = (const float*)d_in[11];
    const float* b1     = (const float*)d_in[12];
    const float* W2     = (const float*)d_in[13];
    const float* b2     = (const float*)d_in[14];
    const float* ln2g   = (const float*)d_in[15];
    const float* ln2b   = (const float*)d_in[16];

    const size_t NBSD = (size_t)Mrows * Ddim;   // 4,194,304
    float* ws = (float*)d_ws;
    float* T1   = ws;
    float* X1   = T1 + NBSD;
    float* Xbuf = X1 + NBSD;
    unsigned short* Kbf = (unsigned short*)(Xbuf + NBSD);
    unsigned short* Vt  = Kbf + NBSD;
    unsigned short* AOb = Vt + NBSD;
    unsigned short* Abf = AOb + NBSD;
    unsigned short* Xbf = Abf + NBSD;
    unsigned short* Ybf = Xbf + NBSD;
    unsigned short* Hbb = Ybf + NBSD;                       // [M,F]
    unsigned short* WtAll = Hbb + (size_t)Mrows * Fdim;

    auto WtK = [&](int l) { return WtAll + (size_t)(l * 3 + 0) * 262144; };
    auto WtV = [&](int l) { return WtAll + (size_t)(l * 3 + 1) * 262144; };
    auto WtO = [&](int l) { return WtAll + (size_t)(l * 3 + 2) * 262144; };
    auto Wt1 = [&](int l) { return WtAll + 9 * 262144 + (size_t)(l >> 1) * (512 * 2048); };
    auto Wt2 = [&](int l) { return WtAll + 9 * 262144 + 2 * (512 * 2048) + (size_t)(l >> 1) * (2048 * 512); };

    const int convBlocks = (int)(NBSD / 2048);

    wtrans_all<<<1600, 256, 0, stream>>>(Wk, Wv, Wo, W1, W2, WtAll);

    auto run_block = [&](int l, const float* qinf, const unsigned short* qinb,
                         const unsigned short* vinb, int mask_type, bool ffn,
                         float* outf, unsigned short* outb) {
        const float* bk_l = bk + (size_t)l * Ddim;
        const float* bv_l = bv + (size_t)l * Ddim;
        const float* bo_l = bo + (size_t)l * Ddim;

        // K (=Q) + V projections in one launch (z=0: K->Kbf, z=1: V->Vt)
        gemm_n64<<<dim3(8, 64, 2), 256, 0, stream>>>(
            qinb, vinb, WtK(l), WtV(l), bk_l, bv_l,
            nullptr, nullptr, Kbf, Vt, Ddim);
        // attention (flash-style streaming, 4-way j-split, LPT order)
        attn_flash8<<<dim3(Bdim * Hdim, Sdim / 16, 1), 256, 0, stream>>>(
            Kbf, Vt, gammas + (size_t)l * Hdim, AOb, mask_type);
        // O-projection + residual -> T1 (fp32); LN1
        gemm_n64<<<dim3(8, 64, 1), 256, 0, stream>>>(
            AOb, AOb, WtO(l), WtO(l), bo_l, bo_l,
            qinf, T1, nullptr, nullptr, Ddim);
        float* x1f = ffn ? X1 : outf;
        unsigned short* x1b = ffn ? Abf : outb;
        ln_kernel<<<Mrows, 256, 0, stream>>>(T1,
            ln1g + (size_t)l * Ddim, ln1b + (size_t)l * Ddim, x1f, x1b);
        if (ffn) {
            const float* b1_l = b1 + (size_t)l * Fdim;
            const float* b2_l = b2 + (size_t)l * Ddim;
            gemm_mfma<<<dim3(Fdim / 128, Mrows / 128), 256, 0, stream>>>(
                (const __hip_bfloat16*)Abf, (const __hip_bfloat16*)Wt1(l),
                b1_l, nullptr, nullptr, Hbb, Mrows, Fdim, Ddim, 1);
            gemm_n64<<<dim3(8, 64, 1), 256, 0, stream>>>(
                Hbb, Hbb, Wt2(l), Wt2(l), b2_l, b2_l,
                X1, T1, nullptr, nullptr, Fdim);
            ln_kernel<<<Mrows, 256, 0, stream>>>(T1,
                ln2g + (size_t)l * Ddim, ln2b + (size_t)l * Ddim, outf, outb);
        }
    };

    // Block 0: knowledge encoder (y), mask1, FFN -> Ybf (bf16 only)
    conv_b<<<convBlocks, 256, 0, stream>>>(y0, Abf);
    run_block(0, y0, Abf, Abf, 1, true, nullptr, Ybf);
    // Block 1: question encoder (x), mask1, no FFN -> Xbuf/Xbf
    conv_b<<<convBlocks, 256, 0, stream>>>(x0, Abf);
    run_block(1, x0, Abf, Abf, 1, false, Xbuf, Xbf);
    // Block 2: knowledge retriever, q/k=x, v=y, mask0, FFN -> d_out (fp32)
    run_block(2, Xbuf, Xbf, Ybf, 0, true, (float*)d_out, nullptr);
}

// Round 7
// 611.676 us; speedup vs baseline: 1.2436x; 1.0261x over previous
//
#include <hip/hip_runtime.h>
#include <hip/hip_bf16.h>

// Problem dims (fixed)
#define Bdim 16
#define Sdim 512
#define Ddim 512
#define Hdim 8
#define DKdim 64
#define Fdim 2048
#define Mrows (Bdim * Sdim)   // 8192

typedef __attribute__((ext_vector_type(8))) short  frag16;   // 8 bf16 (4 VGPRs)
typedef __attribute__((ext_vector_type(4))) float  f32x4;    // MFMA acc
typedef __attribute__((ext_vector_type(8))) unsigned short ushort8;
typedef __attribute__((ext_vector_type(4))) unsigned short ushort4v;

// raw 2^x (v_exp_f32); fallback keeps semantics
#if defined(__has_builtin)
#  if __has_builtin(__builtin_amdgcn_exp2f)
#    define EXP2(x) __builtin_amdgcn_exp2f(x)
#  endif
#endif
#ifndef EXP2
#  define EXP2(x) __expf((x) * 0.6931471805599453f)
#endif
#define SC2 0.18033688011112042f   // 0.125 * log2(e)

// round-to-nearest-even fp32 -> bf16 (finite data)
__device__ __forceinline__ unsigned short f2b(float x) {
    union { float f; unsigned int u; } v; v.f = x;
    unsigned int r = (v.u + 0x7FFFu + ((v.u >> 16) & 1u)) >> 16;
    return (unsigned short)r;
}

// ---------------------------------------------------------------------------
// bf16 MFMA GEMM, 128x128 tile (used for FFN1, N=2048).
// XCD-chunked swizzle + 2-phase double-buffered K-loop.
// ---------------------------------------------------------------------------
__global__ __launch_bounds__(256) void gemm_mfma(
    const __hip_bfloat16* __restrict__ A, const __hip_bfloat16* __restrict__ Bt,
    const float* __restrict__ bias, const float* __restrict__ R,
    float* __restrict__ Cf, unsigned short* __restrict__ Cb,
    int M, int N, int K, int do_relu)
{
    __shared__ short As[2][128 * 32];
    __shared__ short Bs[2][128 * 32];

    const int t = threadIdx.x;
    const int lane = t & 63;
    const int wave = t >> 6;

    // XCD-aware chunked swizzle (grid size divisible by 8)
    const int gx = gridDim.x;
    const int nb = gx * gridDim.y;
    const int lid = blockIdx.x + gx * blockIdx.y;
    const int wid = (lid & 7) * (nb >> 3) + (lid >> 3);
    const int bm = (wid / gx) * 128;
    const int bn = (wid % gx) * 128;

    const int wm = (wave >> 1) * 64;
    const int wn = (wave & 1) * 64;

    f32x4 acc[4][4] = {};
    const int lrow = lane >> 2;
    const int lcol = (lane & 3) * 8;

    auto stage = [&](int k0, int buf) {
#pragma unroll
        for (int i = 0; i < 2; ++i) {
            const int chunk = wave * 2 + i;
            const int row = chunk * 16 + lrow;
            const __hip_bfloat16* ga = A + (size_t)(bm + row) * K + k0 + lcol;
            const __hip_bfloat16* gb = Bt + (size_t)(bn + row) * K + k0 + lcol;
            __builtin_amdgcn_global_load_lds(
                (const __attribute__((address_space(1))) unsigned int*)ga,
                (__attribute__((address_space(3))) unsigned int*)(&As[buf][chunk * 512]),
                16, 0, 0);
            __builtin_amdgcn_global_load_lds(
                (const __attribute__((address_space(1))) unsigned int*)gb,
                (__attribute__((address_space(3))) unsigned int*)(&Bs[buf][chunk * 512]),
                16, 0, 0);
        }
    };

    const int fr = lane & 15;
    const int quad = lane >> 4;
    const int nk = K >> 5;

    stage(0, 0);
    __syncthreads();

    for (int it = 0; it < nk; ++it) {
        const int buf = it & 1;
        if (it + 1 < nk) stage((it + 1) << 5, buf ^ 1);
        frag16 af[4], bfr[4];
#pragma unroll
        for (int i = 0; i < 4; ++i) {
            af[i]  = *(const frag16*)(&As[buf][(wm + i * 16 + fr) * 32 + quad * 8]);
            bfr[i] = *(const frag16*)(&Bs[buf][(wn + i * 16 + fr) * 32 + quad * 8]);
        }
#pragma unroll
        for (int mi = 0; mi < 4; ++mi)
#pragma unroll
            for (int ni = 0; ni < 4; ++ni)
                acc[mi][ni] = __builtin_amdgcn_mfma_f32_16x16x32_bf16(
                    af[mi], bfr[ni], acc[mi][ni], 0, 0, 0);
        __syncthreads();
    }

#pragma unroll
    for (int mi = 0; mi < 4; ++mi) {
#pragma unroll
        for (int r = 0; r < 4; ++r) {
            const int m = bm + wm + mi * 16 + quad * 4 + r;
#pragma unroll
            for (int ni = 0; ni < 4; ++ni) {
                const int n = bn + wn + ni * 16 + fr;
                float v = acc[mi][ni][r] + bias[n];
                if (R) v += R[(size_t)m * N + n];
                if (do_relu) v = fmaxf(v, 0.f);
                if (Cf) Cf[(size_t)m * N + n] = v;
                if (Cb) Cb[(size_t)m * N + n] = f2b(v);
            }
        }
    }
}

// ---------------------------------------------------------------------------
// bf16 MFMA GEMM, 128x64 tile, N=512 fixed, BK=64: 16 MFMA per barrier
// (halves the per-iteration stage+vmcnt+barrier fixed cost vs BK=32).
// LDS row stride is 128 B -> XOR swizzle required: global source column is
// pre-swizzled (srcslot = (lane&7)^(lane>>3), rule: gload_lds dest must stay
// linear) and the ds_read column XORs (fr&7)*8, m214/m201 construction ->
// ~2-way conflicts (free). Dual-mode via blockIdx.z:
// z=0: A0@B0^T+bias0 -> Cb (normal bf16) / Cf(+R) fp32
// z=1: A1@B1^T+bias1 -> CbT transposed Vt[b,h,d,s] bf16
// ---------------------------------------------------------------------------
__global__ __launch_bounds__(256) void gemm_n64(
    const unsigned short* __restrict__ A0, const unsigned short* __restrict__ A1,
    const unsigned short* __restrict__ B0, const unsigned short* __restrict__ B1,
    const float* __restrict__ bias0, const float* __restrict__ bias1,
    const float* __restrict__ R, float* __restrict__ Cf,
    unsigned short* __restrict__ Cb, unsigned short* __restrict__ CbT,
    int K)
{
    const int NN = 512;
    __shared__ short As[2][128 * 64];   // 32 KB
    __shared__ short Bs[2][64 * 64];    // 16 KB

    const int trans = blockIdx.z;
    const unsigned short* A  = trans ? A1 : A0;
    const unsigned short* Bt = trans ? B1 : B0;
    const float* bias        = trans ? bias1 : bias0;

    const int t = threadIdx.x;
    const int lane = t & 63;
    const int wave = t >> 6;

    // XCD-aware chunked swizzle within each z-slice (512 % 8 == 0 so the
    // z offset preserves the XCD residue).
    const int lid = blockIdx.x + 8 * blockIdx.y;          // 0..511
    const int wid = (lid & 7) * 64 + (lid >> 3);
    const int bm = (wid >> 3) * 128;
    const int bn = (wid & 7) * 64;

    const int wm = (wave >> 1) * 64;
    const int wn = (wave & 1) * 32;

    f32x4 acc[4][2] = {};

    // source-side swizzle: LDS slot (lane&7) of row r receives logical
    // col-slot (lane&7)^(r&7); here r&7 == lane>>3 by construction.
    const int srcslot = (((lane & 7) ^ (lane >> 3)) << 3);
    const int rsub = lane >> 3;          // row&7 within each 8-row group

    auto stage = [&](int k0, int buf) {
#pragma unroll
        for (int i = 0; i < 4; ++i) {
            const int row = i * 32 + wave * 8 + rsub;
            const unsigned short* ga = A + (size_t)(bm + row) * K + k0 + srcslot;
            __builtin_amdgcn_global_load_lds(
                (const __attribute__((address_space(1))) unsigned int*)ga,
                (__attribute__((address_space(3))) unsigned int*)(&As[buf][(i * 256 + wave * 64) * 8]),
                16, 0, 0);
        }
#pragma unroll
        for (int i = 0; i < 2; ++i) {
            const int row = i * 32 + wave * 8 + rsub;
            const unsigned short* gb = Bt + (size_t)(bn + row) * K + k0 + srcslot;
            __builtin_amdgcn_global_load_lds(
                (const __attribute__((address_space(1))) unsigned int*)gb,
                (__attribute__((address_space(3))) unsigned int*)(&Bs[buf][(i * 256 + wave * 64) * 8]),
                16, 0, 0);
        }
    };

    const int fr = lane & 15;
    const int quad = lane >> 4;
    const int sw = (fr & 7) << 3;        // read-side XOR (shorts)
    const int nk = K >> 6;

    stage(0, 0);
    __syncthreads();

    for (int it = 0; it < nk; ++it) {
        const int buf = it & 1;
        if (it + 1 < nk) stage((it + 1) << 6, buf ^ 1);
        frag16 af[2][4], bfr[2][2];
#pragma unroll
        for (int ks = 0; ks < 2; ++ks) {
            const int col = (ks * 32 + quad * 8) ^ sw;
#pragma unroll
            for (int i = 0; i < 4; ++i)
                af[ks][i] = *(const frag16*)(&As[buf][(wm + i * 16 + fr) * 64 + col]);
#pragma unroll
            for (int i = 0; i < 2; ++i)
                bfr[ks][i] = *(const frag16*)(&Bs[buf][(wn + i * 16 + fr) * 64 + col]);
        }
#pragma unroll
        for (int ks = 0; ks < 2; ++ks)
#pragma unroll
            for (int mi = 0; mi < 4; ++mi)
#pragma unroll
                for (int ni = 0; ni < 2; ++ni)
                    acc[mi][ni] = __builtin_amdgcn_mfma_f32_16x16x32_bf16(
                        af[ks][mi], bfr[ks][ni], acc[mi][ni], 0, 0, 0);
        __syncthreads();
    }

    if (trans) {
#pragma unroll
        for (int mi = 0; mi < 4; ++mi)
#pragma unroll
            for (int ni = 0; ni < 2; ++ni) {
                const int m = bm + wm + mi * 16 + quad * 4;
                const int n = bn + wn + ni * 16 + fr;
                ushort4v o;
#pragma unroll
                for (int r = 0; r < 4; ++r) o[r] = f2b(acc[mi][ni][r] + bias[n]);
                const int bb = m >> 9, s = m & 511;
                const int hh = n >> 6, dd = n & 63;
                *(ushort4v*)(CbT + (((size_t)((bb * Hdim + hh) * DKdim + dd)) << 9) + s) = o;
            }
        return;
    }

#pragma unroll
    for (int mi = 0; mi < 4; ++mi) {
#pragma unroll
        for (int r = 0; r < 4; ++r) {
            const int m = bm + wm + mi * 16 + quad * 4 + r;
#pragma unroll
            for (int ni = 0; ni < 2; ++ni) {
                const int n = bn + wn + ni * 16 + fr;
                float v = acc[mi][ni][r] + bias[n];
                if (R) v += R[(size_t)m * NN + n];
                if (Cf) Cf[(size_t)m * NN + n] = v;
                if (Cb) Cb[(size_t)m * NN + n] = f2b(v);
            }
        }
    }
}

// ---------------------------------------------------------------------------
// fp32 -> bf16 convert
// ---------------------------------------------------------------------------
__global__ __launch_bounds__(256) void conv_b(
    const float* __restrict__ X, unsigned short* __restrict__ Y)
{
    const size_t i = ((size_t)blockIdx.x * 256 + threadIdx.x) * 8;
    float4 a = *(const float4*)(X + i);
    float4 b = *(const float4*)(X + i + 4);
    ushort8 o;
    o[0] = f2b(a.x); o[1] = f2b(a.y); o[2] = f2b(a.z); o[3] = f2b(a.w);
    o[4] = f2b(b.x); o[5] = f2b(b.y); o[6] = f2b(b.z); o[7] = f2b(b.w);
    *(ushort8*)(Y + i) = o;
}

// ---------------------------------------------------------------------------
// ALL weight transposes fused: 1600 tiles of 64x64, [K,N] fp32 -> [N,K] bf16
// ---------------------------------------------------------------------------
__global__ __launch_bounds__(256) void wtrans_all(
    const float* __restrict__ Wk, const float* __restrict__ Wv,
    const float* __restrict__ Wo, const float* __restrict__ W1,
    const float* __restrict__ W2, unsigned short* __restrict__ dst)
{
    const int bid = blockIdx.x;
    const float* src; unsigned short* d; int K, N, tk, tn;
    if (bid < 576) {
        const int mat = bid >> 6, tile = bid & 63;
        const int l = mat / 3, wch = mat % 3;
        const float* W = (wch == 0) ? Wk : (wch == 1) ? Wv : Wo;
        src = W + (size_t)l * 262144;
        d = dst + (size_t)mat * 262144;
        K = 512; N = 512; tn = tile & 7; tk = tile >> 3;
    } else if (bid < 1088) {
        const int idx = bid - 576, l2 = idx >> 8, tile = idx & 255;
        src = W1 + (size_t)(l2 * 2) * (512 * 2048);
        d = dst + 9 * 262144 + (size_t)l2 * (512 * 2048);
        K = 512; N = 2048; tn = tile & 31; tk = tile >> 5;
    } else {
        const int idx = bid - 1088, l2 = idx >> 8, tile = idx & 255;
        src = W2 + (size_t)(l2 * 2) * (2048 * 512);
        d = dst + 9 * 262144 + 2 * (512 * 2048) + (size_t)l2 * (2048 * 512);
        K = 2048; N = 512; tn = tile & 7; tk = tile >> 3;
    }
    const int n0 = tn * 64, k0 = tk * 64;
    __shared__ float T[64][65];
    const int t = threadIdx.x;
    const int kl = t >> 4, n4 = (t & 15) << 2;
#pragma unroll
    for (int it = 0; it < 4; ++it) {
        const int k = kl + it * 16;
        float4 v = *(const float4*)(src + (size_t)(k0 + k) * N + n0 + n4);
        T[n4 + 0][k] = v.x; T[n4 + 1][k] = v.y;
        T[n4 + 2][k] = v.z; T[n4 + 3][k] = v.w;
    }
    __syncthreads();
    const int nl = t >> 3, k8 = (t & 7) << 3;
#pragma unroll
    for (int it = 0; it < 2; ++it) {
        const int n = nl + it * 32;
        ushort8 o;
#pragma unroll
        for (int c = 0; c < 8; ++c) o[c] = f2b(T[n][k8 + c]);
        *(ushort8*)(d + (size_t)(n0 + n) * K + k0 + k8) = o;
    }
}

// ---------------------------------------------------------------------------
// Flash-style monotonic attention v8. ONE 16-row q-tile per 256-thread
// block, j-range split across FOUR waves (jn/u == w mod 4). Rationale: all
// prior versions (68-74us) were bounded by the same critical path — the
// heaviest tile's j-stream processed by only 2 waves. 4-way split halves
// the per-wave serial path. Grid (128 bh, 32 ranks) = 4096 blocks = 16384
// waves = 2 residency rounds at 32 waves/CU, with LPT dispatch order
// (heaviest tile first; consecutive blocks share a rank so co-resident
// work per CU is equal) so refill keeps residency flat and the tail is
// the cheapest tiles. 4-way combine: sums via LDS; oacc via 2-step tree.
// Fully-masked row (mask0, i==0): uniform 1/512 over ALL j.
// ---------------------------------------------------------------------------
__global__ __launch_bounds__(256, 8) void attn_flash8(
    const unsigned short* __restrict__ Kb,   // [B*S, D] bf16 (Q == K)
    const unsigned short* __restrict__ Vt,   // [B,H,DK,S] bf16
    const float* __restrict__ gam,
    unsigned short* __restrict__ Ob,         // [B*S, D] bf16
    int mask_type)
{
    __shared__ float CTw[16 * 33];               // cross-tile strict suffix
    __shared__ unsigned short Pst[4][16 * 36];   // P staging (A-frag layout, per wave)
    __shared__ float S1s[4][16];                 // sum1 partials [w][row]
    __shared__ float S2s[4][16];                 // sum2 partials
    __shared__ float OaccA[16 * 66];             // oacc combine buffers
    __shared__ float OaccB[16 * 66];

    const int h = blockIdx.x & 7, b = blockIdx.x >> 3;
    const int rk = blockIdx.y;                   // LPT rank: 0 = heaviest
    const int tile = mask_type ? (31 - rk) : (rk == 0 ? 0 : 32 - rk);

    const int t = threadIdx.x, lane = t & 63, w = t >> 6;   // w: j-split slot
    const int quad = lane >> 4, fr = lane & 15;
    const int q0 = tile * 16;
    const int iRow = q0 + fr;                // this lane's q row

    const unsigned short* kbase = Kb + (size_t)b * Sdim * Ddim + h * DKdim;
    const unsigned short* vtb = Vt + (size_t)(b * Hdim + h) * DKdim * Sdim;
    const float gneg2 = -log1pf(__expf(gam[h])) * 1.4426950408889634f;

    // Q as B-operand: rows q0+fr
    frag16 aq0 = *(const frag16*)(kbase + (size_t)(q0 + fr) * Ddim + quad * 8);
    frag16 aq1 = *(const frag16*)(kbase + (size_t)(q0 + fr) * Ddim + 32 + quad * 8);

    // ---- Pass 1: sum1 partials + per-tile totals into CT (4-way jn split)
    float psum = 0.f;
    for (int jn = w; jn <= tile; jn += 4) {
        frag16 k0 = *(const frag16*)(kbase + (size_t)(jn * 16 + fr) * Ddim + quad * 8);
        frag16 k1 = *(const frag16*)(kbase + (size_t)(jn * 16 + fr) * Ddim + 32 + quad * 8);
        f32x4 z = {0.f, 0.f, 0.f, 0.f};
        z = __builtin_amdgcn_mfma_f32_16x16x32_bf16(k0, aq0, z, 0, 0, 0);
        z = __builtin_amdgcn_mfma_f32_16x16x32_bf16(k1, aq1, z, 0, 0, 0);
        float tq = 0.f;
        if (jn < tile) {                 // fully-valid tile (both masks)
#pragma unroll
            for (int r = 0; r < 4; ++r) tq += EXP2(z[r] * SC2);
        } else {                         // diagonal tile
#pragma unroll
            for (int r = 0; r < 4; ++r) {
                const bool valid = mask_type ? (quad * 4 + r <= fr)
                                             : (quad * 4 + r < fr);
                tq += valid ? EXP2(z[r] * SC2) : 0.f;
            }
        }
        psum += tq;
        float tt = tq;
        tt += __shfl_xor(tt, 16);
        tt += __shfl_xor(tt, 32);
        if (quad == 0) CTw[fr * 33 + jn] = tt;
    }
    {
        float s1 = psum;
        s1 += __shfl_xor(s1, 16);
        s1 += __shfl_xor(s1, 32);
        if (lane < 16) S1s[w][lane] = s1;
    }
    __syncthreads();

    // totals -> strict cross-tile suffix (wave 0; rows by lanes 0..15)
    if (w == 0 && lane < 16) {
        float run = 0.f;
        for (int jn = tile; jn >= 0; --jn) {
            const float tv = CTw[lane * 33 + jn];
            CTw[lane * 33 + jn] = run;
            run += tv;
        }
    }
    __syncthreads();

    const float rsum1 = 1.f / (S1s[0][fr] + S1s[1][fr] + S1s[2][fr] + S1s[3][fr]);
    unsigned short* Pw = Pst[w];
    const bool fm_blk = (mask_type == 0) && (tile == 0);
    const bool fmrow = fm_blk && (fr == 0);
    const int umax = fm_blk ? (Sdim / 32 - 1) : (tile >> 1);
    float sum2p = 0.f;
    f32x4 oacc[4] = {};

    // ---- Pass 2: independent u-tiles, 4-way split, online PV
    for (int u = umax - w; u >= 0; u -= 4) {
#pragma unroll
        for (int half = 0; half < 2; ++half) {
            const int jn = 2 * u + half;
            uint2 pku;
            if (jn > tile) {
                // empty tile: P=0, except mask0 row-0 uniform case (P=1)
                const unsigned int pv = fmrow ? 0x3F803F80u : 0u;
                pku.x = pv; pku.y = pv;
                sum2p += fmrow ? 4.f : 0.f;
            } else {
                frag16 k0 = *(const frag16*)(kbase + (size_t)(jn * 16 + fr) * Ddim + quad * 8);
                frag16 k1 = *(const frag16*)(kbase + (size_t)(jn * 16 + fr) * Ddim + 32 + quad * 8);
                f32x4 z = {0.f, 0.f, 0.f, 0.f};
                z = __builtin_amdgcn_mfma_f32_16x16x32_bf16(k0, aq0, z, 0, 0, 0);
                z = __builtin_amdgcn_mfma_f32_16x16x32_bf16(k1, aq1, z, 0, 0, 0);
                const bool full = (jn < tile);   // wave-uniform
                float s2r[4], lsuf[4];
                float tq = 0.f;
#pragma unroll
                for (int r = 3; r >= 0; --r) {
                    lsuf[r] = tq;                // strict suffix within 4-run
                    s2r[r] = z[r] * SC2;
                    float e1 = EXP2(s2r[r]);
                    if (!full) {
                        const bool valid = mask_type ? (quad * 4 + r <= fr)
                                                     : (quad * 4 + r < fr);
                        e1 = valid ? e1 : 0.f;
                    }
                    tq += e1;
                }
                // strict suffix over quads (2 guarded shfl_down)
                float incl = tq;
                {
                    float u1 = __shfl_down(incl, 16);
                    incl += (quad < 3) ? u1 : 0.f;
                    float u2 = __shfl_down(incl, 32);
                    incl += (quad < 2) ? u2 : 0.f;
                }
                const float base = CTw[fr * 33 + jn] + (incl - tq);
                const float pos0 = (float)(iRow - (jn * 16 + quad * 4));
                float e2v[4];
#pragma unroll
                for (int r = 0; r < 4; ++r) {
                    const float ratio = (base + lsuf[r]) * rsum1;   // >= 0
                    const float arg = ratio * fabsf(pos0 - (float)r);
                    const float te = fmaxf(EXP2(gneg2 * sqrtf(arg)), 1e-5f); // <= 1
                    float e2 = EXP2(s2r[r] * te);
                    if (!full) {
                        const bool valid = mask_type ? (quad * 4 + r <= fr)
                                                     : (quad * 4 + r < fr);
                        e2 = valid ? e2 : (fmrow ? 1.f : 0.f);
                    }
                    sum2p += e2;
                    e2v[r] = e2;
                }
                union { __hip_bfloat162 hh; unsigned int u; } c0, c1;
                c0.hh = __float22bfloat162_rn(make_float2(e2v[0], e2v[1]));
                c1.hh = __float22bfloat162_rn(make_float2(e2v[2], e2v[3]));
                pku.x = c0.u; pku.y = c1.u;
            }
            *(uint2*)(Pw + fr * 36 + half * 16 + quad * 4) = pku;
        }
        // PV over this pair's 32-wide window (A = P from LDS, B = Vt)
        frag16 pf = *(const frag16*)(Pw + fr * 36 + quad * 8);
        const int jb = u * 32;
#pragma unroll
        for (int dt = 0; dt < 4; ++dt) {
            frag16 vf = *(const frag16*)(vtb + (size_t)(dt * 16 + fr) * Sdim + jb + quad * 8);
            oacc[dt] = __builtin_amdgcn_mfma_f32_16x16x32_bf16(pf, vf, oacc[dt], 0, 0, 0);
        }
    }

    // ---- combine the four waves' partials (2-step tree through 2 buffers)
    {
        float s2 = sum2p;
        s2 += __shfl_xor(s2, 16);
        s2 += __shfl_xor(s2, 32);
        if (lane < 16) S2s[w][lane] = s2;
    }
    if (w == 1) {
#pragma unroll
        for (int dt = 0; dt < 4; ++dt)
#pragma unroll
            for (int r = 0; r < 4; ++r)
                OaccA[(quad * 4 + r) * 66 + dt * 16 + fr] = oacc[dt][r];
    }
    if (w == 3) {
#pragma unroll
        for (int dt = 0; dt < 4; ++dt)
#pragma unroll
            for (int r = 0; r < 4; ++r)
                OaccB[(quad * 4 + r) * 66 + dt * 16 + fr] = oacc[dt][r];
    }
    __syncthreads();
    if (w == 0) {
#pragma unroll
        for (int dt = 0; dt < 4; ++dt)
#pragma unroll
            for (int r = 0; r < 4; ++r)
                oacc[dt][r] += OaccA[(quad * 4 + r) * 66 + dt * 16 + fr];
    }
    if (w == 2) {
#pragma unroll
        for (int dt = 0; dt < 4; ++dt)
#pragma unroll
            for (int r = 0; r < 4; ++r)
                oacc[dt][r] += OaccB[(quad * 4 + r) * 66 + dt * 16 + fr];
    }
    __syncthreads();
    if (w == 2) {
#pragma unroll
        for (int dt = 0; dt < 4; ++dt)
#pragma unroll
            for (int r = 0; r < 4; ++r)
                OaccA[(quad * 4 + r) * 66 + dt * 16 + fr] = oacc[dt][r];
    }
    __syncthreads();

    if (w == 0) {
        const float rs2 = 1.f / (S2s[0][fr] + S2s[1][fr] + S2s[2][fr] + S2s[3][fr]);
        float rs2q[4];
#pragma unroll
        for (int r = 0; r < 4; ++r) rs2q[r] = __shfl(rs2, quad * 4 + r);

        // O rows q0+quad*4+r, cols dt*16+fr
        unsigned short* obase = Ob + ((size_t)(b * Sdim + q0)) * Ddim + h * DKdim;
#pragma unroll
        for (int dt = 0; dt < 4; ++dt)
#pragma unroll
            for (int r = 0; r < 4; ++r) {
                const float v = oacc[dt][r] + OaccA[(quad * 4 + r) * 66 + dt * 16 + fr];
                obase[(size_t)(quad * 4 + r) * Ddim + dt * 16 + fr] = f2b(v * rs2q[r]);
            }
    }
}

// ---------------------------------------------------------------------------
// LayerNorm over last dim (512); fp32 out (nullable) + bf16 out (nullable).
// ---------------------------------------------------------------------------
__global__ __launch_bounds__(256) void ln_kernel(
    const float* __restrict__ X, const float* __restrict__ g,
    const float* __restrict__ bta, float* __restrict__ Y,
    unsigned short* __restrict__ Yb)
{
    const int row = blockIdx.x;
    const int t = threadIdx.x;
    __shared__ float r1[256], r2[256];
    const float* x = X + (size_t)row * Ddim;
    float a = x[t], b = x[t + 256];
    r1[t] = a + b;
    r2[t] = a * a + b * b;
    __syncthreads();
    for (int off = 128; off; off >>= 1) {
        if (t < off) { r1[t] += r1[t + off]; r2[t] += r2[t + off]; }
        __syncthreads();
    }
    float mean = r1[0] * (1.f / Ddim);
    float var = r2[0] * (1.f / Ddim) - mean * mean;
    float rs = rsqrtf(var + 1e-5f);
    float y0 = (a - mean) * rs * g[t] + bta[t];
    float y1 = (b - mean) * rs * g[t + 256] + bta[t + 256];
    if (Y) {
        float* y = Y + (size_t)row * Ddim;
        y[t] = y0;
        y[t + 256] = y1;
    }
    if (Yb) {
        unsigned short* yb = Yb + (size_t)row * Ddim;
        yb[t] = f2b(y0);
        yb[t + 256] = f2b(y1);
    }
}

// ---------------------------------------------------------------------------
extern "C" void kernel_launch(void* const* d_in, const int* in_sizes, int n_in,
                              void* d_out, int out_size, void* d_ws, size_t ws_size,
                              hipStream_t stream)
{
    const float* x0     = (const float*)d_in[0];
    const float* y0     = (const float*)d_in[1];
    const float* Wk     = (const float*)d_in[2];
    const float* bk     = (const float*)d_in[3];
    const float* Wv     = (const float*)d_in[4];
    const float* bv     = (const float*)d_in[5];
    const float* Wo     = (const float*)d_in[6];
    const float* bo     = (const float*)d_in[7];
    const float* gammas = (const float*)d_in[8];
    const float* ln1g   = (const float*)d_in[9];
    const float* ln1b   = (const float*)d_in[10];
    const float* W1     = (const float*)d_in[11];
    const float* b1     = (const float*)d_in[12];
    const float* W2     = (const float*)d_in[13];
    const float* b2     = (const float*)d_in[14];
    const float* ln2g   = (const float*)d_in[15];
    const float* ln2b   = (const float*)d_in[16];

    const size_t NBSD = (size_t)Mrows * Ddim;   // 4,194,304
    float* ws = (float*)d_ws;
    float* T1   = ws;
    float* X1   = T1 + NBSD;
    float* Xbuf = X1 + NBSD;
    unsigned short* Kbf = (unsigned short*)(Xbuf + NBSD);
    unsigned short* Vt  = Kbf + NBSD;
    unsigned short* AOb = Vt + NBSD;
    unsigned short* Abf = AOb + NBSD;
    unsigned short* Xbf = Abf + NBSD;
    unsigned short* Ybf = Xbf + NBSD;
    unsigned short* Hbb = Ybf + NBSD;                       // [M,F]
    unsigned short* WtAll = Hbb + (size_t)Mrows * Fdim;

    auto WtK = [&](int l) { return WtAll + (size_t)(l * 3 + 0) * 262144; };
    auto WtV = [&](int l) { return WtAll + (size_t)(l * 3 + 1) * 262144; };
    auto WtO = [&](int l) { return WtAll + (size_t)(l * 3 + 2) * 262144; };
    auto Wt1 = [&](int l) { return WtAll + 9 * 262144 + (size_t)(l >> 1) * (512 * 2048); };
    auto Wt2 = [&](int l) { return WtAll + 9 * 262144 + 2 * (512 * 2048) + (size_t)(l >> 1) * (2048 * 512); };

    const int convBlocks = (int)(NBSD / 2048);

    wtrans_all<<<1600, 256, 0, stream>>>(Wk, Wv, Wo, W1, W2, WtAll);

    auto run_block = [&](int l, const float* qinf, const unsigned short* qinb,
                         const unsigned short* vinb, int mask_type, bool ffn,
                         float* outf, unsigned short* outb) {
        const float* bk_l = bk + (size_t)l * Ddim;
        const float* bv_l = bv + (size_t)l * Ddim;
        const float* bo_l = bo + (size_t)l * Ddim;

        // K (=Q) + V projections in one launch (z=0: K->Kbf, z=1: V->Vt)
        gemm_n64<<<dim3(8, 64, 2), 256, 0, stream>>>(
            qinb, vinb, WtK(l), WtV(l), bk_l, bv_l,
            nullptr, nullptr, Kbf, Vt, Ddim);
        // attention (flash-style streaming, 4-way j-split, LPT order)
        attn_flash8<<<dim3(Bdim * Hdim, Sdim / 16, 1), 256, 0, stream>>>(
            Kbf, Vt, gammas + (size_t)l * Hdim, AOb, mask_type);
        // O-projection + residual -> T1 (fp32); LN1
        gemm_n64<<<dim3(8, 64, 1), 256, 0, stream>>>(
            AOb, AOb, WtO(l), WtO(l), bo_l, bo_l,
            qinf, T1, nullptr, nullptr, Ddim);
        float* x1f = ffn ? X1 : outf;
        unsigned short* x1b = ffn ? Abf : outb;
        ln_kernel<<<Mrows, 256, 0, stream>>>(T1,
            ln1g + (size_t)l * Ddim, ln1b + (size_t)l * Ddim, x1f, x1b);
        if (ffn) {
            const float* b1_l = b1 + (size_t)l * Fdim;
            const float* b2_l = b2 + (size_t)l * Ddim;
            gemm_mfma<<<dim3(Fdim / 128, Mrows / 128), 256, 0, stream>>>(
                (const __hip_bfloat16*)Abf, (const __hip_bfloat16*)Wt1(l),
                b1_l, nullptr, nullptr, Hbb, Mrows, Fdim, Ddim, 1);
            gemm_n64<<<dim3(8, 64, 1), 256, 0, stream>>>(
                Hbb, Hbb, Wt2(l), Wt2(l), b2_l, b2_l,
                X1, T1, nullptr, nullptr, Fdim);
            ln_kernel<<<Mrows, 256, 0, stream>>>(T1,
                ln2g + (size_t)l * Ddim, ln2b + (size_t)l * Ddim, outf, outb);
        }
    };

    // Block 0: knowledge encoder (y), mask1, FFN -> Ybf (bf16 only)
    conv_b<<<convBlocks, 256, 0, stream>>>(y0, Abf);
    run_block(0, y0, Abf, Abf, 1, true, nullptr, Ybf);
    // Block 1: question encoder (x), mask1, no FFN -> Xbuf/Xbf
    conv_b<<<convBlocks, 256, 0, stream>>>(x0, Abf);
    run_block(1, x0, Abf, Abf, 1, false, Xbuf, Xbf);
    // Block 2: knowledge retriever, q/k=x, v=y, mask0, FFN -> d_out (fp32)
    run_block(2, Xbuf, Xbf, Ybf, 0, true, (float*)d_out, nullptr);
}

// Round 8
// 575.337 us; speedup vs baseline: 1.3221x; 1.0632x over previous
//
#include <hip/hip_runtime.h>
#include <hip/hip_bf16.h>

// Problem dims (fixed)
#define Bdim 16
#define Sdim 512
#define Ddim 512
#define Hdim 8
#define DKdim 64
#define Fdim 2048
#define Mrows (Bdim * Sdim)   // 8192

typedef __attribute__((ext_vector_type(8))) short  frag16;   // 8 bf16 (4 VGPRs)
typedef __attribute__((ext_vector_type(4))) float  f32x4;    // MFMA acc
typedef __attribute__((ext_vector_type(8))) unsigned short ushort8;
typedef __attribute__((ext_vector_type(4))) unsigned short ushort4v;

// raw 2^x (v_exp_f32); fallback keeps semantics
#if defined(__has_builtin)
#  if __has_builtin(__builtin_amdgcn_exp2f)
#    define EXP2(x) __builtin_amdgcn_exp2f(x)
#  endif
#endif
#ifndef EXP2
#  define EXP2(x) __expf((x) * 0.6931471805599453f)
#endif
#define SC2 0.18033688011112042f   // 0.125 * log2(e)

// round-to-nearest-even fp32 -> bf16 (finite data)
__device__ __forceinline__ unsigned short f2b(float x) {
    union { float f; unsigned int u; } v; v.f = x;
    unsigned int r = (v.u + 0x7FFFu + ((v.u >> 16) & 1u)) >> 16;
    return (unsigned short)r;
}

// ---------------------------------------------------------------------------
// bf16 MFMA GEMM, 128x128 tile (used for FFN1, N=2048).
// XCD-chunked swizzle + 2-phase double-buffered K-loop.
// ---------------------------------------------------------------------------
__global__ __launch_bounds__(256) void gemm_mfma(
    const __hip_bfloat16* __restrict__ A, const __hip_bfloat16* __restrict__ Bt,
    const float* __restrict__ bias, const float* __restrict__ R,
    float* __restrict__ Cf, unsigned short* __restrict__ Cb,
    int M, int N, int K, int do_relu)
{
    __shared__ short As[2][128 * 32];
    __shared__ short Bs[2][128 * 32];

    const int t = threadIdx.x;
    const int lane = t & 63;
    const int wave = t >> 6;

    // XCD-aware chunked swizzle (grid size divisible by 8)
    const int gx = gridDim.x;
    const int nb = gx * gridDim.y;
    const int lid = blockIdx.x + gx * blockIdx.y;
    const int wid = (lid & 7) * (nb >> 3) + (lid >> 3);
    const int bm = (wid / gx) * 128;
    const int bn = (wid % gx) * 128;

    const int wm = (wave >> 1) * 64;
    const int wn = (wave & 1) * 64;

    f32x4 acc[4][4] = {};
    const int lrow = lane >> 2;
    const int lcol = (lane & 3) * 8;

    auto stage = [&](int k0, int buf) {
#pragma unroll
        for (int i = 0; i < 2; ++i) {
            const int chunk = wave * 2 + i;
            const int row = chunk * 16 + lrow;
            const __hip_bfloat16* ga = A + (size_t)(bm + row) * K + k0 + lcol;
            const __hip_bfloat16* gb = Bt + (size_t)(bn + row) * K + k0 + lcol;
            __builtin_amdgcn_global_load_lds(
                (const __attribute__((address_space(1))) unsigned int*)ga,
                (__attribute__((address_space(3))) unsigned int*)(&As[buf][chunk * 512]),
                16, 0, 0);
            __builtin_amdgcn_global_load_lds(
                (const __attribute__((address_space(1))) unsigned int*)gb,
                (__attribute__((address_space(3))) unsigned int*)(&Bs[buf][chunk * 512]),
                16, 0, 0);
        }
    };

    const int fr = lane & 15;
    const int quad = lane >> 4;
    const int nk = K >> 5;

    stage(0, 0);
    __syncthreads();

    for (int it = 0; it < nk; ++it) {
        const int buf = it & 1;
        if (it + 1 < nk) stage((it + 1) << 5, buf ^ 1);
        frag16 af[4], bfr[4];
#pragma unroll
        for (int i = 0; i < 4; ++i) {
            af[i]  = *(const frag16*)(&As[buf][(wm + i * 16 + fr) * 32 + quad * 8]);
            bfr[i] = *(const frag16*)(&Bs[buf][(wn + i * 16 + fr) * 32 + quad * 8]);
        }
#pragma unroll
        for (int mi = 0; mi < 4; ++mi)
#pragma unroll
            for (int ni = 0; ni < 4; ++ni)
                acc[mi][ni] = __builtin_amdgcn_mfma_f32_16x16x32_bf16(
                    af[mi], bfr[ni], acc[mi][ni], 0, 0, 0);
        __syncthreads();
    }

#pragma unroll
    for (int mi = 0; mi < 4; ++mi) {
#pragma unroll
        for (int r = 0; r < 4; ++r) {
            const int m = bm + wm + mi * 16 + quad * 4 + r;
#pragma unroll
            for (int ni = 0; ni < 4; ++ni) {
                const int n = bn + wn + ni * 16 + fr;
                float v = acc[mi][ni][r] + bias[n];
                if (R) v += R[(size_t)m * N + n];
                if (do_relu) v = fmaxf(v, 0.f);
                if (Cf) Cf[(size_t)m * N + n] = v;
                if (Cb) Cb[(size_t)m * N + n] = f2b(v);
            }
        }
    }
}

// ---------------------------------------------------------------------------
// bf16 MFMA GEMM, 128x64 tile, N=512 fixed, BK=64 (16 MFMA per barrier).
// XOR-swizzled LDS (source pre-swizzle + read-side XOR). Dual-mode via z:
// z=0: A0@B0^T+bias0 -> Cb / Cf(+R);  z=1: A1@B1^T+bias1 -> CbT (Vt layout)
// ---------------------------------------------------------------------------
__global__ __launch_bounds__(256) void gemm_n64(
    const unsigned short* __restrict__ A0, const unsigned short* __restrict__ A1,
    const unsigned short* __restrict__ B0, const unsigned short* __restrict__ B1,
    const float* __restrict__ bias0, const float* __restrict__ bias1,
    const float* __restrict__ R, float* __restrict__ Cf,
    unsigned short* __restrict__ Cb, unsigned short* __restrict__ CbT,
    int K)
{
    const int NN = 512;
    __shared__ short As[2][128 * 64];   // 32 KB
    __shared__ short Bs[2][64 * 64];    // 16 KB

    const int trans = blockIdx.z;
    const unsigned short* A  = trans ? A1 : A0;
    const unsigned short* Bt = trans ? B1 : B0;
    const float* bias        = trans ? bias1 : bias0;

    const int t = threadIdx.x;
    const int lane = t & 63;
    const int wave = t >> 6;

    const int lid = blockIdx.x + 8 * blockIdx.y;          // 0..511
    const int wid = (lid & 7) * 64 + (lid >> 3);
    const int bm = (wid >> 3) * 128;
    const int bn = (wid & 7) * 64;

    const int wm = (wave >> 1) * 64;
    const int wn = (wave & 1) * 32;

    f32x4 acc[4][2] = {};

    const int srcslot = (((lane & 7) ^ (lane >> 3)) << 3);
    const int rsub = lane >> 3;

    auto stage = [&](int k0, int buf) {
#pragma unroll
        for (int i = 0; i < 4; ++i) {
            const int row = i * 32 + wave * 8 + rsub;
            const unsigned short* ga = A + (size_t)(bm + row) * K + k0 + srcslot;
            __builtin_amdgcn_global_load_lds(
                (const __attribute__((address_space(1))) unsigned int*)ga,
                (__attribute__((address_space(3))) unsigned int*)(&As[buf][(i * 256 + wave * 64) * 8]),
                16, 0, 0);
        }
#pragma unroll
        for (int i = 0; i < 2; ++i) {
            const int row = i * 32 + wave * 8 + rsub;
            const unsigned short* gb = Bt + (size_t)(bn + row) * K + k0 + srcslot;
            __builtin_amdgcn_global_load_lds(
                (const __attribute__((address_space(1))) unsigned int*)gb,
                (__attribute__((address_space(3))) unsigned int*)(&Bs[buf][(i * 256 + wave * 64) * 8]),
                16, 0, 0);
        }
    };

    const int fr = lane & 15;
    const int quad = lane >> 4;
    const int sw = (fr & 7) << 3;
    const int nk = K >> 6;

    stage(0, 0);
    __syncthreads();

    for (int it = 0; it < nk; ++it) {
        const int buf = it & 1;
        if (it + 1 < nk) stage((it + 1) << 6, buf ^ 1);
        frag16 af[2][4], bfr[2][2];
#pragma unroll
        for (int ks = 0; ks < 2; ++ks) {
            const int col = (ks * 32 + quad * 8) ^ sw;
#pragma unroll
            for (int i = 0; i < 4; ++i)
                af[ks][i] = *(const frag16*)(&As[buf][(wm + i * 16 + fr) * 64 + col]);
#pragma unroll
            for (int i = 0; i < 2; ++i)
                bfr[ks][i] = *(const frag16*)(&Bs[buf][(wn + i * 16 + fr) * 64 + col]);
        }
#pragma unroll
        for (int ks = 0; ks < 2; ++ks)
#pragma unroll
            for (int mi = 0; mi < 4; ++mi)
#pragma unroll
                for (int ni = 0; ni < 2; ++ni)
                    acc[mi][ni] = __builtin_amdgcn_mfma_f32_16x16x32_bf16(
                        af[ks][mi], bfr[ks][ni], acc[mi][ni], 0, 0, 0);
        __syncthreads();
    }

    if (trans) {
#pragma unroll
        for (int mi = 0; mi < 4; ++mi)
#pragma unroll
            for (int ni = 0; ni < 2; ++ni) {
                const int m = bm + wm + mi * 16 + quad * 4;
                const int n = bn + wn + ni * 16 + fr;
                ushort4v o;
#pragma unroll
                for (int r = 0; r < 4; ++r) o[r] = f2b(acc[mi][ni][r] + bias[n]);
                const int bb = m >> 9, s = m & 511;
                const int hh = n >> 6, dd = n & 63;
                *(ushort4v*)(CbT + (((size_t)((bb * Hdim + hh) * DKdim + dd)) << 9) + s) = o;
            }
        return;
    }

#pragma unroll
    for (int mi = 0; mi < 4; ++mi) {
#pragma unroll
        for (int r = 0; r < 4; ++r) {
            const int m = bm + wm + mi * 16 + quad * 4 + r;
#pragma unroll
            for (int ni = 0; ni < 2; ++ni) {
                const int n = bn + wn + ni * 16 + fr;
                float v = acc[mi][ni][r] + bias[n];
                if (R) v += R[(size_t)m * NN + n];
                if (Cf) Cf[(size_t)m * NN + n] = v;
                if (Cb) Cb[(size_t)m * NN + n] = f2b(v);
            }
        }
    }
}

// ---------------------------------------------------------------------------
// 4-way KV projection: z in 0..3 selects {L0-K, L0-V(trans), L1-K, L1-V(trans)}.
// Same verified BK=64 swizzled core as gemm_n64; K fixed at 512.
// ---------------------------------------------------------------------------
__global__ __launch_bounds__(256) void gemm_kv4(
    const unsigned short* __restrict__ Ya, const unsigned short* __restrict__ Xa,
    const unsigned short* __restrict__ BtK0, const unsigned short* __restrict__ BtV0,
    const unsigned short* __restrict__ BtK1, const unsigned short* __restrict__ BtV1,
    const float* __restrict__ bk0, const float* __restrict__ bv0,
    const float* __restrict__ bk1, const float* __restrict__ bv1,
    unsigned short* __restrict__ K0, unsigned short* __restrict__ V0t,
    unsigned short* __restrict__ K1, unsigned short* __restrict__ V1t)
{
    const int K = 512;
    __shared__ short As[2][128 * 64];
    __shared__ short Bs[2][64 * 64];

    const int z = blockIdx.z;
    const unsigned short* A  = (z < 2) ? Ya : Xa;
    const unsigned short* Bt = (z == 0) ? BtK0 : (z == 1) ? BtV0 : (z == 2) ? BtK1 : BtV1;
    const float* bias        = (z == 0) ? bk0 : (z == 1) ? bv0 : (z == 2) ? bk1 : bv1;
    const int trans = z & 1;

    const int t = threadIdx.x;
    const int lane = t & 63;
    const int wave = t >> 6;

    const int lid = blockIdx.x + 8 * blockIdx.y;
    const int wid = (lid & 7) * 64 + (lid >> 3);
    const int bm = (wid >> 3) * 128;
    const int bn = (wid & 7) * 64;

    const int wm = (wave >> 1) * 64;
    const int wn = (wave & 1) * 32;

    f32x4 acc[4][2] = {};
    const int srcslot = (((lane & 7) ^ (lane >> 3)) << 3);
    const int rsub = lane >> 3;

    auto stage = [&](int k0, int buf) {
#pragma unroll
        for (int i = 0; i < 4; ++i) {
            const int row = i * 32 + wave * 8 + rsub;
            const unsigned short* ga = A + (size_t)(bm + row) * K + k0 + srcslot;
            __builtin_amdgcn_global_load_lds(
                (const __attribute__((address_space(1))) unsigned int*)ga,
                (__attribute__((address_space(3))) unsigned int*)(&As[buf][(i * 256 + wave * 64) * 8]),
                16, 0, 0);
        }
#pragma unroll
        for (int i = 0; i < 2; ++i) {
            const int row = i * 32 + wave * 8 + rsub;
            const unsigned short* gb = Bt + (size_t)(bn + row) * K + k0 + srcslot;
            __builtin_amdgcn_global_load_lds(
                (const __attribute__((address_space(1))) unsigned int*)gb,
                (__attribute__((address_space(3))) unsigned int*)(&Bs[buf][(i * 256 + wave * 64) * 8]),
                16, 0, 0);
        }
    };

    const int fr = lane & 15;
    const int quad = lane >> 4;
    const int sw = (fr & 7) << 3;
    const int nk = K >> 6;

    stage(0, 0);
    __syncthreads();

    for (int it = 0; it < nk; ++it) {
        const int buf = it & 1;
        if (it + 1 < nk) stage((it + 1) << 6, buf ^ 1);
        frag16 af[2][4], bfr[2][2];
#pragma unroll
        for (int ks = 0; ks < 2; ++ks) {
            const int col = (ks * 32 + quad * 8) ^ sw;
#pragma unroll
            for (int i = 0; i < 4; ++i)
                af[ks][i] = *(const frag16*)(&As[buf][(wm + i * 16 + fr) * 64 + col]);
#pragma unroll
            for (int i = 0; i < 2; ++i)
                bfr[ks][i] = *(const frag16*)(&Bs[buf][(wn + i * 16 + fr) * 64 + col]);
        }
#pragma unroll
        for (int ks = 0; ks < 2; ++ks)
#pragma unroll
            for (int mi = 0; mi < 4; ++mi)
#pragma unroll
                for (int ni = 0; ni < 2; ++ni)
                    acc[mi][ni] = __builtin_amdgcn_mfma_f32_16x16x32_bf16(
                        af[ks][mi], bfr[ks][ni], acc[mi][ni], 0, 0, 0);
        __syncthreads();
    }

    if (trans) {
        unsigned short* CbT = (z == 1) ? V0t : V1t;
#pragma unroll
        for (int mi = 0; mi < 4; ++mi)
#pragma unroll
            for (int ni = 0; ni < 2; ++ni) {
                const int m = bm + wm + mi * 16 + quad * 4;
                const int n = bn + wn + ni * 16 + fr;
                ushort4v o;
#pragma unroll
                for (int r = 0; r < 4; ++r) o[r] = f2b(acc[mi][ni][r] + bias[n]);
                const int bb = m >> 9, s = m & 511;
                const int hh = n >> 6, dd = n & 63;
                *(ushort4v*)(CbT + (((size_t)((bb * Hdim + hh) * DKdim + dd)) << 9) + s) = o;
            }
    } else {
        unsigned short* Cb = (z == 0) ? K0 : K1;
#pragma unroll
        for (int mi = 0; mi < 4; ++mi)
#pragma unroll
            for (int r = 0; r < 4; ++r) {
                const int m = bm + wm + mi * 16 + quad * 4 + r;
#pragma unroll
                for (int ni = 0; ni < 2; ++ni) {
                    const int n = bn + wn + ni * 16 + fr;
                    Cb[(size_t)m * 512 + n] = f2b(acc[mi][ni][r] + bias[n]);
                }
            }
    }
}

// ---------------------------------------------------------------------------
// Dual O-projection: z in {0,1} selects layer; both normal mode, fp32 out
// (C = A@Bt + bias + R). Same verified BK=64 swizzled core. K fixed 512.
// ---------------------------------------------------------------------------
__global__ __launch_bounds__(256) void gemm_o2(
    const unsigned short* __restrict__ A0, const unsigned short* __restrict__ A1,
    const unsigned short* __restrict__ B0, const unsigned short* __restrict__ B1,
    const float* __restrict__ bias0, const float* __restrict__ bias1,
    const float* __restrict__ R0, const float* __restrict__ R1,
    float* __restrict__ C0, float* __restrict__ C1)
{
    const int K = 512;
    __shared__ short As[2][128 * 64];
    __shared__ short Bs[2][64 * 64];

    const int z = blockIdx.z;
    const unsigned short* A  = z ? A1 : A0;
    const unsigned short* Bt = z ? B1 : B0;
    const float* bias        = z ? bias1 : bias0;
    const float* R           = z ? R1 : R0;
    float* Cf                = z ? C1 : C0;

    const int t = threadIdx.x;
    const int lane = t & 63;
    const int wave = t >> 6;

    const int lid = blockIdx.x + 8 * blockIdx.y;
    const int wid = (lid & 7) * 64 + (lid >> 3);
    const int bm = (wid >> 3) * 128;
    const int bn = (wid & 7) * 64;

    const int wm = (wave >> 1) * 64;
    const int wn = (wave & 1) * 32;

    f32x4 acc[4][2] = {};
    const int srcslot = (((lane & 7) ^ (lane >> 3)) << 3);
    const int rsub = lane >> 3;

    auto stage = [&](int k0, int buf) {
#pragma unroll
        for (int i = 0; i < 4; ++i) {
            const int row = i * 32 + wave * 8 + rsub;
            const unsigned short* ga = A + (size_t)(bm + row) * K + k0 + srcslot;
            __builtin_amdgcn_global_load_lds(
                (const __attribute__((address_space(1))) unsigned int*)ga,
                (__attribute__((address_space(3))) unsigned int*)(&As[buf][(i * 256 + wave * 64) * 8]),
                16, 0, 0);
        }
#pragma unroll
        for (int i = 0; i < 2; ++i) {
            const int row = i * 32 + wave * 8 + rsub;
            const unsigned short* gb = Bt + (size_t)(bn + row) * K + k0 + srcslot;
            __builtin_amdgcn_global_load_lds(
                (const __attribute__((address_space(1))) unsigned int*)gb,
                (__attribute__((address_space(3))) unsigned int*)(&Bs[buf][(i * 256 + wave * 64) * 8]),
                16, 0, 0);
        }
    };

    const int fr = lane & 15;
    const int quad = lane >> 4;
    const int sw = (fr & 7) << 3;
    const int nk = K >> 6;

    stage(0, 0);
    __syncthreads();

    for (int it = 0; it < nk; ++it) {
        const int buf = it & 1;
        if (it + 1 < nk) stage((it + 1) << 6, buf ^ 1);
        frag16 af[2][4], bfr[2][2];
#pragma unroll
        for (int ks = 0; ks < 2; ++ks) {
            const int col = (ks * 32 + quad * 8) ^ sw;
#pragma unroll
            for (int i = 0; i < 4; ++i)
                af[ks][i] = *(const frag16*)(&As[buf][(wm + i * 16 + fr) * 64 + col]);
#pragma unroll
            for (int i = 0; i < 2; ++i)
                bfr[ks][i] = *(const frag16*)(&Bs[buf][(wn + i * 16 + fr) * 64 + col]);
        }
#pragma unroll
        for (int ks = 0; ks < 2; ++ks)
#pragma unroll
            for (int mi = 0; mi < 4; ++mi)
#pragma unroll
                for (int ni = 0; ni < 2; ++ni)
                    acc[mi][ni] = __builtin_amdgcn_mfma_f32_16x16x32_bf16(
                        af[ks][mi], bfr[ks][ni], acc[mi][ni], 0, 0, 0);
        __syncthreads();
    }

#pragma unroll
    for (int mi = 0; mi < 4; ++mi) {
#pragma unroll
        for (int r = 0; r < 4; ++r) {
            const int m = bm + wm + mi * 16 + quad * 4 + r;
#pragma unroll
            for (int ni = 0; ni < 2; ++ni) {
                const int n = bn + wn + ni * 16 + fr;
                Cf[(size_t)m * 512 + n] = acc[mi][ni][r] + bias[n] + R[(size_t)m * 512 + n];
            }
        }
    }
}

// ---------------------------------------------------------------------------
// fp32 -> bf16 convert, dual-source (two tensors in one launch)
// ---------------------------------------------------------------------------
__global__ __launch_bounds__(256) void conv_b2(
    const float* __restrict__ X0, unsigned short* __restrict__ Y0,
    const float* __restrict__ X1, unsigned short* __restrict__ Y1,
    int halfBlocks)
{
    const int bid = blockIdx.x;
    const float* X = (bid < halfBlocks) ? X0 : X1;
    unsigned short* Y = (bid < halfBlocks) ? Y0 : Y1;
    const int lb = (bid < halfBlocks) ? bid : bid - halfBlocks;
    const size_t i = ((size_t)lb * 256 + threadIdx.x) * 8;
    float4 a = *(const float4*)(X + i);
    float4 b = *(const float4*)(X + i + 4);
    ushort8 o;
    o[0] = f2b(a.x); o[1] = f2b(a.y); o[2] = f2b(a.z); o[3] = f2b(a.w);
    o[4] = f2b(b.x); o[5] = f2b(b.y); o[6] = f2b(b.z); o[7] = f2b(b.w);
    *(ushort8*)(Y + i) = o;
}

// ---------------------------------------------------------------------------
// ALL weight transposes fused: 1600 tiles of 64x64, [K,N] fp32 -> [N,K] bf16
// ---------------------------------------------------------------------------
__global__ __launch_bounds__(256) void wtrans_all(
    const float* __restrict__ Wk, const float* __restrict__ Wv,
    const float* __restrict__ Wo, const float* __restrict__ W1,
    const float* __restrict__ W2, unsigned short* __restrict__ dst)
{
    const int bid = blockIdx.x;
    const float* src; unsigned short* d; int K, N, tk, tn;
    if (bid < 576) {
        const int mat = bid >> 6, tile = bid & 63;
        const int l = mat / 3, wch = mat % 3;
        const float* W = (wch == 0) ? Wk : (wch == 1) ? Wv : Wo;
        src = W + (size_t)l * 262144;
        d = dst + (size_t)mat * 262144;
        K = 512; N = 512; tn = tile & 7; tk = tile >> 3;
    } else if (bid < 1088) {
        const int idx = bid - 576, l2 = idx >> 8, tile = idx & 255;
        src = W1 + (size_t)(l2 * 2) * (512 * 2048);
        d = dst + 9 * 262144 + (size_t)l2 * (512 * 2048);
        K = 512; N = 2048; tn = tile & 31; tk = tile >> 5;
    } else {
        const int idx = bid - 1088, l2 = idx >> 8, tile = idx & 255;
        src = W2 + (size_t)(l2 * 2) * (2048 * 512);
        d = dst + 9 * 262144 + 2 * (512 * 2048) + (size_t)l2 * (2048 * 512);
        K = 2048; N = 512; tn = tile & 7; tk = tile >> 3;
    }
    const int n0 = tn * 64, k0 = tk * 64;
    __shared__ float T[64][65];
    const int t = threadIdx.x;
    const int kl = t >> 4, n4 = (t & 15) << 2;
#pragma unroll
    for (int it = 0; it < 4; ++it) {
        const int k = kl + it * 16;
        float4 v = *(const float4*)(src + (size_t)(k0 + k) * N + n0 + n4);
        T[n4 + 0][k] = v.x; T[n4 + 1][k] = v.y;
        T[n4 + 2][k] = v.z; T[n4 + 3][k] = v.w;
    }
    __syncthreads();
    const int nl = t >> 3, k8 = (t & 7) << 3;
#pragma unroll
    for (int it = 0; it < 2; ++it) {
        const int n = nl + it * 32;
        ushort8 o;
#pragma unroll
        for (int c = 0; c < 8; ++c) o[c] = f2b(T[n][k8 + c]);
        *(ushort8*)(d + (size_t)(n0 + n) * K + k0 + k8) = o;
    }
}

// ---------------------------------------------------------------------------
// Flash-style monotonic attention v8 (round-7 verified structure), with
// optional DUAL-LAYER mode: dual=1 interleaves two independent layers in
// blockIdx.x (layer = x&1) so both encoder blocks run in one launch.
// 4-way j-split across waves, LPT rank order in blockIdx.y.
// ---------------------------------------------------------------------------
__global__ __launch_bounds__(256, 8) void attn_flash8(
    const unsigned short* __restrict__ Kb0, const unsigned short* __restrict__ Vt0,
    const unsigned short* __restrict__ Kb1, const unsigned short* __restrict__ Vt1,
    const float* __restrict__ gam,           // base; layer adds Hdim
    unsigned short* __restrict__ Ob0, unsigned short* __restrict__ Ob1,
    int mask_type, int dual)
{
    __shared__ float CTw[16 * 33];               // cross-tile strict suffix
    __shared__ unsigned short Pst[4][16 * 36];   // P staging (A-frag layout, per wave)
    __shared__ float S1s[4][16];                 // sum1 partials [w][row]
    __shared__ float S2s[4][16];                 // sum2 partials
    __shared__ float OaccA[16 * 66];             // oacc combine buffers
    __shared__ float OaccB[16 * 66];

    int bh, layer;
    if (dual) { layer = blockIdx.x & 1; bh = blockIdx.x >> 1; }
    else      { layer = 0;              bh = blockIdx.x; }
    const unsigned short* Kb = layer ? Kb1 : Kb0;
    const unsigned short* Vt = layer ? Vt1 : Vt0;
    unsigned short* Ob       = layer ? Ob1 : Ob0;
    const float* g           = gam + layer * Hdim;

    const int h = bh & 7, b = bh >> 3;
    const int rk = blockIdx.y;                   // LPT rank: 0 = heaviest
    const int tile = mask_type ? (31 - rk) : (rk == 0 ? 0 : 32 - rk);

    const int t = threadIdx.x, lane = t & 63, w = t >> 6;   // w: j-split slot
    const int quad = lane >> 4, fr = lane & 15;
    const int q0 = tile * 16;
    const int iRow = q0 + fr;                // this lane's q row

    const unsigned short* kbase = Kb + (size_t)b * Sdim * Ddim + h * DKdim;
    const unsigned short* vtb = Vt + (size_t)(b * Hdim + h) * DKdim * Sdim;
    const float gneg2 = -log1pf(__expf(g[h])) * 1.4426950408889634f;

    // Q as B-operand: rows q0+fr
    frag16 aq0 = *(const frag16*)(kbase + (size_t)(q0 + fr) * Ddim + quad * 8);
    frag16 aq1 = *(const frag16*)(kbase + (size_t)(q0 + fr) * Ddim + 32 + quad * 8);

    // ---- Pass 1: sum1 partials + per-tile totals into CT (4-way jn split)
    float psum = 0.f;
    for (int jn = w; jn <= tile; jn += 4) {
        frag16 k0 = *(const frag16*)(kbase + (size_t)(jn * 16 + fr) * Ddim + quad * 8);
        frag16 k1 = *(const frag16*)(kbase + (size_t)(jn * 16 + fr) * Ddim + 32 + quad * 8);
        f32x4 z = {0.f, 0.f, 0.f, 0.f};
        z = __builtin_amdgcn_mfma_f32_16x16x32_bf16(k0, aq0, z, 0, 0, 0);
        z = __builtin_amdgcn_mfma_f32_16x16x32_bf16(k1, aq1, z, 0, 0, 0);
        float tq = 0.f;
        if (jn < tile) {                 // fully-valid tile (both masks)
#pragma unroll
            for (int r = 0; r < 4; ++r) tq += EXP2(z[r] * SC2);
        } else {                         // diagonal tile
#pragma unroll
            for (int r = 0; r < 4; ++r) {
                const bool valid = mask_type ? (quad * 4 + r <= fr)
                                             : (quad * 4 + r < fr);
                tq += valid ? EXP2(z[r] * SC2) : 0.f;
            }
        }
        psum += tq;
        float tt = tq;
        tt += __shfl_xor(tt, 16);
        tt += __shfl_xor(tt, 32);
        if (quad == 0) CTw[fr * 33 + jn] = tt;
    }
    {
        float s1 = psum;
        s1 += __shfl_xor(s1, 16);
        s1 += __shfl_xor(s1, 32);
        if (lane < 16) S1s[w][lane] = s1;
    }
    __syncthreads();

    // totals -> strict cross-tile suffix (wave 0; rows by lanes 0..15)
    if (w == 0 && lane < 16) {
        float run = 0.f;
        for (int jn = tile; jn >= 0; --jn) {
            const float tv = CTw[lane * 33 + jn];
            CTw[lane * 33 + jn] = run;
            run += tv;
        }
    }
    __syncthreads();

    const float rsum1 = 1.f / (S1s[0][fr] + S1s[1][fr] + S1s[2][fr] + S1s[3][fr]);
    unsigned short* Pw = Pst[w];
    const bool fm_blk = (mask_type == 0) && (tile == 0);
    const bool fmrow = fm_blk && (fr == 0);
    const int umax = fm_blk ? (Sdim / 32 - 1) : (tile >> 1);
    float sum2p = 0.f;
    f32x4 oacc[4] = {};

    // ---- Pass 2: independent u-tiles, 4-way split, online PV
    for (int u = umax - w; u >= 0; u -= 4) {
#pragma unroll
        for (int half = 0; half < 2; ++half) {
            const int jn = 2 * u + half;
            uint2 pku;
            if (jn > tile) {
                // empty tile: P=0, except mask0 row-0 uniform case (P=1)
                const unsigned int pv = fmrow ? 0x3F803F80u : 0u;
                pku.x = pv; pku.y = pv;
                sum2p += fmrow ? 4.f : 0.f;
            } else {
                frag16 k0 = *(const frag16*)(kbase + (size_t)(jn * 16 + fr) * Ddim + quad * 8);
                frag16 k1 = *(const frag16*)(kbase + (size_t)(jn * 16 + fr) * Ddim + 32 + quad * 8);
                f32x4 z = {0.f, 0.f, 0.f, 0.f};
                z = __builtin_amdgcn_mfma_f32_16x16x32_bf16(k0, aq0, z, 0, 0, 0);
                z = __builtin_amdgcn_mfma_f32_16x16x32_bf16(k1, aq1, z, 0, 0, 0);
                const bool full = (jn < tile);   // wave-uniform
                float s2r[4], lsuf[4];
                float tq = 0.f;
#pragma unroll
                for (int r = 3; r >= 0; --r) {
                    lsuf[r] = tq;                // strict suffix within 4-run
                    s2r[r] = z[r] * SC2;
                    float e1 = EXP2(s2r[r]);
                    if (!full) {
                        const bool valid = mask_type ? (quad * 4 + r <= fr)
                                                     : (quad * 4 + r < fr);
                        e1 = valid ? e1 : 0.f;
                    }
                    tq += e1;
                }
                // strict suffix over quads (2 guarded shfl_down)
                float incl = tq;
                {
                    float u1 = __shfl_down(incl, 16);
                    incl += (quad < 3) ? u1 : 0.f;
                    float u2 = __shfl_down(incl, 32);
                    incl += (quad < 2) ? u2 : 0.f;
                }
                const float base = CTw[fr * 33 + jn] + (incl - tq);
                const float pos0 = (float)(iRow - (jn * 16 + quad * 4));
                float e2v[4];
#pragma unroll
                for (int r = 0; r < 4; ++r) {
                    const float ratio = (base + lsuf[r]) * rsum1;   // >= 0
                    const float arg = ratio * fabsf(pos0 - (float)r);
                    const float te = fmaxf(EXP2(gneg2 * sqrtf(arg)), 1e-5f); // <= 1
                    float e2 = EXP2(s2r[r] * te);
                    if (!full) {
                        const bool valid = mask_type ? (quad * 4 + r <= fr)
                                                     : (quad * 4 + r < fr);
                        e2 = valid ? e2 : (fmrow ? 1.f : 0.f);
                    }
                    sum2p += e2;
                    e2v[r] = e2;
                }
                union { __hip_bfloat162 hh; unsigned int u; } c0, c1;
                c0.hh = __float22bfloat162_rn(make_float2(e2v[0], e2v[1]));
                c1.hh = __float22bfloat162_rn(make_float2(e2v[2], e2v[3]));
                pku.x = c0.u; pku.y = c1.u;
            }
            *(uint2*)(Pw + fr * 36 + half * 16 + quad * 4) = pku;
        }
        // PV over this pair's 32-wide window (A = P from LDS, B = Vt)
        frag16 pf = *(const frag16*)(Pw + fr * 36 + quad * 8);
        const int jb = u * 32;
#pragma unroll
        for (int dt = 0; dt < 4; ++dt) {
            frag16 vf = *(const frag16*)(vtb + (size_t)(dt * 16 + fr) * Sdim + jb + quad * 8);
            oacc[dt] = __builtin_amdgcn_mfma_f32_16x16x32_bf16(pf, vf, oacc[dt], 0, 0, 0);
        }
    }

    // ---- combine the four waves' partials (2-step tree through 2 buffers)
    {
        float s2 = sum2p;
        s2 += __shfl_xor(s2, 16);
        s2 += __shfl_xor(s2, 32);
        if (lane < 16) S2s[w][lane] = s2;
    }
    if (w == 1) {
#pragma unroll
        for (int dt = 0; dt < 4; ++dt)
#pragma unroll
            for (int r = 0; r < 4; ++r)
                OaccA[(quad * 4 + r) * 66 + dt * 16 + fr] = oacc[dt][r];
    }
    if (w == 3) {
#pragma unroll
        for (int dt = 0; dt < 4; ++dt)
#pragma unroll
            for (int r = 0; r < 4; ++r)
                OaccB[(quad * 4 + r) * 66 + dt * 16 + fr] = oacc[dt][r];
    }
    __syncthreads();
    if (w == 0) {
#pragma unroll
        for (int dt = 0; dt < 4; ++dt)
#pragma unroll
            for (int r = 0; r < 4; ++r)
                oacc[dt][r] += OaccA[(quad * 4 + r) * 66 + dt * 16 + fr];
    }
    if (w == 2) {
#pragma unroll
        for (int dt = 0; dt < 4; ++dt)
#pragma unroll
            for (int r = 0; r < 4; ++r)
                oacc[dt][r] += OaccB[(quad * 4 + r) * 66 + dt * 16 + fr];
    }
    __syncthreads();
    if (w == 2) {
#pragma unroll
        for (int dt = 0; dt < 4; ++dt)
#pragma unroll
            for (int r = 0; r < 4; ++r)
                OaccA[(quad * 4 + r) * 66 + dt * 16 + fr] = oacc[dt][r];
    }
    __syncthreads();

    if (w == 0) {
        const float rs2 = 1.f / (S2s[0][fr] + S2s[1][fr] + S2s[2][fr] + S2s[3][fr]);
        float rs2q[4];
#pragma unroll
        for (int r = 0; r < 4; ++r) rs2q[r] = __shfl(rs2, quad * 4 + r);

        // O rows q0+quad*4+r, cols dt*16+fr
        unsigned short* obase = Ob + ((size_t)(b * Sdim + q0)) * Ddim + h * DKdim;
#pragma unroll
        for (int dt = 0; dt < 4; ++dt)
#pragma unroll
            for (int r = 0; r < 4; ++r) {
                const float v = oacc[dt][r] + OaccA[(quad * 4 + r) * 66 + dt * 16 + fr];
                obase[(size_t)(quad * 4 + r) * Ddim + dt * 16 + fr] = f2b(v * rs2q[r]);
            }
    }
}

// ---------------------------------------------------------------------------
// LayerNorm over last dim (512); fp32 out (nullable) + bf16 out (nullable).
// ---------------------------------------------------------------------------
__device__ __forceinline__ void ln_row(
    const float* __restrict__ X, const float* __restrict__ g,
    const float* __restrict__ bta, float* __restrict__ Y,
    unsigned short* __restrict__ Yb, int row, int t,
    float* r1, float* r2)
{
    const float* x = X + (size_t)row * Ddim;
    float a = x[t], b = x[t + 256];
    r1[t] = a + b;
    r2[t] = a * a + b * b;
    __syncthreads();
    for (int off = 128; off; off >>= 1) {
        if (t < off) { r1[t] += r1[t + off]; r2[t] += r2[t + off]; }
        __syncthreads();
    }
    float mean = r1[0] * (1.f / Ddim);
    float var = r2[0] * (1.f / Ddim) - mean * mean;
    float rs = rsqrtf(var + 1e-5f);
    float y0 = (a - mean) * rs * g[t] + bta[t];
    float y1 = (b - mean) * rs * g[t + 256] + bta[t + 256];
    if (Y) {
        float* y = Y + (size_t)row * Ddim;
        y[t] = y0;
        y[t + 256] = y1;
    }
    if (Yb) {
        unsigned short* yb = Yb + (size_t)row * Ddim;
        yb[t] = f2b(y0);
        yb[t + 256] = f2b(y1);
    }
}

__global__ __launch_bounds__(256) void ln_kernel(
    const float* __restrict__ X, const float* __restrict__ g,
    const float* __restrict__ bta, float* __restrict__ Y,
    unsigned short* __restrict__ Yb)
{
    __shared__ float r1[256], r2[256];
    ln_row(X, g, bta, Y, Yb, blockIdx.x, threadIdx.x, r1, r2);
}

// dual-tensor LN: rows [0,Mrows) from set 0, rows [Mrows,2*Mrows) from set 1
__global__ __launch_bounds__(256) void ln_kernel2(
    const float* __restrict__ Xa, const float* __restrict__ ga,
    const float* __restrict__ ba, float* __restrict__ Ya,
    unsigned short* __restrict__ Yba,
    const float* __restrict__ Xb, const float* __restrict__ gb,
    const float* __restrict__ bb, float* __restrict__ Yb2,
    unsigned short* __restrict__ Ybb)
{
    __shared__ float r1[256], r2[256];
    const int row = blockIdx.x;
    if (row < Mrows)
        ln_row(Xa, ga, ba, Ya, Yba, row, threadIdx.x, r1, r2);
    else
        ln_row(Xb, gb, bb, Yb2, Ybb, row - Mrows, threadIdx.x, r1, r2);
}

// ---------------------------------------------------------------------------
extern "C" void kernel_launch(void* const* d_in, const int* in_sizes, int n_in,
                              void* d_out, int out_size, void* d_ws, size_t ws_size,
                              hipStream_t stream)
{
    const float* x0     = (const float*)d_in[0];
    const float* y0     = (const float*)d_in[1];
    const float* Wk     = (const float*)d_in[2];
    const float* bk     = (const float*)d_in[3];
    const float* Wv     = (const float*)d_in[4];
    const float* bv     = (const float*)d_in[5];
    const float* Wo     = (const float*)d_in[6];
    const float* bo     = (const float*)d_in[7];
    const float* gammas = (const float*)d_in[8];
    const float* ln1g   = (const float*)d_in[9];
    const float* ln1b   = (const float*)d_in[10];
    const float* W1     = (const float*)d_in[11];
    const float* b1     = (const float*)d_in[12];
    const float* W2     = (const float*)d_in[13];
    const float* b2     = (const float*)d_in[14];
    const float* ln2g   = (const float*)d_in[15];
    const float* ln2b   = (const float*)d_in[16];

    const size_t NBSD = (size_t)Mrows * Ddim;   // 4,194,304
    float* ws = (float*)d_ws;
    float* T1   = ws;
    float* X1   = T1 + NBSD;
    float* Xbuf = X1 + NBSD;
    unsigned short* Kbf = (unsigned short*)(Xbuf + NBSD);
    unsigned short* Vt  = Kbf + NBSD;
    unsigned short* AOb = Vt + NBSD;
    unsigned short* Abf = AOb + NBSD;
    unsigned short* Xbf = Abf + NBSD;
    unsigned short* Ybf = Xbf + NBSD;
    unsigned short* Hbb = Ybf + NBSD;                       // [M,F] = 4 NBSD units
    unsigned short* WtAll = Hbb + (size_t)Mrows * Fdim;

    // transient aliases for the merged block0/block1 phase (all regions are
    // dead at their aliased use time in the serial launch order):
    unsigned short* Xb_in = Hbb;                 // bf16(x0), consumed by kv4
    unsigned short* AOb1  = Hbb + NBSD;          // layer-1 attention out
    unsigned short* Yb_in = Hbb + 2 * NBSD;      // bf16(y0), consumed by kv4
    unsigned short* Kbf1  = Abf;                 // layer-1 K (dead until LN writes Abf)
    unsigned short* Vt1   = Ybf;                 // layer-1 Vt (dead until LN2_0 writes Ybf)
    float* T1b = (float*)d_out;                  // layer-1 O out (dead until final LN)

    auto WtK = [&](int l) { return WtAll + (size_t)(l * 3 + 0) * 262144; };
    auto WtV = [&](int l) { return WtAll + (size_t)(l * 3 + 1) * 262144; };
    auto WtO = [&](int l) { return WtAll + (size_t)(l * 3 + 2) * 262144; };
    auto Wt1 = [&](int l) { return WtAll + 9 * 262144 + (size_t)(l >> 1) * (512 * 2048); };
    auto Wt2 = [&](int l) { return WtAll + 9 * 262144 + 2 * (512 * 2048) + (size_t)(l >> 1) * (2048 * 512); };

    const int convBlocks = (int)(NBSD / 2048);   // 2048

    // 1. weight transposes
    wtrans_all<<<1600, 256, 0, stream>>>(Wk, Wv, Wo, W1, W2, WtAll);
    // 2. both inputs -> bf16 (one launch)
    conv_b2<<<2 * convBlocks, 256, 0, stream>>>(y0, Yb_in, x0, Xb_in, convBlocks);
    // 3. KV projections for layers 0 and 1 (one launch, z=0..3)
    gemm_kv4<<<dim3(8, 64, 4), 256, 0, stream>>>(
        Yb_in, Xb_in, WtK(0), WtV(0), WtK(1), WtV(1),
        bk, bv, bk + Ddim, bv + Ddim,
        Kbf, Vt, Kbf1, Vt1);
    // 4. attention layers 0+1 merged (mask1 both; layer interleaved in x)
    attn_flash8<<<dim3(2 * Bdim * Hdim, Sdim / 16, 1), 256, 0, stream>>>(
        Kbf, Vt, Kbf1, Vt1, gammas, AOb, AOb1, 1, 1);
    // 5. O-projections + residual for layers 0+1 (one launch)
    gemm_o2<<<dim3(8, 64, 2), 256, 0, stream>>>(
        AOb, AOb1, WtO(0), WtO(1), bo, bo + Ddim, y0, x0, T1, T1b);
    // 6. LN1 for both layers (one launch): L0 -> X1 + Abf; L1 -> Xbuf + Xbf (final)
    ln_kernel2<<<2 * Mrows, 256, 0, stream>>>(
        T1, ln1g, ln1b, X1, Abf,
        T1b, ln1g + Ddim, ln1b + Ddim, Xbuf, Xbf);
    // 7-9. block-0 FFN + LN2 -> Ybf
    gemm_mfma<<<dim3(Fdim / 128, Mrows / 128), 256, 0, stream>>>(
        (const __hip_bfloat16*)Abf, (const __hip_bfloat16*)Wt1(0),
        b1, nullptr, nullptr, Hbb, Mrows, Fdim, Ddim, 1);
    gemm_n64<<<dim3(8, 64, 1), 256, 0, stream>>>(
        Hbb, Hbb, Wt2(0), Wt2(0), b2, b2,
        X1, T1, nullptr, nullptr, Fdim);
    ln_kernel<<<Mrows, 256, 0, stream>>>(T1, ln2g, ln2b, nullptr, Ybf);

    // ---- block 2: knowledge retriever (q/k = x-out, v = y-out, mask0, FFN)
    const int l = 2;
    // 10. KV (dual z): K from Xbf, V from Ybf
    gemm_n64<<<dim3(8, 64, 2), 256, 0, stream>>>(
        Xbf, Ybf, WtK(l), WtV(l), bk + l * Ddim, bv + l * Ddim,
        nullptr, nullptr, Kbf, Vt, Ddim);
    // 11. attention (mask0, single layer)
    attn_flash8<<<dim3(Bdim * Hdim, Sdim / 16, 1), 256, 0, stream>>>(
        Kbf, Vt, Kbf, Vt, gammas + (size_t)l * Hdim, AOb, AOb, 0, 0);
    // 12. O-projection + residual (Xbuf)
    gemm_n64<<<dim3(8, 64, 1), 256, 0, stream>>>(
        AOb, AOb, WtO(l), WtO(l), bo + l * Ddim, bo + l * Ddim,
        Xbuf, T1, nullptr, nullptr, Ddim);
    // 13. LN1 -> X1 + Abf
    ln_kernel<<<Mrows, 256, 0, stream>>>(T1,
        ln1g + (size_t)l * Ddim, ln1b + (size_t)l * Ddim, X1, Abf);
    // 14-16. FFN + LN2 -> d_out (fp32)
    gemm_mfma<<<dim3(Fdim / 128, Mrows / 128), 256, 0, stream>>>(
        (const __hip_bfloat16*)Abf, (const __hip_bfloat16*)Wt1(l),
        b1 + (size_t)l * Fdim, nullptr, nullptr, Hbb, Mrows, Fdim, Ddim, 1);
    gemm_n64<<<dim3(8, 64, 1), 256, 0, stream>>>(
        Hbb, Hbb, Wt2(l), Wt2(l), b2 + (size_t)l * Ddim, b2 + (size_t)l * Ddim,
        X1, T1, nullptr, nullptr, Fdim);
    ln_kernel<<<Mrows, 256, 0, stream>>>(T1,
        ln2g + (size_t)l * Ddim, ln2b + (size_t)l * Ddim, (float*)d_out, nullptr);
}

// Round 9
// 562.391 us; speedup vs baseline: 1.3525x; 1.0230x over previous
//
#include <hip/hip_runtime.h>
#include <hip/hip_bf16.h>

// Problem dims (fixed)
#define Bdim 16
#define Sdim 512
#define Ddim 512
#define Hdim 8
#define DKdim 64
#define Fdim 2048
#define Mrows (Bdim * Sdim)   // 8192

typedef __attribute__((ext_vector_type(8))) short  frag16;   // 8 bf16 (4 VGPRs)
typedef __attribute__((ext_vector_type(4))) float  f32x4;    // MFMA acc
typedef __attribute__((ext_vector_type(8))) unsigned short ushort8;
typedef __attribute__((ext_vector_type(4))) unsigned short ushort4v;

// raw 2^x (v_exp_f32); fallback keeps semantics
#if defined(__has_builtin)
#  if __has_builtin(__builtin_amdgcn_exp2f)
#    define EXP2(x) __builtin_amdgcn_exp2f(x)
#  endif
#endif
#ifndef EXP2
#  define EXP2(x) __expf((x) * 0.6931471805599453f)
#endif
#define SC2 0.18033688011112042f   // 0.125 * log2(e)

// round-to-nearest-even fp32 -> bf16 (finite data)
__device__ __forceinline__ unsigned short f2b(float x) {
    union { float f; unsigned int u; } v; v.f = x;
    unsigned int r = (v.u + 0x7FFFu + ((v.u >> 16) & 1u)) >> 16;
    return (unsigned short)r;
}

// ---------------------------------------------------------------------------
// bf16 MFMA GEMM, 128x128 tile (used for FFN1, N=2048).
// XCD-chunked swizzle + 2-phase double-buffered K-loop.
// ---------------------------------------------------------------------------
__global__ __launch_bounds__(256) void gemm_mfma(
    const __hip_bfloat16* __restrict__ A, const __hip_bfloat16* __restrict__ Bt,
    const float* __restrict__ bias, const float* __restrict__ R,
    float* __restrict__ Cf, unsigned short* __restrict__ Cb,
    int M, int N, int K, int do_relu)
{
    __shared__ short As[2][128 * 32];
    __shared__ short Bs[2][128 * 32];

    const int t = threadIdx.x;
    const int lane = t & 63;
    const int wave = t >> 6;

    // XCD-aware chunked swizzle (grid size divisible by 8)
    const int gx = gridDim.x;
    const int nb = gx * gridDim.y;
    const int lid = blockIdx.x + gx * blockIdx.y;
    const int wid = (lid & 7) * (nb >> 3) + (lid >> 3);
    const int bm = (wid / gx) * 128;
    const int bn = (wid % gx) * 128;

    const int wm = (wave >> 1) * 64;
    const int wn = (wave & 1) * 64;

    f32x4 acc[4][4] = {};
    const int lrow = lane >> 2;
    const int lcol = (lane & 3) * 8;

    auto stage = [&](int k0, int buf) {
#pragma unroll
        for (int i = 0; i < 2; ++i) {
            const int chunk = wave * 2 + i;
            const int row = chunk * 16 + lrow;
            const __hip_bfloat16* ga = A + (size_t)(bm + row) * K + k0 + lcol;
            const __hip_bfloat16* gb = Bt + (size_t)(bn + row) * K + k0 + lcol;
            __builtin_amdgcn_global_load_lds(
                (const __attribute__((address_space(1))) unsigned int*)ga,
                (__attribute__((address_space(3))) unsigned int*)(&As[buf][chunk * 512]),
                16, 0, 0);
            __builtin_amdgcn_global_load_lds(
                (const __attribute__((address_space(1))) unsigned int*)gb,
                (__attribute__((address_space(3))) unsigned int*)(&Bs[buf][chunk * 512]),
                16, 0, 0);
        }
    };

    const int fr = lane & 15;
    const int quad = lane >> 4;
    const int nk = K >> 5;

    stage(0, 0);
    __syncthreads();

    for (int it = 0; it < nk; ++it) {
        const int buf = it & 1;
        if (it + 1 < nk) stage((it + 1) << 5, buf ^ 1);
        frag16 af[4], bfr[4];
#pragma unroll
        for (int i = 0; i < 4; ++i) {
            af[i]  = *(const frag16*)(&As[buf][(wm + i * 16 + fr) * 32 + quad * 8]);
            bfr[i] = *(const frag16*)(&Bs[buf][(wn + i * 16 + fr) * 32 + quad * 8]);
        }
#pragma unroll
        for (int mi = 0; mi < 4; ++mi)
#pragma unroll
            for (int ni = 0; ni < 4; ++ni)
                acc[mi][ni] = __builtin_amdgcn_mfma_f32_16x16x32_bf16(
                    af[mi], bfr[ni], acc[mi][ni], 0, 0, 0);
        __syncthreads();
    }

#pragma unroll
    for (int mi = 0; mi < 4; ++mi) {
#pragma unroll
        for (int r = 0; r < 4; ++r) {
            const int m = bm + wm + mi * 16 + quad * 4 + r;
#pragma unroll
            for (int ni = 0; ni < 4; ++ni) {
                const int n = bn + wn + ni * 16 + fr;
                float v = acc[mi][ni][r] + bias[n];
                if (R) v += R[(size_t)m * N + n];
                if (do_relu) v = fmaxf(v, 0.f);
                if (Cf) Cf[(size_t)m * N + n] = v;
                if (Cb) Cb[(size_t)m * N + n] = f2b(v);
            }
        }
    }
}

// ---------------------------------------------------------------------------
// bf16 MFMA GEMM, 128x64 tile, N=512 fixed, BK=64 (16 MFMA per barrier).
// XOR-swizzled LDS (source pre-swizzle + read-side XOR). Dual-mode via z:
// z=0: A0@B0^T+bias0 -> Cb / Cf(+R);  z=1: A1@B1^T+bias1 -> CbT (Vt layout)
// ---------------------------------------------------------------------------
__global__ __launch_bounds__(256) void gemm_n64(
    const unsigned short* __restrict__ A0, const unsigned short* __restrict__ A1,
    const unsigned short* __restrict__ B0, const unsigned short* __restrict__ B1,
    const float* __restrict__ bias0, const float* __restrict__ bias1,
    const float* __restrict__ R, float* __restrict__ Cf,
    unsigned short* __restrict__ Cb, unsigned short* __restrict__ CbT,
    int K)
{
    const int NN = 512;
    __shared__ short As[2][128 * 64];   // 32 KB
    __shared__ short Bs[2][64 * 64];    // 16 KB

    const int trans = blockIdx.z;
    const unsigned short* A  = trans ? A1 : A0;
    const unsigned short* Bt = trans ? B1 : B0;
    const float* bias        = trans ? bias1 : bias0;

    const int t = threadIdx.x;
    const int lane = t & 63;
    const int wave = t >> 6;

    const int lid = blockIdx.x + 8 * blockIdx.y;          // 0..511
    const int wid = (lid & 7) * 64 + (lid >> 3);
    const int bm = (wid >> 3) * 128;
    const int bn = (wid & 7) * 64;

    const int wm = (wave >> 1) * 64;
    const int wn = (wave & 1) * 32;

    f32x4 acc[4][2] = {};

    const int srcslot = (((lane & 7) ^ (lane >> 3)) << 3);
    const int rsub = lane >> 3;

    auto stage = [&](int k0, int buf) {
#pragma unroll
        for (int i = 0; i < 4; ++i) {
            const int row = i * 32 + wave * 8 + rsub;
            const unsigned short* ga = A + (size_t)(bm + row) * K + k0 + srcslot;
            __builtin_amdgcn_global_load_lds(
                (const __attribute__((address_space(1))) unsigned int*)ga,
                (__attribute__((address_space(3))) unsigned int*)(&As[buf][(i * 256 + wave * 64) * 8]),
                16, 0, 0);
        }
#pragma unroll
        for (int i = 0; i < 2; ++i) {
            const int row = i * 32 + wave * 8 + rsub;
            const unsigned short* gb = Bt + (size_t)(bn + row) * K + k0 + srcslot;
            __builtin_amdgcn_global_load_lds(
                (const __attribute__((address_space(1))) unsigned int*)gb,
                (__attribute__((address_space(3))) unsigned int*)(&Bs[buf][(i * 256 + wave * 64) * 8]),
                16, 0, 0);
        }
    };

    const int fr = lane & 15;
    const int quad = lane >> 4;
    const int sw = (fr & 7) << 3;
    const int nk = K >> 6;

    stage(0, 0);
    __syncthreads();

    for (int it = 0; it < nk; ++it) {
        const int buf = it & 1;
        if (it + 1 < nk) stage((it + 1) << 6, buf ^ 1);
        frag16 af[2][4], bfr[2][2];
#pragma unroll
        for (int ks = 0; ks < 2; ++ks) {
            const int col = (ks * 32 + quad * 8) ^ sw;
#pragma unroll
            for (int i = 0; i < 4; ++i)
                af[ks][i] = *(const frag16*)(&As[buf][(wm + i * 16 + fr) * 64 + col]);
#pragma unroll
            for (int i = 0; i < 2; ++i)
                bfr[ks][i] = *(const frag16*)(&Bs[buf][(wn + i * 16 + fr) * 64 + col]);
        }
#pragma unroll
        for (int ks = 0; ks < 2; ++ks)
#pragma unroll
            for (int mi = 0; mi < 4; ++mi)
#pragma unroll
                for (int ni = 0; ni < 2; ++ni)
                    acc[mi][ni] = __builtin_amdgcn_mfma_f32_16x16x32_bf16(
                        af[ks][mi], bfr[ks][ni], acc[mi][ni], 0, 0, 0);
        __syncthreads();
    }

    if (trans) {
#pragma unroll
        for (int mi = 0; mi < 4; ++mi)
#pragma unroll
            for (int ni = 0; ni < 2; ++ni) {
                const int m = bm + wm + mi * 16 + quad * 4;
                const int n = bn + wn + ni * 16 + fr;
                ushort4v o;
#pragma unroll
                for (int r = 0; r < 4; ++r) o[r] = f2b(acc[mi][ni][r] + bias[n]);
                const int bb = m >> 9, s = m & 511;
                const int hh = n >> 6, dd = n & 63;
                *(ushort4v*)(CbT + (((size_t)((bb * Hdim + hh) * DKdim + dd)) << 9) + s) = o;
            }
        return;
    }

#pragma unroll
    for (int mi = 0; mi < 4; ++mi) {
#pragma unroll
        for (int r = 0; r < 4; ++r) {
            const int m = bm + wm + mi * 16 + quad * 4 + r;
#pragma unroll
            for (int ni = 0; ni < 2; ++ni) {
                const int n = bn + wn + ni * 16 + fr;
                float v = acc[mi][ni][r] + bias[n];
                if (R) v += R[(size_t)m * NN + n];
                if (Cf) Cf[(size_t)m * NN + n] = v;
                if (Cb) Cb[(size_t)m * NN + n] = f2b(v);
            }
        }
    }
}

// ---------------------------------------------------------------------------
// FFN2 with SPLIT-K=2: A [M,2048] bf16, Bt [512,2048] bf16.
// z=0: K in [0,1024)  -> C0 = acc + bias + R  (fp32)
// z=1: K in [1024,2048) -> C1 = acc           (raw partial, fp32)
// The following LN fuses C0+C1. Same BK=64 swizzled core; 1024 blocks
// (vs 512 unsplit) with 16 iters each (vs 32) -> better residency cover.
// ---------------------------------------------------------------------------
__global__ __launch_bounds__(256) void gemm_ffn2(
    const unsigned short* __restrict__ A, const unsigned short* __restrict__ Bt,
    const float* __restrict__ bias, const float* __restrict__ R,
    float* __restrict__ C0, float* __restrict__ C1)
{
    const int K = 2048, KH = 1024;
    __shared__ short As[2][128 * 64];
    __shared__ short Bs[2][64 * 64];

    const int z = blockIdx.z;
    const int kbase = z * KH;

    const int t = threadIdx.x;
    const int lane = t & 63;
    const int wave = t >> 6;

    const int lid = blockIdx.x + 8 * blockIdx.y;
    const int wid = (lid & 7) * 64 + (lid >> 3);
    const int bm = (wid >> 3) * 128;
    const int bn = (wid & 7) * 64;

    const int wm = (wave >> 1) * 64;
    const int wn = (wave & 1) * 32;

    f32x4 acc[4][2] = {};
    const int srcslot = (((lane & 7) ^ (lane >> 3)) << 3);
    const int rsub = lane >> 3;

    auto stage = [&](int k0, int buf) {
#pragma unroll
        for (int i = 0; i < 4; ++i) {
            const int row = i * 32 + wave * 8 + rsub;
            const unsigned short* ga = A + (size_t)(bm + row) * K + k0 + srcslot;
            __builtin_amdgcn_global_load_lds(
                (const __attribute__((address_space(1))) unsigned int*)ga,
                (__attribute__((address_space(3))) unsigned int*)(&As[buf][(i * 256 + wave * 64) * 8]),
                16, 0, 0);
        }
#pragma unroll
        for (int i = 0; i < 2; ++i) {
            const int row = i * 32 + wave * 8 + rsub;
            const unsigned short* gb = Bt + (size_t)(bn + row) * K + k0 + srcslot;
            __builtin_amdgcn_global_load_lds(
                (const __attribute__((address_space(1))) unsigned int*)gb,
                (__attribute__((address_space(3))) unsigned int*)(&Bs[buf][(i * 256 + wave * 64) * 8]),
                16, 0, 0);
        }
    };

    const int fr = lane & 15;
    const int quad = lane >> 4;
    const int sw = (fr & 7) << 3;
    const int nk = KH >> 6;   // 16

    stage(kbase, 0);
    __syncthreads();

    for (int it = 0; it < nk; ++it) {
        const int buf = it & 1;
        if (it + 1 < nk) stage(kbase + ((it + 1) << 6), buf ^ 1);
        frag16 af[2][4], bfr[2][2];
#pragma unroll
        for (int ks = 0; ks < 2; ++ks) {
            const int col = (ks * 32 + quad * 8) ^ sw;
#pragma unroll
            for (int i = 0; i < 4; ++i)
                af[ks][i] = *(const frag16*)(&As[buf][(wm + i * 16 + fr) * 64 + col]);
#pragma unroll
            for (int i = 0; i < 2; ++i)
                bfr[ks][i] = *(const frag16*)(&Bs[buf][(wn + i * 16 + fr) * 64 + col]);
        }
#pragma unroll
        for (int ks = 0; ks < 2; ++ks)
#pragma unroll
            for (int mi = 0; mi < 4; ++mi)
#pragma unroll
                for (int ni = 0; ni < 2; ++ni)
                    acc[mi][ni] = __builtin_amdgcn_mfma_f32_16x16x32_bf16(
                        af[ks][mi], bfr[ks][ni], acc[mi][ni], 0, 0, 0);
        __syncthreads();
    }

#pragma unroll
    for (int mi = 0; mi < 4; ++mi) {
#pragma unroll
        for (int r = 0; r < 4; ++r) {
            const int m = bm + wm + mi * 16 + quad * 4 + r;
#pragma unroll
            for (int ni = 0; ni < 2; ++ni) {
                const int n = bn + wn + ni * 16 + fr;
                if (z == 0)
                    C0[(size_t)m * 512 + n] = acc[mi][ni][r] + bias[n] + R[(size_t)m * 512 + n];
                else
                    C1[(size_t)m * 512 + n] = acc[mi][ni][r];
            }
        }
    }
}

// ---------------------------------------------------------------------------
// 4-way KV projection: z in 0..3 selects {L0-K, L0-V(trans), L1-K, L1-V(trans)}.
// Same verified BK=64 swizzled core as gemm_n64; K fixed at 512.
// ---------------------------------------------------------------------------
__global__ __launch_bounds__(256) void gemm_kv4(
    const unsigned short* __restrict__ Ya, const unsigned short* __restrict__ Xa,
    const unsigned short* __restrict__ BtK0, const unsigned short* __restrict__ BtV0,
    const unsigned short* __restrict__ BtK1, const unsigned short* __restrict__ BtV1,
    const float* __restrict__ bk0, const float* __restrict__ bv0,
    const float* __restrict__ bk1, const float* __restrict__ bv1,
    unsigned short* __restrict__ K0, unsigned short* __restrict__ V0t,
    unsigned short* __restrict__ K1, unsigned short* __restrict__ V1t)
{
    const int K = 512;
    __shared__ short As[2][128 * 64];
    __shared__ short Bs[2][64 * 64];

    const int z = blockIdx.z;
    const unsigned short* A  = (z < 2) ? Ya : Xa;
    const unsigned short* Bt = (z == 0) ? BtK0 : (z == 1) ? BtV0 : (z == 2) ? BtK1 : BtV1;
    const float* bias        = (z == 0) ? bk0 : (z == 1) ? bv0 : (z == 2) ? bk1 : bv1;
    const int trans = z & 1;

    const int t = threadIdx.x;
    const int lane = t & 63;
    const int wave = t >> 6;

    const int lid = blockIdx.x + 8 * blockIdx.y;
    const int wid = (lid & 7) * 64 + (lid >> 3);
    const int bm = (wid >> 3) * 128;
    const int bn = (wid & 7) * 64;

    const int wm = (wave >> 1) * 64;
    const int wn = (wave & 1) * 32;

    f32x4 acc[4][2] = {};
    const int srcslot = (((lane & 7) ^ (lane >> 3)) << 3);
    const int rsub = lane >> 3;

    auto stage = [&](int k0, int buf) {
#pragma unroll
        for (int i = 0; i < 4; ++i) {
            const int row = i * 32 + wave * 8 + rsub;
            const unsigned short* ga = A + (size_t)(bm + row) * K + k0 + srcslot;
            __builtin_amdgcn_global_load_lds(
                (const __attribute__((address_space(1))) unsigned int*)ga,
                (__attribute__((address_space(3))) unsigned int*)(&As[buf][(i * 256 + wave * 64) * 8]),
                16, 0, 0);
        }
#pragma unroll
        for (int i = 0; i < 2; ++i) {
            const int row = i * 32 + wave * 8 + rsub;
            const unsigned short* gb = Bt + (size_t)(bn + row) * K + k0 + srcslot;
            __builtin_amdgcn_global_load_lds(
                (const __attribute__((address_space(1))) unsigned int*)gb,
                (__attribute__((address_space(3))) unsigned int*)(&Bs[buf][(i * 256 + wave * 64) * 8]),
                16, 0, 0);
        }
    };

    const int fr = lane & 15;
    const int quad = lane >> 4;
    const int sw = (fr & 7) << 3;
    const int nk = K >> 6;

    stage(0, 0);
    __syncthreads();

    for (int it = 0; it < nk; ++it) {
        const int buf = it & 1;
        if (it + 1 < nk) stage((it + 1) << 6, buf ^ 1);
        frag16 af[2][4], bfr[2][2];
#pragma unroll
        for (int ks = 0; ks < 2; ++ks) {
            const int col = (ks * 32 + quad * 8) ^ sw;
#pragma unroll
            for (int i = 0; i < 4; ++i)
                af[ks][i] = *(const frag16*)(&As[buf][(wm + i * 16 + fr) * 64 + col]);
#pragma unroll
            for (int i = 0; i < 2; ++i)
                bfr[ks][i] = *(const frag16*)(&Bs[buf][(wn + i * 16 + fr) * 64 + col]);
        }
#pragma unroll
        for (int ks = 0; ks < 2; ++ks)
#pragma unroll
            for (int mi = 0; mi < 4; ++mi)
#pragma unroll
                for (int ni = 0; ni < 2; ++ni)
                    acc[mi][ni] = __builtin_amdgcn_mfma_f32_16x16x32_bf16(
                        af[ks][mi], bfr[ks][ni], acc[mi][ni], 0, 0, 0);
        __syncthreads();
    }

    if (trans) {
        unsigned short* CbT = (z == 1) ? V0t : V1t;
#pragma unroll
        for (int mi = 0; mi < 4; ++mi)
#pragma unroll
            for (int ni = 0; ni < 2; ++ni) {
                const int m = bm + wm + mi * 16 + quad * 4;
                const int n = bn + wn + ni * 16 + fr;
                ushort4v o;
#pragma unroll
                for (int r = 0; r < 4; ++r) o[r] = f2b(acc[mi][ni][r] + bias[n]);
                const int bb = m >> 9, s = m & 511;
                const int hh = n >> 6, dd = n & 63;
                *(ushort4v*)(CbT + (((size_t)((bb * Hdim + hh) * DKdim + dd)) << 9) + s) = o;
            }
    } else {
        unsigned short* Cb = (z == 0) ? K0 : K1;
#pragma unroll
        for (int mi = 0; mi < 4; ++mi)
#pragma unroll
            for (int r = 0; r < 4; ++r) {
                const int m = bm + wm + mi * 16 + quad * 4 + r;
#pragma unroll
                for (int ni = 0; ni < 2; ++ni) {
                    const int n = bn + wn + ni * 16 + fr;
                    Cb[(size_t)m * 512 + n] = f2b(acc[mi][ni][r] + bias[n]);
                }
            }
    }
}

// ---------------------------------------------------------------------------
// Dual O-projection: z in {0,1} selects layer; both normal mode, fp32 out
// (C = A@Bt + bias + R). Same verified BK=64 swizzled core. K fixed 512.
// ---------------------------------------------------------------------------
__global__ __launch_bounds__(256) void gemm_o2(
    const unsigned short* __restrict__ A0, const unsigned short* __restrict__ A1,
    const unsigned short* __restrict__ B0, const unsigned short* __restrict__ B1,
    const float* __restrict__ bias0, const float* __restrict__ bias1,
    const float* __restrict__ R0, const float* __restrict__ R1,
    float* __restrict__ C0, float* __restrict__ C1)
{
    const int K = 512;
    __shared__ short As[2][128 * 64];
    __shared__ short Bs[2][64 * 64];

    const int z = blockIdx.z;
    const unsigned short* A  = z ? A1 : A0;
    const unsigned short* Bt = z ? B1 : B0;
    const float* bias        = z ? bias1 : bias0;
    const float* R           = z ? R1 : R0;
    float* Cf                = z ? C1 : C0;

    const int t = threadIdx.x;
    const int lane = t & 63;
    const int wave = t >> 6;

    const int lid = blockIdx.x + 8 * blockIdx.y;
    const int wid = (lid & 7) * 64 + (lid >> 3);
    const int bm = (wid >> 3) * 128;
    const int bn = (wid & 7) * 64;

    const int wm = (wave >> 1) * 64;
    const int wn = (wave & 1) * 32;

    f32x4 acc[4][2] = {};
    const int srcslot = (((lane & 7) ^ (lane >> 3)) << 3);
    const int rsub = lane >> 3;

    auto stage = [&](int k0, int buf) {
#pragma unroll
        for (int i = 0; i < 4; ++i) {
            const int row = i * 32 + wave * 8 + rsub;
            const unsigned short* ga = A + (size_t)(bm + row) * K + k0 + srcslot;
            __builtin_amdgcn_global_load_lds(
                (const __attribute__((address_space(1))) unsigned int*)ga,
                (__attribute__((address_space(3))) unsigned int*)(&As[buf][(i * 256 + wave * 64) * 8]),
                16, 0, 0);
        }
#pragma unroll
        for (int i = 0; i < 2; ++i) {
            const int row = i * 32 + wave * 8 + rsub;
            const unsigned short* gb = Bt + (size_t)(bn + row) * K + k0 + srcslot;
            __builtin_amdgcn_global_load_lds(
                (const __attribute__((address_space(1))) unsigned int*)gb,
                (__attribute__((address_space(3))) unsigned int*)(&Bs[buf][(i * 256 + wave * 64) * 8]),
                16, 0, 0);
        }
    };

    const int fr = lane & 15;
    const int quad = lane >> 4;
    const int sw = (fr & 7) << 3;
    const int nk = K >> 6;

    stage(0, 0);
    __syncthreads();

    for (int it = 0; it < nk; ++it) {
        const int buf = it & 1;
        if (it + 1 < nk) stage((it + 1) << 6, buf ^ 1);
        frag16 af[2][4], bfr[2][2];
#pragma unroll
        for (int ks = 0; ks < 2; ++ks) {
            const int col = (ks * 32 + quad * 8) ^ sw;
#pragma unroll
            for (int i = 0; i < 4; ++i)
                af[ks][i] = *(const frag16*)(&As[buf][(wm + i * 16 + fr) * 64 + col]);
#pragma unroll
            for (int i = 0; i < 2; ++i)
                bfr[ks][i] = *(const frag16*)(&Bs[buf][(wn + i * 16 + fr) * 64 + col]);
        }
#pragma unroll
        for (int ks = 0; ks < 2; ++ks)
#pragma unroll
            for (int mi = 0; mi < 4; ++mi)
#pragma unroll
                for (int ni = 0; ni < 2; ++ni)
                    acc[mi][ni] = __builtin_amdgcn_mfma_f32_16x16x32_bf16(
                        af[ks][mi], bfr[ks][ni], acc[mi][ni], 0, 0, 0);
        __syncthreads();
    }

#pragma unroll
    for (int mi = 0; mi < 4; ++mi) {
#pragma unroll
        for (int r = 0; r < 4; ++r) {
            const int m = bm + wm + mi * 16 + quad * 4 + r;
#pragma unroll
            for (int ni = 0; ni < 2; ++ni) {
                const int n = bn + wn + ni * 16 + fr;
                Cf[(size_t)m * 512 + n] = acc[mi][ni][r] + bias[n] + R[(size_t)m * 512 + n];
            }
        }
    }
}

// ---------------------------------------------------------------------------
// fp32 -> bf16 convert, dual-source (two tensors in one launch)
// ---------------------------------------------------------------------------
__global__ __launch_bounds__(256) void conv_b2(
    const float* __restrict__ X0, unsigned short* __restrict__ Y0,
    const float* __restrict__ X1, unsigned short* __restrict__ Y1,
    int halfBlocks)
{
    const int bid = blockIdx.x;
    const float* X = (bid < halfBlocks) ? X0 : X1;
    unsigned short* Y = (bid < halfBlocks) ? Y0 : Y1;
    const int lb = (bid < halfBlocks) ? bid : bid - halfBlocks;
    const size_t i = ((size_t)lb * 256 + threadIdx.x) * 8;
    float4 a = *(const float4*)(X + i);
    float4 b = *(const float4*)(X + i + 4);
    ushort8 o;
    o[0] = f2b(a.x); o[1] = f2b(a.y); o[2] = f2b(a.z); o[3] = f2b(a.w);
    o[4] = f2b(b.x); o[5] = f2b(b.y); o[6] = f2b(b.z); o[7] = f2b(b.w);
    *(ushort8*)(Y + i) = o;
}

// ---------------------------------------------------------------------------
// ALL weight transposes fused: 1600 tiles of 64x64, [K,N] fp32 -> [N,K] bf16
// ---------------------------------------------------------------------------
__global__ __launch_bounds__(256) void wtrans_all(
    const float* __restrict__ Wk, const float* __restrict__ Wv,
    const float* __restrict__ Wo, const float* __restrict__ W1,
    const float* __restrict__ W2, unsigned short* __restrict__ dst)
{
    const int bid = blockIdx.x;
    const float* src; unsigned short* d; int K, N, tk, tn;
    if (bid < 576) {
        const int mat = bid >> 6, tile = bid & 63;
        const int l = mat / 3, wch = mat % 3;
        const float* W = (wch == 0) ? Wk : (wch == 1) ? Wv : Wo;
        src = W + (size_t)l * 262144;
        d = dst + (size_t)mat * 262144;
        K = 512; N = 512; tn = tile & 7; tk = tile >> 3;
    } else if (bid < 1088) {
        const int idx = bid - 576, l2 = idx >> 8, tile = idx & 255;
        src = W1 + (size_t)(l2 * 2) * (512 * 2048);
        d = dst + 9 * 262144 + (size_t)l2 * (512 * 2048);
        K = 512; N = 2048; tn = tile & 31; tk = tile >> 5;
    } else {
        const int idx = bid - 1088, l2 = idx >> 8, tile = idx & 255;
        src = W2 + (size_t)(l2 * 2) * (2048 * 512);
        d = dst + 9 * 262144 + 2 * (512 * 2048) + (size_t)l2 * (2048 * 512);
        K = 2048; N = 512; tn = tile & 7; tk = tile >> 3;
    }
    const int n0 = tn * 64, k0 = tk * 64;
    __shared__ float T[64][65];
    const int t = threadIdx.x;
    const int kl = t >> 4, n4 = (t & 15) << 2;
#pragma unroll
    for (int it = 0; it < 4; ++it) {
        const int k = kl + it * 16;
        float4 v = *(const float4*)(src + (size_t)(k0 + k) * N + n0 + n4);
        T[n4 + 0][k] = v.x; T[n4 + 1][k] = v.y;
        T[n4 + 2][k] = v.z; T[n4 + 3][k] = v.w;
    }
    __syncthreads();
    const int nl = t >> 3, k8 = (t & 7) << 3;
#pragma unroll
    for (int it = 0; it < 2; ++it) {
        const int n = nl + it * 32;
        ushort8 o;
#pragma unroll
        for (int c = 0; c < 8; ++c) o[c] = f2b(T[n][k8 + c]);
        *(ushort8*)(d + (size_t)(n0 + n) * K + k0 + k8) = o;
    }
}

// ---------------------------------------------------------------------------
// Flash-style monotonic attention v8 (round-7 verified structure), with
// optional DUAL-LAYER mode: dual=1 interleaves two independent layers in
// blockIdx.x (layer = x&1) so both encoder blocks run in one launch.
// 4-way j-split across waves, LPT rank order in blockIdx.y.
// ---------------------------------------------------------------------------
__global__ __launch_bounds__(256, 8) void attn_flash8(
    const unsigned short* __restrict__ Kb0, const unsigned short* __restrict__ Vt0,
    const unsigned short* __restrict__ Kb1, const unsigned short* __restrict__ Vt1,
    const float* __restrict__ gam,           // base; layer adds Hdim
    unsigned short* __restrict__ Ob0, unsigned short* __restrict__ Ob1,
    int mask_type, int dual)
{
    __shared__ float CTw[16 * 33];               // cross-tile strict suffix
    __shared__ unsigned short Pst[4][16 * 36];   // P staging (A-frag layout, per wave)
    __shared__ float S1s[4][16];                 // sum1 partials [w][row]
    __shared__ float S2s[4][16];                 // sum2 partials
    __shared__ float OaccA[16 * 66];             // oacc combine buffers
    __shared__ float OaccB[16 * 66];

    int bh, layer;
    if (dual) { layer = blockIdx.x & 1; bh = blockIdx.x >> 1; }
    else      { layer = 0;              bh = blockIdx.x; }
    const unsigned short* Kb = layer ? Kb1 : Kb0;
    const unsigned short* Vt = layer ? Vt1 : Vt0;
    unsigned short* Ob       = layer ? Ob1 : Ob0;
    const float* g           = gam + layer * Hdim;

    const int h = bh & 7, b = bh >> 3;
    const int rk = blockIdx.y;                   // LPT rank: 0 = heaviest
    const int tile = mask_type ? (31 - rk) : (rk == 0 ? 0 : 32 - rk);

    const int t = threadIdx.x, lane = t & 63, w = t >> 6;   // w: j-split slot
    const int quad = lane >> 4, fr = lane & 15;
    const int q0 = tile * 16;
    const int iRow = q0 + fr;                // this lane's q row

    const unsigned short* kbase = Kb + (size_t)b * Sdim * Ddim + h * DKdim;
    const unsigned short* vtb = Vt + (size_t)(b * Hdim + h) * DKdim * Sdim;
    const float gneg2 = -log1pf(__expf(g[h])) * 1.4426950408889634f;

    // Q as B-operand: rows q0+fr
    frag16 aq0 = *(const frag16*)(kbase + (size_t)(q0 + fr) * Ddim + quad * 8);
    frag16 aq1 = *(const frag16*)(kbase + (size_t)(q0 + fr) * Ddim + 32 + quad * 8);

    // ---- Pass 1: sum1 partials + per-tile totals into CT (4-way jn split)
    float psum = 0.f;
    for (int jn = w; jn <= tile; jn += 4) {
        frag16 k0 = *(const frag16*)(kbase + (size_t)(jn * 16 + fr) * Ddim + quad * 8);
        frag16 k1 = *(const frag16*)(kbase + (size_t)(jn * 16 + fr) * Ddim + 32 + quad * 8);
        f32x4 z = {0.f, 0.f, 0.f, 0.f};
        z = __builtin_amdgcn_mfma_f32_16x16x32_bf16(k0, aq0, z, 0, 0, 0);
        z = __builtin_amdgcn_mfma_f32_16x16x32_bf16(k1, aq1, z, 0, 0, 0);
        float tq = 0.f;
        if (jn < tile) {                 // fully-valid tile (both masks)
#pragma unroll
            for (int r = 0; r < 4; ++r) tq += EXP2(z[r] * SC2);
        } else {                         // diagonal tile
#pragma unroll
            for (int r = 0; r < 4; ++r) {
                const bool valid = mask_type ? (quad * 4 + r <= fr)
                                             : (quad * 4 + r < fr);
                tq += valid ? EXP2(z[r] * SC2) : 0.f;
            }
        }
        psum += tq;
        float tt = tq;
        tt += __shfl_xor(tt, 16);
        tt += __shfl_xor(tt, 32);
        if (quad == 0) CTw[fr * 33 + jn] = tt;
    }
    {
        float s1 = psum;
        s1 += __shfl_xor(s1, 16);
        s1 += __shfl_xor(s1, 32);
        if (lane < 16) S1s[w][lane] = s1;
    }
    __syncthreads();

    // totals -> strict cross-tile suffix (wave 0; rows by lanes 0..15)
    if (w == 0 && lane < 16) {
        float run = 0.f;
        for (int jn = tile; jn >= 0; --jn) {
            const float tv = CTw[lane * 33 + jn];
            CTw[lane * 33 + jn] = run;
            run += tv;
        }
    }
    __syncthreads();

    const float rsum1 = 1.f / (S1s[0][fr] + S1s[1][fr] + S1s[2][fr] + S1s[3][fr]);
    unsigned short* Pw = Pst[w];
    const bool fm_blk = (mask_type == 0) && (tile == 0);
    const bool fmrow = fm_blk && (fr == 0);
    const int umax = fm_blk ? (Sdim / 32 - 1) : (tile >> 1);
    float sum2p = 0.f;
    f32x4 oacc[4] = {};

    // ---- Pass 2: independent u-tiles, 4-way split, online PV
    for (int u = umax - w; u >= 0; u -= 4) {
#pragma unroll
        for (int half = 0; half < 2; ++half) {
            const int jn = 2 * u + half;
            uint2 pku;
            if (jn > tile) {
                // empty tile: P=0, except mask0 row-0 uniform case (P=1)
                const unsigned int pv = fmrow ? 0x3F803F80u : 0u;
                pku.x = pv; pku.y = pv;
                sum2p += fmrow ? 4.f : 0.f;
            } else {
                frag16 k0 = *(const frag16*)(kbase + (size_t)(jn * 16 + fr) * Ddim + quad * 8);
                frag16 k1 = *(const frag16*)(kbase + (size_t)(jn * 16 + fr) * Ddim + 32 + quad * 8);
                f32x4 z = {0.f, 0.f, 0.f, 0.f};
                z = __builtin_amdgcn_mfma_f32_16x16x32_bf16(k0, aq0, z, 0, 0, 0);
                z = __builtin_amdgcn_mfma_f32_16x16x32_bf16(k1, aq1, z, 0, 0, 0);
                const bool full = (jn < tile);   // wave-uniform
                float s2r[4], lsuf[4];
                float tq = 0.f;
#pragma unroll
                for (int r = 3; r >= 0; --r) {
                    lsuf[r] = tq;                // strict suffix within 4-run
                    s2r[r] = z[r] * SC2;
                    float e1 = EXP2(s2r[r]);
                    if (!full) {
                        const bool valid = mask_type ? (quad * 4 + r <= fr)
                                                     : (quad * 4 + r < fr);
                        e1 = valid ? e1 : 0.f;
                    }
                    tq += e1;
                }
                // strict suffix over quads (2 guarded shfl_down)
                float incl = tq;
                {
                    float u1 = __shfl_down(incl, 16);
                    incl += (quad < 3) ? u1 : 0.f;
                    float u2 = __shfl_down(incl, 32);
                    incl += (quad < 2) ? u2 : 0.f;
                }
                const float base = CTw[fr * 33 + jn] + (incl - tq);
                const float pos0 = (float)(iRow - (jn * 16 + quad * 4));
                float e2v[4];
#pragma unroll
                for (int r = 0; r < 4; ++r) {
                    const float ratio = (base + lsuf[r]) * rsum1;   // >= 0
                    const float arg = ratio * fabsf(pos0 - (float)r);
                    const float te = fmaxf(EXP2(gneg2 * sqrtf(arg)), 1e-5f); // <= 1
                    float e2 = EXP2(s2r[r] * te);
                    if (!full) {
                        const bool valid = mask_type ? (quad * 4 + r <= fr)
                                                     : (quad * 4 + r < fr);
                        e2 = valid ? e2 : (fmrow ? 1.f : 0.f);
                    }
                    sum2p += e2;
                    e2v[r] = e2;
                }
                union { __hip_bfloat162 hh; unsigned int u; } c0, c1;
                c0.hh = __float22bfloat162_rn(make_float2(e2v[0], e2v[1]));
                c1.hh = __float22bfloat162_rn(make_float2(e2v[2], e2v[3]));
                pku.x = c0.u; pku.y = c1.u;
            }
            *(uint2*)(Pw + fr * 36 + half * 16 + quad * 4) = pku;
        }
        // PV over this pair's 32-wide window (A = P from LDS, B = Vt)
        frag16 pf = *(const frag16*)(Pw + fr * 36 + quad * 8);
        const int jb = u * 32;
#pragma unroll
        for (int dt = 0; dt < 4; ++dt) {
            frag16 vf = *(const frag16*)(vtb + (size_t)(dt * 16 + fr) * Sdim + jb + quad * 8);
            oacc[dt] = __builtin_amdgcn_mfma_f32_16x16x32_bf16(pf, vf, oacc[dt], 0, 0, 0);
        }
    }

    // ---- combine the four waves' partials (2-step tree through 2 buffers)
    {
        float s2 = sum2p;
        s2 += __shfl_xor(s2, 16);
        s2 += __shfl_xor(s2, 32);
        if (lane < 16) S2s[w][lane] = s2;
    }
    if (w == 1) {
#pragma unroll
        for (int dt = 0; dt < 4; ++dt)
#pragma unroll
            for (int r = 0; r < 4; ++r)
                OaccA[(quad * 4 + r) * 66 + dt * 16 + fr] = oacc[dt][r];
    }
    if (w == 3) {
#pragma unroll
        for (int dt = 0; dt < 4; ++dt)
#pragma unroll
            for (int r = 0; r < 4; ++r)
                OaccB[(quad * 4 + r) * 66 + dt * 16 + fr] = oacc[dt][r];
    }
    __syncthreads();
    if (w == 0) {
#pragma unroll
        for (int dt = 0; dt < 4; ++dt)
#pragma unroll
            for (int r = 0; r < 4; ++r)
                oacc[dt][r] += OaccA[(quad * 4 + r) * 66 + dt * 16 + fr];
    }
    if (w == 2) {
#pragma unroll
        for (int dt = 0; dt < 4; ++dt)
#pragma unroll
            for (int r = 0; r < 4; ++r)
                oacc[dt][r] += OaccB[(quad * 4 + r) * 66 + dt * 16 + fr];
    }
    __syncthreads();
    if (w == 2) {
#pragma unroll
        for (int dt = 0; dt < 4; ++dt)
#pragma unroll
            for (int r = 0; r < 4; ++r)
                OaccA[(quad * 4 + r) * 66 + dt * 16 + fr] = oacc[dt][r];
    }
    __syncthreads();

    if (w == 0) {
        const float rs2 = 1.f / (S2s[0][fr] + S2s[1][fr] + S2s[2][fr] + S2s[3][fr]);
        float rs2q[4];
#pragma unroll
        for (int r = 0; r < 4; ++r) rs2q[r] = __shfl(rs2, quad * 4 + r);

        // O rows q0+quad*4+r, cols dt*16+fr
        unsigned short* obase = Ob + ((size_t)(b * Sdim + q0)) * Ddim + h * DKdim;
#pragma unroll
        for (int dt = 0; dt < 4; ++dt)
#pragma unroll
            for (int r = 0; r < 4; ++r) {
                const float v = oacc[dt][r] + OaccA[(quad * 4 + r) * 66 + dt * 16 + fr];
                obase[(size_t)(quad * 4 + r) * Ddim + dt * 16 + fr] = f2b(v * rs2q[r]);
            }
    }
}

// ---------------------------------------------------------------------------
// LayerNorm, WAVE-PER-ROW (no barriers): 64 lanes x 8 f32, 12 shfl_xor.
// Optional fp32 partial P fused-added to X (split-K combine). fp32 out
// (nullable) + bf16 out (nullable). 4 rows per 256-thread block.
// ---------------------------------------------------------------------------
__device__ __forceinline__ void ln_row_wave(
    const float* __restrict__ X, const float* __restrict__ P,
    const float* __restrict__ g, const float* __restrict__ bta,
    float* __restrict__ Y, unsigned short* __restrict__ Yb,
    int row, int lane)
{
    const size_t base = (size_t)row * Ddim + lane * 8;
    float4 a = *(const float4*)(X + base);
    float4 b = *(const float4*)(X + base + 4);
    if (P) {
        float4 pa = *(const float4*)(P + base);
        float4 pb = *(const float4*)(P + base + 4);
        a.x += pa.x; a.y += pa.y; a.z += pa.z; a.w += pa.w;
        b.x += pb.x; b.y += pb.y; b.z += pb.z; b.w += pb.w;
    }
    float s  = a.x + a.y + a.z + a.w + b.x + b.y + b.z + b.w;
    float s2 = a.x * a.x + a.y * a.y + a.z * a.z + a.w * a.w
             + b.x * b.x + b.y * b.y + b.z * b.z + b.w * b.w;
#pragma unroll
    for (int off = 1; off < 64; off <<= 1) {
        s  += __shfl_xor(s, off);
        s2 += __shfl_xor(s2, off);
    }
    const float mean = s * (1.f / Ddim);
    const float var = s2 * (1.f / Ddim) - mean * mean;
    const float rs = rsqrtf(var + 1e-5f);
    float4 ga = *(const float4*)(g + lane * 8);
    float4 gb = *(const float4*)(g + lane * 8 + 4);
    float4 ba = *(const float4*)(bta + lane * 8);
    float4 bb = *(const float4*)(bta + lane * 8 + 4);
    float y[8];
    y[0] = (a.x - mean) * rs * ga.x + ba.x;
    y[1] = (a.y - mean) * rs * ga.y + ba.y;
    y[2] = (a.z - mean) * rs * ga.z + ba.z;
    y[3] = (a.w - mean) * rs * ga.w + ba.w;
    y[4] = (b.x - mean) * rs * gb.x + bb.x;
    y[5] = (b.y - mean) * rs * gb.y + bb.y;
    y[6] = (b.z - mean) * rs * gb.z + bb.z;
    y[7] = (b.w - mean) * rs * gb.w + bb.w;
    if (Y) {
        *(float4*)(Y + base)     = make_float4(y[0], y[1], y[2], y[3]);
        *(float4*)(Y + base + 4) = make_float4(y[4], y[5], y[6], y[7]);
    }
    if (Yb) {
        ushort8 o;
#pragma unroll
        for (int c = 0; c < 8; ++c) o[c] = f2b(y[c]);
        *(ushort8*)(Yb + base) = o;
    }
}

__global__ __launch_bounds__(256) void ln_w1(
    const float* __restrict__ X, const float* __restrict__ P,
    const float* __restrict__ g, const float* __restrict__ bta,
    float* __restrict__ Y, unsigned short* __restrict__ Yb)
{
    const int row = blockIdx.x * 4 + (threadIdx.x >> 6);
    ln_row_wave(X, P, g, bta, Y, Yb, row, threadIdx.x & 63);
}

// dual-tensor LN (no partial): rows [0,Mrows) set a, [Mrows,2*Mrows) set b
__global__ __launch_bounds__(256) void ln_w2(
    const float* __restrict__ Xa, const float* __restrict__ ga,
    const float* __restrict__ ba, float* __restrict__ Ya,
    unsigned short* __restrict__ Yba,
    const float* __restrict__ Xb, const float* __restrict__ gb,
    const float* __restrict__ bb, float* __restrict__ Yb2,
    unsigned short* __restrict__ Ybb)
{
    const int row = blockIdx.x * 4 + (threadIdx.x >> 6);
    if (row < Mrows)
        ln_row_wave(Xa, nullptr, ga, ba, Ya, Yba, row, threadIdx.x & 63);
    else
        ln_row_wave(Xb, nullptr, gb, bb, Yb2, Ybb, row - Mrows, threadIdx.x & 63);
}

// ---------------------------------------------------------------------------
extern "C" void kernel_launch(void* const* d_in, const int* in_sizes, int n_in,
                              void* d_out, int out_size, void* d_ws, size_t ws_size,
                              hipStream_t stream)
{
    const float* x0     = (const float*)d_in[0];
    const float* y0     = (const float*)d_in[1];
    const float* Wk     = (const float*)d_in[2];
    const float* bk     = (const float*)d_in[3];
    const float* Wv     = (const float*)d_in[4];
    const float* bv     = (const float*)d_in[5];
    const float* Wo     = (const float*)d_in[6];
    const float* bo     = (const float*)d_in[7];
    const float* gammas = (const float*)d_in[8];
    const float* ln1g   = (const float*)d_in[9];
    const float* ln1b   = (const float*)d_in[10];
    const float* W1     = (const float*)d_in[11];
    const float* b1     = (const float*)d_in[12];
    const float* W2     = (const float*)d_in[13];
    const float* b2     = (const float*)d_in[14];
    const float* ln2g   = (const float*)d_in[15];
    const float* ln2b   = (const float*)d_in[16];

    const size_t NBSD = (size_t)Mrows * Ddim;   // 4,194,304
    float* ws = (float*)d_ws;
    float* T1   = ws;
    float* X1   = T1 + NBSD;
    float* Xbuf = X1 + NBSD;
    unsigned short* Kbf = (unsigned short*)(Xbuf + NBSD);
    unsigned short* Vt  = Kbf + NBSD;
    unsigned short* AOb = Vt + NBSD;
    unsigned short* Abf = AOb + NBSD;
    unsigned short* Xbf = Abf + NBSD;
    unsigned short* Ybf = Xbf + NBSD;
    unsigned short* Hbb = Ybf + NBSD;                       // [M,F] = 4 NBSD units
    unsigned short* WtAll = Hbb + (size_t)Mrows * Fdim;

    // transient aliases (all regions dead at their aliased use time):
    unsigned short* Xb_in = Hbb;                 // bf16(x0), consumed by kv4
    unsigned short* AOb1  = Hbb + NBSD;          // layer-1 attention out
    unsigned short* Yb_in = Hbb + 2 * NBSD;      // bf16(y0), consumed by kv4
    unsigned short* Kbf1  = Abf;                 // layer-1 K (dead until LN writes Abf)
    unsigned short* Vt1   = Ybf;                 // layer-1 Vt (dead until LN2_0 writes Ybf)
    float* T1b = (float*)d_out;                  // layer-1 O out (dead until final LN)
    float* P1  = (float*)AOb;                    // FFN2 split-K partial: spans AOb+Abf
                                                 // (both dead at each FFN2 call site)

    auto WtK = [&](int l) { return WtAll + (size_t)(l * 3 + 0) * 262144; };
    auto WtV = [&](int l) { return WtAll + (size_t)(l * 3 + 1) * 262144; };
    auto WtO = [&](int l) { return WtAll + (size_t)(l * 3 + 2) * 262144; };
    auto Wt1 = [&](int l) { return WtAll + 9 * 262144 + (size_t)(l >> 1) * (512 * 2048); };
    auto Wt2 = [&](int l) { return WtAll + 9 * 262144 + 2 * (512 * 2048) + (size_t)(l >> 1) * (2048 * 512); };

    const int convBlocks = (int)(NBSD / 2048);   // 2048

    // 1. weight transposes
    wtrans_all<<<1600, 256, 0, stream>>>(Wk, Wv, Wo, W1, W2, WtAll);
    // 2. both inputs -> bf16 (one launch)
    conv_b2<<<2 * convBlocks, 256, 0, stream>>>(y0, Yb_in, x0, Xb_in, convBlocks);
    // 3. KV projections for layers 0 and 1 (one launch, z=0..3)
    gemm_kv4<<<dim3(8, 64, 4), 256, 0, stream>>>(
        Yb_in, Xb_in, WtK(0), WtV(0), WtK(1), WtV(1),
        bk, bv, bk + Ddim, bv + Ddim,
        Kbf, Vt, Kbf1, Vt1);
    // 4. attention layers 0+1 merged (mask1 both; layer interleaved in x)
    attn_flash8<<<dim3(2 * Bdim * Hdim, Sdim / 16, 1), 256, 0, stream>>>(
        Kbf, Vt, Kbf1, Vt1, gammas, AOb, AOb1, 1, 1);
    // 5. O-projections + residual for layers 0+1 (one launch)
    gemm_o2<<<dim3(8, 64, 2), 256, 0, stream>>>(
        AOb, AOb1, WtO(0), WtO(1), bo, bo + Ddim, y0, x0, T1, T1b);
    // 6. LN1 for both layers (one launch): L0 -> X1 + Abf; L1 -> Xbuf + Xbf (final)
    ln_w2<<<2 * Mrows / 4, 256, 0, stream>>>(
        T1, ln1g, ln1b, X1, Abf,
        T1b, ln1g + Ddim, ln1b + Ddim, Xbuf, Xbf);
    // 7-9. block-0 FFN (FFN2 split-K=2, LN combines) + LN2 -> Ybf
    gemm_mfma<<<dim3(Fdim / 128, Mrows / 128), 256, 0, stream>>>(
        (const __hip_bfloat16*)Abf, (const __hip_bfloat16*)Wt1(0),
        b1, nullptr, nullptr, Hbb, Mrows, Fdim, Ddim, 1);
    gemm_ffn2<<<dim3(8, 64, 2), 256, 0, stream>>>(
        Hbb, Wt2(0), b2, X1, T1, P1);
    ln_w1<<<Mrows / 4, 256, 0, stream>>>(T1, P1, ln2g, ln2b, nullptr, Ybf);

    // ---- block 2: knowledge retriever (q/k = x-out, v = y-out, mask0, FFN)
    const int l = 2;
    // 10. KV (dual z): K from Xbf, V from Ybf
    gemm_n64<<<dim3(8, 64, 2), 256, 0, stream>>>(
        Xbf, Ybf, WtK(l), WtV(l), bk + l * Ddim, bv + l * Ddim,
        nullptr, nullptr, Kbf, Vt, Ddim);
    // 11. attention (mask0, single layer)
    attn_flash8<<<dim3(Bdim * Hdim, Sdim / 16, 1), 256, 0, stream>>>(
        Kbf, Vt, Kbf, Vt, gammas + (size_t)l * Hdim, AOb, AOb, 0, 0);
    // 12. O-projection + residual (Xbuf)
    gemm_n64<<<dim3(8, 64, 1), 256, 0, stream>>>(
        AOb, AOb, WtO(l), WtO(l), bo + l * Ddim, bo + l * Ddim,
        Xbuf, T1, nullptr, nullptr, Ddim);
    // 13. LN1 -> X1 + Abf
    ln_w1<<<Mrows / 4, 256, 0, stream>>>(T1, nullptr,
        ln1g + (size_t)l * Ddim, ln1b + (size_t)l * Ddim, X1, Abf);
    // 14-16. FFN (split-K FFN2) + LN2 -> d_out (fp32)
    gemm_mfma<<<dim3(Fdim / 128, Mrows / 128), 256, 0, stream>>>(
        (const __hip_bfloat16*)Abf, (const __hip_bfloat16*)Wt1(l),
        b1 + (size_t)l * Fdim, nullptr, nullptr, Hbb, Mrows, Fdim, Ddim, 1);
    gemm_ffn2<<<dim3(8, 64, 2), 256, 0, stream>>>(
        Hbb, Wt2(l), b2 + (size_t)l * Ddim, X1, T1, P1);
    ln_w1<<<Mrows / 4, 256, 0, stream>>>(T1, P1,
        ln2g + (size_t)l * Ddim, ln2b + (size_t)l * Ddim, (float*)d_out, nullptr);
}